// Round 9
// baseline (197.362 us; speedup 1.0000x reference)
//
#include <hip/hip_runtime.h>
#include <hip/hip_bf16.h>

#define S_TOK 3072   // 64*48
#define NHEADS 8

typedef __attribute__((ext_vector_type(8))) short short8;
typedef __attribute__((ext_vector_type(4))) float floatx4;
typedef __attribute__((ext_vector_type(4))) unsigned short ushortx4;

__device__ __forceinline__ unsigned short f2bf(float f) {
  union { float f; unsigned u; } v; v.f = f;
  unsigned r = v.u + 0x7fffu + ((v.u >> 16) & 1u);   // RTN-even
  return (unsigned short)(r >> 16);
}
__device__ __forceinline__ float bf2f(unsigned short h) {
  union { unsigned u; float f; } v; v.u = (unsigned)h << 16;
  return v.f;
}
__device__ __forceinline__ unsigned pack2bf(float a, float b) {
  __hip_bfloat162 h = __float22bfloat162_rn(make_float2(a, b));
  union { __hip_bfloat162 h; unsigned u; } c; c.h = h;
  return c.u;
}
__device__ __forceinline__ void gload16(const void* g, void* l) {
  __builtin_amdgcn_global_load_lds(
      (const __attribute__((address_space(1))) unsigned int*)g,
      (__attribute__((address_space(3))) unsigned int*)l, 16, 0, 0);
}

// ---- merged converter: X hi/lo (blocks 0..1535), w_qkv^T (1536..1727),
// w_out^T (1728..1791); all outputs pre-swizzled for gload_lds staging ----
__global__ __launch_bounds__(256) void ga_conv_all(
    const float* __restrict__ X, const float* __restrict__ Wq,
    const float* __restrict__ Wo, unsigned short* __restrict__ xh,
    unsigned short* __restrict__ xl, unsigned short* __restrict__ wqh,
    unsigned short* __restrict__ wql, unsigned short* __restrict__ woh,
    unsigned short* __restrict__ wol) {
  const int blk = blockIdx.x;
  const int t = threadIdx.x;
  if (blk < 1536) {
    const int c = blk * 256 + t;
    const int m = c >> 6;
    const int c8 = (c & 63) << 3;
    const float* src = X + (size_t)m * 512 + c8;
    float4 v0 = *(const float4*)src, v1 = *(const float4*)(src + 4);
    float vv[8] = {v0.x, v0.y, v0.z, v0.w, v1.x, v1.y, v1.z, v1.w};
    union { unsigned short s[8]; short8 v; } hh, ll;
#pragma unroll
    for (int e = 0; e < 8; ++e) {
      hh.s[e] = f2bf(vv[e]);
      ll.s[e] = f2bf(vv[e] - bf2f(hh.s[e]));
    }
    const size_t dst = (size_t)m * 512 + (c8 ^ ((m & 7) << 3));
    *(short8*)&xh[dst] = hh.v;
    *(short8*)&xl[dst] = ll.v;
    return;
  }
  // weight transpose paths
  const int wq = (blk < 1728);
  const int b2 = wq ? (blk - 1536) : (blk - 1728);
  const int N = wq ? 1536 : 512;
  const float* W = wq ? Wq : Wo;
  unsigned short* th = wq ? wqh : woh;
  unsigned short* tl = wq ? wql : wol;
  const int k0 = (b2 & 7) * 64, n0 = (b2 >> 3) * 64;
  __shared__ float Ts[64][65];
#pragma unroll
  for (int i = 0; i < 4; ++i) {
    const int r = (t >> 4) + i * 16, c4 = (t & 15) * 4;
    float4 v = *(const float4*)&W[(size_t)(k0 + r) * N + n0 + c4];
    Ts[r][c4] = v.x; Ts[r][c4 + 1] = v.y; Ts[r][c4 + 2] = v.z; Ts[r][c4 + 3] = v.w;
  }
  __syncthreads();
#pragma unroll
  for (int j = 0; j < 2; ++j) {
    const int chunk = t * 2 + j;
    const int nl = chunk >> 3, m8 = chunk & 7;
    const int n = n0 + nl;
    const int ks = (m8 * 8) ^ ((n & 7) << 3);
    union { unsigned short s[8]; short8 v; } hh, ll;
#pragma unroll
    for (int e = 0; e < 8; ++e) {
      float f = Ts[ks + e][nl];
      hh.s[e] = f2bf(f);
      ll.s[e] = f2bf(f - bf2f(hh.s[e]));
    }
    const size_t dst = (size_t)n * 512 + k0 + m8 * 8;
    *(short8*)&th[dst] = hh.v;
    *(short8*)&tl[dst] = ll.v;
  }
}

// ---- bf16x3 MFMA GEMM (unchanged from R8) ----
template <int BM, int BN, int WHICH>
__global__ __launch_bounds__(256, 2) void ga_mm3(
    const unsigned short* __restrict__ Ah, const unsigned short* __restrict__ Al,
    const unsigned short* __restrict__ Bh, const unsigned short* __restrict__ Bl,
    unsigned short* __restrict__ Qd, unsigned short* __restrict__ Kd,
    unsigned short* __restrict__ Vd, float* __restrict__ Out) {
  const int tid = threadIdx.x;
  const int w = tid >> 6, l = tid & 63;
  const int g = l >> 4, ln = l & 15;
  const int wm = w >> 1, wn = w & 1;
  const int m0 = blockIdx.x * BM;
  const int n0 = blockIdx.y * BN;
  constexpr int MI = BM / 32;
  constexpr int NI = BN / 32;
  __shared__ unsigned short Alds[2][BM * 64];
  __shared__ unsigned short Blds[2][BN * 64];
  floatx4 acc[MI][NI];
#pragma unroll
  for (int mi = 0; mi < MI; ++mi)
#pragma unroll
    for (int ni = 0; ni < NI; ++ni)
#pragma unroll
      for (int r = 0; r < 4; ++r) acc[mi][ni][r] = 0.f;

  for (int k0 = 0; k0 < 512; k0 += 64) {
    __syncthreads();
    {
      constexpr int PWA = (BM * 128) / 4096;
      constexpr int PWB = (BN * 128) / 4096;
      const char* ga_h = (const char*)(Ah + (size_t)m0 * 512 + k0);
      const char* ga_l = (const char*)(Al + (size_t)m0 * 512 + k0);
      const char* gb_h = (const char*)(Bh + (size_t)n0 * 512 + k0);
      const char* gb_l = (const char*)(Bl + (size_t)n0 * 512 + k0);
#pragma unroll
      for (int i = 0; i < PWA; ++i) {
        const int off = (w * PWA + i) * 1024;
        const int gb = ((off >> 7) + (l >> 3)) * 1024 + (l & 7) * 16;
        gload16(ga_h + gb, (char*)&Alds[0][0] + off);
        gload16(ga_l + gb, (char*)&Alds[1][0] + off);
      }
#pragma unroll
      for (int i = 0; i < PWB; ++i) {
        const int off = (w * PWB + i) * 1024;
        const int gb = ((off >> 7) + (l >> 3)) * 1024 + (l & 7) * 16;
        gload16(gb_h + gb, (char*)&Blds[0][0] + off);
        gload16(gb_l + gb, (char*)&Blds[1][0] + off);
      }
    }
    asm volatile("s_waitcnt vmcnt(0)" ::: "memory");
    __syncthreads();
#pragma unroll
    for (int kk = 0; kk < 64; kk += 32) {
      const int kbase = kk + g * 8;
      short8 ah[MI], al[MI], bh[NI], bl[NI];
#pragma unroll
      for (int mi = 0; mi < MI; ++mi) {
        const int row = wm * (BM / 2) + mi * 16 + ln;
        const int a = row * 64 + (kbase ^ ((row & 7) << 3));
        ah[mi] = *(const short8*)&Alds[0][a];
        al[mi] = *(const short8*)&Alds[1][a];
      }
#pragma unroll
      for (int ni = 0; ni < NI; ++ni) {
        const int row = wn * (BN / 2) + ni * 16 + ln;
        const int a = row * 64 + (kbase ^ ((row & 7) << 3));
        bh[ni] = *(const short8*)&Blds[0][a];
        bl[ni] = *(const short8*)&Blds[1][a];
      }
#pragma unroll
      for (int mi = 0; mi < MI; ++mi)
#pragma unroll
        for (int ni = 0; ni < NI; ++ni) {
          acc[mi][ni] = __builtin_amdgcn_mfma_f32_16x16x32_bf16(
              ah[mi], bh[ni], acc[mi][ni], 0, 0, 0);
          acc[mi][ni] = __builtin_amdgcn_mfma_f32_16x16x32_bf16(
              al[mi], bh[ni], acc[mi][ni], 0, 0, 0);
          acc[mi][ni] = __builtin_amdgcn_mfma_f32_16x16x32_bf16(
              ah[mi], bl[ni], acc[mi][ni], 0, 0, 0);
        }
    }
  }
  if constexpr (WHICH == 0) {
    const int b = m0 / S_TOK;
    const int s_base = (m0 % S_TOK) + wm * (BM / 2);
#pragma unroll
    for (int ni = 0; ni < NI; ++ni) {
      const int ng = n0 + wn * (BN / 2) + ni * 16;
      const int which = ng >> 9;
      const int h = (ng >> 6) & 7;
      const int d = (ng & 63) + ln;
      unsigned short* hp = (which == 0 ? Qd : which == 1 ? Kd : Vd) +
                           (size_t)(b * 8 + h) * S_TOK * 64;
      const float qs = (which == 0) ? 0.18033688f : 1.0f;  // 1/8*log2e
#pragma unroll
      for (int mi = 0; mi < MI; ++mi)
#pragma unroll
        for (int r = 0; r < 4; ++r) {
          const int s = s_base + mi * 16 + g * 4 + r;
          const size_t idx =
              (size_t)s * 64 + ((which == 1) ? (d ^ ((s & 7) << 3)) : d);
          hp[idx] = f2bf(acc[mi][ni][r] * qs);
        }
    }
  } else {
#pragma unroll
    for (int mi = 0; mi < MI; ++mi)
#pragma unroll
      for (int ni = 0; ni < NI; ++ni)
#pragma unroll
        for (int r = 0; r < 4; ++r)
          Out[(size_t)(m0 + wm * (BM / 2) + mi * 16 + g * 4 + r) * 512 + n0 +
              wn * (BN / 2) + ni * 16 + ln] = acc[mi][ni][r];
  }
}

// ---- Pass A2: V -> tiled/transposed/pre-swizzled, key-permuted Vt2 (R8) ----
__global__ __launch_bounds__(256) void ga_vtrans(
    const unsigned short* __restrict__ V, unsigned short* __restrict__ Vt2) {
  const int t = threadIdx.x;
  const int tile = blockIdx.x;
  const int bh = blockIdx.y;
  __shared__ unsigned short Ts[96][72];
  const unsigned short* vp = V + ((size_t)bh * S_TOK + tile * 96) * 64;
#pragma unroll
  for (int it = 0; it < 3; ++it) {
    int c = it * 256 + t;
    int s = c >> 3, d8 = c & 7;
    short8 v = *(const short8*)&vp[(size_t)s * 64 + d8 * 8];
    *(short8*)&Ts[s][d8 * 8] = v;
  }
  __syncthreads();
  unsigned short* op = Vt2 + ((size_t)bh * 32 + tile) * 8192;
#pragma unroll
  for (int it = 0; it < 4; ++it) {
    int c2 = it * 256 + t;
    int a = c2 * 8;
    int d = a >> 7;
    int pos0 = (a & 127) ^ ((d & 7) << 3);
    short8 o;
    if (pos0 < 96) {
      const int base = (pos0 & 96) + ((pos0 >> 3) & 3) * 4;
#pragma unroll
      for (int j = 0; j < 8; ++j) {
        const int key = base + ((j >> 2) << 4) + (j & 3);
        o[j] = (short)Ts[key][d];
      }
    } else {
#pragma unroll
      for (int j = 0; j < 8; ++j) o[j] = 0;
    }
    *(short8*)&op[a] = o;
  }
}

// ------- Pass B: attention; T14 reg-prefetch staging + XCD-swizzled grid -----
__global__ __launch_bounds__(256) void ga_attn16(
    const unsigned short* __restrict__ Q, const unsigned short* __restrict__ Kg,
    const unsigned short* __restrict__ Vt2, const float* __restrict__ rowtab,
    const float* __restrict__ coltab, float* __restrict__ Opart,
    float* __restrict__ Lpart, int nsplit) {
  const int tid = threadIdx.x;
  const int w = tid >> 6;
  const int l = tid & 63;
  const int g = l >> 4;
  const int ln = l & 15;
  // XCD-aware decode: all blocks of one bh land on one XCD (K/V L2-resident)
  const int wgid = blockIdx.x;
  const int idx = wgid >> 3;
  const int bpb = 24 * nsplit;                  // blocks per bh
  const int bh = ((wgid & 7) << 1) + idx / bpb;
  const int rem = idx % bpb;
  const int sp = rem / 24;
  const int qb = rem % 24;
  const int h = bh & 7;
  const int q0 = qb * 128 + w * 32;
  const int tiles_per_split = 32 / nsplit;

  __shared__ float rtab[127];
  __shared__ float ctab[95];
  __shared__ unsigned short Klds[6144];
  __shared__ unsigned short Vlds[8192];
  for (int i = tid; i < 127; i += 256) rtab[i] = rowtab[i * 8 + h] * 1.44269504f;
  for (int i = tid; i < 95; i += 256) ctab[i] = coltab[i * 8 + h] * 1.44269504f;

  const unsigned short* Qp = Q + (size_t)bh * S_TOK * 64;
  const unsigned short* Kp = Kg + (size_t)bh * S_TOK * 64;
  const unsigned short* Vp = Vt2 + (size_t)bh * 32 * 8192;

  int qr[2], qc[2];
  short8 qf[2][2];
  float ctr[2][3][4];
  uint4 kreg[3], vreg[4];

  const int t0 = sp * tiles_per_split;
  const int tend = t0 + tiles_per_split;
  // prologue: load tile t0 to regs
  {
    const char* kg = (const char*)(Kp + (size_t)t0 * 96 * 64);
    const char* vg = (const char*)(Vp + (size_t)t0 * 8192);
#pragma unroll
    for (int i = 0; i < 3; ++i)
      kreg[i] = *(const uint4*)(kg + w * 3072 + i * 1024 + l * 16);
#pragma unroll
    for (int i = 0; i < 4; ++i)
      vreg[i] = *(const uint4*)(vg + w * 4096 + i * 1024 + l * 16);
  }
  __syncthreads();   // tabs ready (also pre-write barrier)
#pragma unroll
  for (int u = 0; u < 2; ++u) {
    const int q = q0 + u * 16 + ln;
    qr[u] = q / 48;
    qc[u] = q - qr[u] * 48;
    qf[u][0] = *(const short8*)&Qp[(size_t)q * 64 + g * 8];
    qf[u][1] = *(const short8*)&Qp[(size_t)q * 64 + 32 + g * 8];
    const float* cb = &ctab[qc[u] - g * 4 + 47];
#pragma unroll
    for (int m = 0; m < 3; ++m)
#pragma unroll
      for (int r = 0; r < 4; ++r) ctr[u][m][r] = cb[-(16 * m + r)];
  }
  // write t0 to LDS
#pragma unroll
  for (int i = 0; i < 3; ++i)
    *(uint4*)((char*)Klds + w * 3072 + i * 1024 + l * 16) = kreg[i];
#pragma unroll
  for (int i = 0; i < 4; ++i)
    *(uint4*)((char*)Vlds + w * 4096 + i * 1024 + l * 16) = vreg[i];
  __syncthreads();

  short8 ones;
  {
    union { unsigned short s[8]; short8 v; } on;
#pragma unroll
    for (int j = 0; j < 8; ++j) on.s[j] = 0x3F80;  // bf16 1.0
    ones = on.v;
  }

  floatx4 o_acc[2][4];
  floatx4 o5[2];
#pragma unroll
  for (int u = 0; u < 2; ++u) {
#pragma unroll
    for (int r = 0; r < 4; ++r) o5[u][r] = 0.f;
#pragma unroll
    for (int dt = 0; dt < 4; ++dt)
#pragma unroll
      for (int r = 0; r < 4; ++r) o_acc[u][dt][r] = 0.f;
  }

  for (int t = t0; t < tend; ++t) {
    const bool pf = (t + 1 < tend);
    if (pf) {  // issue next tile's loads early; latency hides under compute
      const char* kg = (const char*)(Kp + (size_t)(t + 1) * 96 * 64);
      const char* vg = (const char*)(Vp + (size_t)(t + 1) * 8192);
#pragma unroll
      for (int i = 0; i < 3; ++i)
        kreg[i] = *(const uint4*)(kg + w * 3072 + i * 1024 + l * 16);
#pragma unroll
      for (int i = 0; i < 4; ++i)
        vreg[i] = *(const uint4*)(vg + w * 4096 + i * 1024 + l * 16);
    }
    float rt[2][2];
#pragma unroll
    for (int u = 0; u < 2; ++u) {
      rt[u][0] = rtab[qr[u] + 63 - 2 * t] - 12.0f;
      rt[u][1] = rtab[qr[u] + 62 - 2 * t] - 12.0f;
    }
    const int swz = (ln & 7) << 3;
#pragma unroll
    for (int kc32 = 0; kc32 < 3; ++kc32) {
      float e[2][2][4];
#pragma unroll
      for (int kh = 0; kh < 2; ++kh) {
        const int kt = kc32 * 2 + kh;
        const int rb = (kt * 16 + ln) * 64;
        short8 kf0 = *(const short8*)&Klds[rb + ((g * 8) ^ swz)];
        short8 kf1 = *(const short8*)&Klds[rb + ((32 + g * 8) ^ swz)];
        const int m = kt % 3, wrap = kt / 3;
#pragma unroll
        for (int u = 0; u < 2; ++u) {
          floatx4 s = {0.f, 0.f, 0.f, 0.f};
          s = __builtin_amdgcn_mfma_f32_16x16x32_bf16(kf0, qf[u][0], s, 0, 0, 0);
          s = __builtin_amdgcn_mfma_f32_16x16x32_bf16(kf1, qf[u][1], s, 0, 0, 0);
          const float rtw = rt[u][wrap];
#pragma unroll
          for (int r = 0; r < 4; ++r)
            e[u][kh][r] = __builtin_amdgcn_exp2f(s[r] + rtw + ctr[u][m][r]);
        }
      }
      short8 pf2[2];
#pragma unroll
      for (int u = 0; u < 2; ++u) {
        union { unsigned uu[4]; short8 v; } pk;
        pk.uu[0] = pack2bf(e[u][0][0], e[u][0][1]);
        pk.uu[1] = pack2bf(e[u][0][2], e[u][0][3]);
        pk.uu[2] = pack2bf(e[u][1][0], e[u][1][1]);
        pk.uu[3] = pack2bf(e[u][1][2], e[u][1][3]);
        pf2[u] = pk.v;
      }
#pragma unroll
      for (int dt = 0; dt < 4; ++dt) {
        const int vrow = dt * 16 + ln;
        short8 vf = *(const short8*)&Vlds[vrow * 128 +
                                          ((kc32 * 32 + g * 8) ^ swz)];
        o_acc[0][dt] =
            __builtin_amdgcn_mfma_f32_16x16x32_bf16(pf2[0], vf, o_acc[0][dt], 0, 0, 0);
        o_acc[1][dt] =
            __builtin_amdgcn_mfma_f32_16x16x32_bf16(pf2[1], vf, o_acc[1][dt], 0, 0, 0);
      }
      o5[0] = __builtin_amdgcn_mfma_f32_16x16x32_bf16(pf2[0], ones, o5[0], 0, 0, 0);
      o5[1] = __builtin_amdgcn_mfma_f32_16x16x32_bf16(pf2[1], ones, o5[1], 0, 0, 0);
    }
    __syncthreads();   // all waves done reading tile t
    if (pf) {          // write tile t+1 (vmcnt auto-inserted on reg use)
#pragma unroll
      for (int i = 0; i < 3; ++i)
        *(uint4*)((char*)Klds + w * 3072 + i * 1024 + l * 16) = kreg[i];
#pragma unroll
      for (int i = 0; i < 4; ++i)
        *(uint4*)((char*)Vlds + w * 4096 + i * 1024 + l * 16) = vreg[i];
      __syncthreads();
    }
  }
  const size_t rowbase = (size_t)(sp * 16 + bh) * S_TOK;
#pragma unroll
  for (int u = 0; u < 2; ++u) {
    if (ln == 0) {
#pragma unroll
      for (int r = 0; r < 4; ++r)
        Lpart[rowbase + q0 + u * 16 + g * 4 + r] = o5[u][r];
    }
#pragma unroll
    for (int dt = 0; dt < 4; ++dt)
#pragma unroll
      for (int r = 0; r < 4; ++r)
        Opart[(rowbase + q0 + u * 16 + g * 4 + r) * 64 + dt * 16 + ln] =
            o_acc[u][dt][r];
  }
}

// ---- combine split-K partials -> ctx bf16 hi/lo, swizzled (R8) ----
template <int NS>
__global__ __launch_bounds__(256) void ga_combine(
    const float* __restrict__ Opart, const float* __restrict__ Lpart,
    unsigned short* __restrict__ ch, unsigned short* __restrict__ cl) {
  const int c = blockIdx.x * 256 + threadIdx.x;
  const int m = c >> 6;
  const int col8 = (c & 63) << 3;
  const int b = (m >= S_TOK) ? 1 : 0;
  const int q = m - b * S_TOK;
  const int h = col8 >> 6, d0 = col8 & 63;
  const int bh = b * 8 + h;
  float v[8] = {0.f, 0.f, 0.f, 0.f, 0.f, 0.f, 0.f, 0.f};
  float ls = 0.f;
#pragma unroll
  for (int s = 0; s < NS; ++s) {
    const size_t row = (size_t)(s * 16 + bh) * S_TOK + q;
    ls += Lpart[row];
    const float4 o0 = *(const float4*)&Opart[row * 64 + d0];
    const float4 o1 = *(const float4*)&Opart[row * 64 + d0 + 4];
    v[0] += o0.x; v[1] += o0.y; v[2] += o0.z; v[3] += o0.w;
    v[4] += o1.x; v[5] += o1.y; v[6] += o1.z; v[7] += o1.w;
  }
  const float inv = 1.0f / ls;
  union { unsigned short s[8]; short8 vv; } hh, ll;
#pragma unroll
  for (int e = 0; e < 8; ++e) {
    float f = v[e] * inv;
    hh.s[e] = f2bf(f);
    ll.s[e] = f2bf(f - bf2f(hh.s[e]));
  }
  const size_t dst = (size_t)m * 512 + (col8 ^ ((m & 7) << 3));
  *(short8*)&ch[dst] = hh.vv;
  *(short8*)&cl[dst] = ll.vv;
}

extern "C" void kernel_launch(void* const* d_in, const int* in_sizes, int n_in,
                              void* d_out, int out_size, void* d_ws,
                              size_t ws_size, hipStream_t stream) {
  const float* x = (const float*)d_in[0];       // [2,64,48,512]
  const float* w_qkv = (const float*)d_in[1];   // [512,1536]
  const float* w_out = (const float*)d_in[2];   // [512,512]
  const float* rrow = (const float*)d_in[3];    // [127,8]
  const float* rcol = (const float*)d_in[4];    // [95,8]
  float* out = (float*)d_out;                   // [6144,512]

  unsigned short* ws16 = (unsigned short*)d_ws;
  unsigned short* xh = ws16;                    // 3145728 (later ctx_hi)
  unsigned short* xl = xh + 3145728;            // 3145728 (later ctx_lo)
  unsigned short* wqh = xl + 3145728;           // 786432
  unsigned short* wql = wqh + 786432;
  unsigned short* woh = wql + 786432;           // 262144
  unsigned short* wol = woh + 262144;
  unsigned short* Qb = wol + 262144;            // 3145728
  unsigned short* Kb = Qb + 3145728;
  unsigned short* Vb = Kb + 3145728;
  unsigned short* Vt2 = Vb + 3145728;           // 4194304
  float* Opart = (float*)(Vt2 + 4194304);
  const size_t base_bytes = (size_t)22020096 * 2;
  const size_t per_split = (size_t)(3145728 + 49152) * 4;
  int nsplit = (ws_size >= base_bytes + 2 * per_split) ? 2 : 1;
  float* Lpart = Opart + (size_t)nsplit * 3145728;

  ga_conv_all<<<1792, 256, 0, stream>>>(x, w_qkv, w_out, xh, xl, wqh, wql, woh,
                                        wol);
  ga_mm3<128, 128, 0><<<dim3(48, 12), 256, 0, stream>>>(
      xh, xl, wqh, wql, Qb, Kb, Vb, nullptr);
  ga_vtrans<<<dim3(32, 16), 256, 0, stream>>>(Vb, Vt2);
  ga_attn16<<<24 * 16 * nsplit, 256, 0, stream>>>(
      Qb, Kb, Vt2, rrow, rcol, Opart, Lpart, nsplit);
  if (nsplit == 2)
    ga_combine<2><<<1536, 256, 0, stream>>>(Opart, Lpart, xh, xl);
  else
    ga_combine<1><<<1536, 256, 0, stream>>>(Opart, Lpart, xh, xl);
  ga_mm3<64, 64, 1><<<dim3(96, 8), 256, 0, stream>>>(
      xh, xl, woh, wol, nullptr, nullptr, nullptr, out);
}

// Round 10
// 135.161 us; speedup vs baseline: 1.4602x; 1.4602x over previous
//
#include <hip/hip_runtime.h>
#include <hip/hip_bf16.h>

#define S_TOK 3072   // 64*48
#define NHEADS 8

typedef __attribute__((ext_vector_type(8))) short short8;
typedef __attribute__((ext_vector_type(4))) float floatx4;
typedef __attribute__((ext_vector_type(4))) unsigned short ushortx4;

__device__ __forceinline__ unsigned short f2bf(float f) {
  union { float f; unsigned u; } v; v.f = f;
  unsigned r = v.u + 0x7fffu + ((v.u >> 16) & 1u);   // RTN-even
  return (unsigned short)(r >> 16);
}
__device__ __forceinline__ float bf2f(unsigned short h) {
  union { unsigned u; float f; } v; v.u = (unsigned)h << 16;
  return v.f;
}
__device__ __forceinline__ unsigned pack2bf(float a, float b) {
  __hip_bfloat162 h = __float22bfloat162_rn(make_float2(a, b));
  union { __hip_bfloat162 h; unsigned u; } c; c.h = h;
  return c.u;
}
__device__ __forceinline__ void gload16(const void* g, void* l) {
  __builtin_amdgcn_global_load_lds(
      (const __attribute__((address_space(1))) unsigned int*)g,
      (__attribute__((address_space(3))) unsigned int*)l, 16, 0, 0);
}

// ---- merged converter: X hi/lo (blocks 0..1535), w_qkv^T (1536..1727),
// w_out^T (1728..1791); all outputs pre-swizzled for gload_lds staging ----
__global__ __launch_bounds__(256) void ga_conv_all(
    const float* __restrict__ X, const float* __restrict__ Wq,
    const float* __restrict__ Wo, unsigned short* __restrict__ xh,
    unsigned short* __restrict__ xl, unsigned short* __restrict__ wqh,
    unsigned short* __restrict__ wql, unsigned short* __restrict__ woh,
    unsigned short* __restrict__ wol) {
  const int blk = blockIdx.x;
  const int t = threadIdx.x;
  if (blk < 1536) {
    const int c = blk * 256 + t;
    const int m = c >> 6;
    const int c8 = (c & 63) << 3;
    const float* src = X + (size_t)m * 512 + c8;
    float4 v0 = *(const float4*)src, v1 = *(const float4*)(src + 4);
    float vv[8] = {v0.x, v0.y, v0.z, v0.w, v1.x, v1.y, v1.z, v1.w};
    union { unsigned short s[8]; short8 v; } hh, ll;
#pragma unroll
    for (int e = 0; e < 8; ++e) {
      hh.s[e] = f2bf(vv[e]);
      ll.s[e] = f2bf(vv[e] - bf2f(hh.s[e]));
    }
    const size_t dst = (size_t)m * 512 + (c8 ^ ((m & 7) << 3));
    *(short8*)&xh[dst] = hh.v;
    *(short8*)&xl[dst] = ll.v;
    return;
  }
  const int wq = (blk < 1728);
  const int b2 = wq ? (blk - 1536) : (blk - 1728);
  const int N = wq ? 1536 : 512;
  const float* W = wq ? Wq : Wo;
  unsigned short* th = wq ? wqh : woh;
  unsigned short* tl = wq ? wql : wol;
  const int k0 = (b2 & 7) * 64, n0 = (b2 >> 3) * 64;
  __shared__ float Ts[64][65];
#pragma unroll
  for (int i = 0; i < 4; ++i) {
    const int r = (t >> 4) + i * 16, c4 = (t & 15) * 4;
    float4 v = *(const float4*)&W[(size_t)(k0 + r) * N + n0 + c4];
    Ts[r][c4] = v.x; Ts[r][c4 + 1] = v.y; Ts[r][c4 + 2] = v.z; Ts[r][c4 + 3] = v.w;
  }
  __syncthreads();
#pragma unroll
  for (int j = 0; j < 2; ++j) {
    const int chunk = t * 2 + j;
    const int nl = chunk >> 3, m8 = chunk & 7;
    const int n = n0 + nl;
    const int ks = (m8 * 8) ^ ((n & 7) << 3);
    union { unsigned short s[8]; short8 v; } hh, ll;
#pragma unroll
    for (int e = 0; e < 8; ++e) {
      float f = Ts[ks + e][nl];
      hh.s[e] = f2bf(f);
      ll.s[e] = f2bf(f - bf2f(hh.s[e]));
    }
    const size_t dst = (size_t)n * 512 + k0 + m8 * 8;
    *(short8*)&th[dst] = hh.v;
    *(short8*)&tl[dst] = ll.v;
  }
}

// ---- bf16x3 MFMA GEMM (R8) ----
template <int BM, int BN, int WHICH>
__global__ __launch_bounds__(256, 2) void ga_mm3(
    const unsigned short* __restrict__ Ah, const unsigned short* __restrict__ Al,
    const unsigned short* __restrict__ Bh, const unsigned short* __restrict__ Bl,
    unsigned short* __restrict__ Qd, unsigned short* __restrict__ Kd,
    unsigned short* __restrict__ Vd, float* __restrict__ Out) {
  const int tid = threadIdx.x;
  const int w = tid >> 6, l = tid & 63;
  const int g = l >> 4, ln = l & 15;
  const int wm = w >> 1, wn = w & 1;
  const int m0 = blockIdx.x * BM;
  const int n0 = blockIdx.y * BN;
  constexpr int MI = BM / 32;
  constexpr int NI = BN / 32;
  __shared__ unsigned short Alds[2][BM * 64];
  __shared__ unsigned short Blds[2][BN * 64];
  floatx4 acc[MI][NI];
#pragma unroll
  for (int mi = 0; mi < MI; ++mi)
#pragma unroll
    for (int ni = 0; ni < NI; ++ni)
#pragma unroll
      for (int r = 0; r < 4; ++r) acc[mi][ni][r] = 0.f;

  for (int k0 = 0; k0 < 512; k0 += 64) {
    __syncthreads();
    {
      constexpr int PWA = (BM * 128) / 4096;
      constexpr int PWB = (BN * 128) / 4096;
      const char* ga_h = (const char*)(Ah + (size_t)m0 * 512 + k0);
      const char* ga_l = (const char*)(Al + (size_t)m0 * 512 + k0);
      const char* gb_h = (const char*)(Bh + (size_t)n0 * 512 + k0);
      const char* gb_l = (const char*)(Bl + (size_t)n0 * 512 + k0);
#pragma unroll
      for (int i = 0; i < PWA; ++i) {
        const int off = (w * PWA + i) * 1024;
        const int gb = ((off >> 7) + (l >> 3)) * 1024 + (l & 7) * 16;
        gload16(ga_h + gb, (char*)&Alds[0][0] + off);
        gload16(ga_l + gb, (char*)&Alds[1][0] + off);
      }
#pragma unroll
      for (int i = 0; i < PWB; ++i) {
        const int off = (w * PWB + i) * 1024;
        const int gb = ((off >> 7) + (l >> 3)) * 1024 + (l & 7) * 16;
        gload16(gb_h + gb, (char*)&Blds[0][0] + off);
        gload16(gb_l + gb, (char*)&Blds[1][0] + off);
      }
    }
    asm volatile("s_waitcnt vmcnt(0)" ::: "memory");
    __syncthreads();
#pragma unroll
    for (int kk = 0; kk < 64; kk += 32) {
      const int kbase = kk + g * 8;
      short8 ah[MI], al[MI], bh[NI], bl[NI];
#pragma unroll
      for (int mi = 0; mi < MI; ++mi) {
        const int row = wm * (BM / 2) + mi * 16 + ln;
        const int a = row * 64 + (kbase ^ ((row & 7) << 3));
        ah[mi] = *(const short8*)&Alds[0][a];
        al[mi] = *(const short8*)&Alds[1][a];
      }
#pragma unroll
      for (int ni = 0; ni < NI; ++ni) {
        const int row = wn * (BN / 2) + ni * 16 + ln;
        const int a = row * 64 + (kbase ^ ((row & 7) << 3));
        bh[ni] = *(const short8*)&Blds[0][a];
        bl[ni] = *(const short8*)&Blds[1][a];
      }
#pragma unroll
      for (int mi = 0; mi < MI; ++mi)
#pragma unroll
        for (int ni = 0; ni < NI; ++ni) {
          acc[mi][ni] = __builtin_amdgcn_mfma_f32_16x16x32_bf16(
              ah[mi], bh[ni], acc[mi][ni], 0, 0, 0);
          acc[mi][ni] = __builtin_amdgcn_mfma_f32_16x16x32_bf16(
              al[mi], bh[ni], acc[mi][ni], 0, 0, 0);
          acc[mi][ni] = __builtin_amdgcn_mfma_f32_16x16x32_bf16(
              ah[mi], bl[ni], acc[mi][ni], 0, 0, 0);
        }
    }
  }
  if constexpr (WHICH == 0) {
    const int b = m0 / S_TOK;
    const int s_base = (m0 % S_TOK) + wm * (BM / 2);
#pragma unroll
    for (int ni = 0; ni < NI; ++ni) {
      const int ng = n0 + wn * (BN / 2) + ni * 16;
      const int which = ng >> 9;
      const int h = (ng >> 6) & 7;
      const int d = (ng & 63) + ln;
      unsigned short* hp = (which == 0 ? Qd : which == 1 ? Kd : Vd) +
                           (size_t)(b * 8 + h) * S_TOK * 64;
      const float qs = (which == 0) ? 0.18033688f : 1.0f;  // 1/8*log2e
#pragma unroll
      for (int mi = 0; mi < MI; ++mi)
#pragma unroll
        for (int r = 0; r < 4; ++r) {
          const int s = s_base + mi * 16 + g * 4 + r;
          const size_t idx =
              (size_t)s * 64 + ((which == 1) ? (d ^ ((s & 7) << 3)) : d);
          hp[idx] = f2bf(acc[mi][ni][r] * qs);
        }
    }
  } else {
#pragma unroll
    for (int mi = 0; mi < MI; ++mi)
#pragma unroll
      for (int ni = 0; ni < NI; ++ni)
#pragma unroll
        for (int r = 0; r < 4; ++r)
          Out[(size_t)(m0 + wm * (BM / 2) + mi * 16 + g * 4 + r) * 512 + n0 +
              wn * (BN / 2) + ni * 16 + ln] = acc[mi][ni][r];
  }
}

// ---- Pass A2: V -> tiled/transposed/pre-swizzled, key-permuted Vt2 (R8) ----
__global__ __launch_bounds__(256) void ga_vtrans(
    const unsigned short* __restrict__ V, unsigned short* __restrict__ Vt2) {
  const int t = threadIdx.x;
  const int tile = blockIdx.x;
  const int bh = blockIdx.y;
  __shared__ unsigned short Ts[96][72];
  const unsigned short* vp = V + ((size_t)bh * S_TOK + tile * 96) * 64;
#pragma unroll
  for (int it = 0; it < 3; ++it) {
    int c = it * 256 + t;
    int s = c >> 3, d8 = c & 7;
    short8 v = *(const short8*)&vp[(size_t)s * 64 + d8 * 8];
    *(short8*)&Ts[s][d8 * 8] = v;
  }
  __syncthreads();
  unsigned short* op = Vt2 + ((size_t)bh * 32 + tile) * 8192;
#pragma unroll
  for (int it = 0; it < 4; ++it) {
    int c2 = it * 256 + t;
    int a = c2 * 8;
    int d = a >> 7;
    int pos0 = (a & 127) ^ ((d & 7) << 3);
    short8 o;
    if (pos0 < 96) {
      const int base = (pos0 & 96) + ((pos0 >> 3) & 3) * 4;
#pragma unroll
      for (int j = 0; j < 8; ++j) {
        const int key = base + ((j >> 2) << 4) + (j & 3);
        o[j] = (short)Ts[key][d];
      }
    } else {
#pragma unroll
      for (int j = 0; j < 8; ++j) o[j] = 0;
    }
    *(short8*)&op[a] = o;
  }
}

// ------- Pass B: R8 attention (gload_lds staging, reg-P, ones-MFMA l) -------
__global__ __launch_bounds__(256) void ga_attn16(
    const unsigned short* __restrict__ Q, const unsigned short* __restrict__ Kg,
    const unsigned short* __restrict__ Vt2, const float* __restrict__ rowtab,
    const float* __restrict__ coltab, float* __restrict__ Opart,
    float* __restrict__ Lpart, int tiles_per_split) {
  const int tid = threadIdx.x;
  const int w = tid >> 6;
  const int l = tid & 63;
  const int g = l >> 4;
  const int ln = l & 15;
  const int bh = blockIdx.y;
  const int sp = blockIdx.z;
  const int h = bh & 7;
  const int q0 = blockIdx.x * 128 + w * 32;

  __shared__ float rtab[127];
  __shared__ float ctab[95];
  __shared__ unsigned short Klds[6144];
  __shared__ unsigned short Vlds[8192];
  for (int i = tid; i < 127; i += 256) rtab[i] = rowtab[i * 8 + h] * 1.44269504f;
  for (int i = tid; i < 95; i += 256) ctab[i] = coltab[i * 8 + h] * 1.44269504f;
  __syncthreads();

  const unsigned short* Qp = Q + (size_t)bh * S_TOK * 64;
  const unsigned short* Kp = Kg + (size_t)bh * S_TOK * 64;
  const unsigned short* Vp = Vt2 + (size_t)bh * 32 * 8192;

  int qr[2], qc[2];
  short8 qf[2][2];
  float ctr[2][3][4];
#pragma unroll
  for (int u = 0; u < 2; ++u) {
    const int q = q0 + u * 16 + ln;
    qr[u] = q / 48;
    qc[u] = q - qr[u] * 48;
    qf[u][0] = *(const short8*)&Qp[(size_t)q * 64 + g * 8];
    qf[u][1] = *(const short8*)&Qp[(size_t)q * 64 + 32 + g * 8];
    const float* cb = &ctab[qc[u] - g * 4 + 47];
#pragma unroll
    for (int m = 0; m < 3; ++m)
#pragma unroll
      for (int r = 0; r < 4; ++r) ctr[u][m][r] = cb[-(16 * m + r)];
  }

  short8 ones;
  {
    union { unsigned short s[8]; short8 v; } on;
#pragma unroll
    for (int j = 0; j < 8; ++j) on.s[j] = 0x3F80;  // bf16 1.0
    ones = on.v;
  }

  floatx4 o_acc[2][4];
  floatx4 o5[2];
#pragma unroll
  for (int u = 0; u < 2; ++u) {
#pragma unroll
    for (int r = 0; r < 4; ++r) o5[u][r] = 0.f;
#pragma unroll
    for (int dt = 0; dt < 4; ++dt)
#pragma unroll
      for (int r = 0; r < 4; ++r) o_acc[u][dt][r] = 0.f;
  }

  const int t0 = sp * tiles_per_split;
  for (int t = t0; t < t0 + tiles_per_split; ++t) {
    __syncthreads();
    {
      const char* kg = (const char*)(Kp + (size_t)t * 96 * 64);
      const char* vg = (const char*)(Vp + (size_t)t * 8192);
#pragma unroll
      for (int i = 0; i < 3; ++i) {
        const int off = w * 3072 + i * 1024;
        gload16(kg + off + l * 16, (char*)Klds + off);
      }
#pragma unroll
      for (int i = 0; i < 4; ++i) {
        const int off = w * 4096 + i * 1024;
        gload16(vg + off + l * 16, (char*)Vlds + off);
      }
      asm volatile("s_waitcnt vmcnt(0)" ::: "memory");
      __syncthreads();
    }
    float rt[2][2];
#pragma unroll
    for (int u = 0; u < 2; ++u) {
      rt[u][0] = rtab[qr[u] + 63 - 2 * t] - 12.0f;
      rt[u][1] = rtab[qr[u] + 62 - 2 * t] - 12.0f;
    }
    const int swz = (ln & 7) << 3;
#pragma unroll
    for (int kc32 = 0; kc32 < 3; ++kc32) {
      float e[2][2][4];
#pragma unroll
      for (int kh = 0; kh < 2; ++kh) {
        const int kt = kc32 * 2 + kh;
        const int rb = (kt * 16 + ln) * 64;
        short8 kf0 = *(const short8*)&Klds[rb + ((g * 8) ^ swz)];
        short8 kf1 = *(const short8*)&Klds[rb + ((32 + g * 8) ^ swz)];
        const int m = kt % 3, wrap = kt / 3;
#pragma unroll
        for (int u = 0; u < 2; ++u) {
          floatx4 s = {0.f, 0.f, 0.f, 0.f};
          s = __builtin_amdgcn_mfma_f32_16x16x32_bf16(kf0, qf[u][0], s, 0, 0, 0);
          s = __builtin_amdgcn_mfma_f32_16x16x32_bf16(kf1, qf[u][1], s, 0, 0, 0);
          const float rtw = rt[u][wrap];
#pragma unroll
          for (int r = 0; r < 4; ++r)
            e[u][kh][r] = __builtin_amdgcn_exp2f(s[r] + rtw + ctr[u][m][r]);
        }
      }
      short8 pf[2];
#pragma unroll
      for (int u = 0; u < 2; ++u) {
        union { unsigned uu[4]; short8 v; } pk;
        pk.uu[0] = pack2bf(e[u][0][0], e[u][0][1]);
        pk.uu[1] = pack2bf(e[u][0][2], e[u][0][3]);
        pk.uu[2] = pack2bf(e[u][1][0], e[u][1][1]);
        pk.uu[3] = pack2bf(e[u][1][2], e[u][1][3]);
        pf[u] = pk.v;
      }
#pragma unroll
      for (int dt = 0; dt < 4; ++dt) {
        const int vrow = dt * 16 + ln;
        short8 vf = *(const short8*)&Vlds[vrow * 128 +
                                          ((kc32 * 32 + g * 8) ^ swz)];
        o_acc[0][dt] =
            __builtin_amdgcn_mfma_f32_16x16x32_bf16(pf[0], vf, o_acc[0][dt], 0, 0, 0);
        o_acc[1][dt] =
            __builtin_amdgcn_mfma_f32_16x16x32_bf16(pf[1], vf, o_acc[1][dt], 0, 0, 0);
      }
      o5[0] = __builtin_amdgcn_mfma_f32_16x16x32_bf16(pf[0], ones, o5[0], 0, 0, 0);
      o5[1] = __builtin_amdgcn_mfma_f32_16x16x32_bf16(pf[1], ones, o5[1], 0, 0, 0);
    }
  }
  const size_t rowbase = (size_t)(sp * 16 + bh) * S_TOK;
#pragma unroll
  for (int u = 0; u < 2; ++u) {
    if (ln == 0) {
#pragma unroll
      for (int r = 0; r < 4; ++r)
        Lpart[rowbase + q0 + u * 16 + g * 4 + r] = o5[u][r];
    }
#pragma unroll
    for (int dt = 0; dt < 4; ++dt)
#pragma unroll
      for (int r = 0; r < 4; ++r)
        Opart[(rowbase + q0 + u * 16 + g * 4 + r) * 64 + dt * 16 + ln] =
            o_acc[u][dt][r];
  }
}

// ---- combine split-K partials -> ctx bf16 hi/lo, swizzled ----
template <int NS>
__global__ __launch_bounds__(256) void ga_combine(
    const float* __restrict__ Opart, const float* __restrict__ Lpart,
    unsigned short* __restrict__ ch, unsigned short* __restrict__ cl) {
  const int c = blockIdx.x * 256 + threadIdx.x;
  const int m = c >> 6;
  const int col8 = (c & 63) << 3;
  const int b = (m >= S_TOK) ? 1 : 0;
  const int q = m - b * S_TOK;
  const int h = col8 >> 6, d0 = col8 & 63;
  const int bh = b * 8 + h;
  float v[8] = {0.f, 0.f, 0.f, 0.f, 0.f, 0.f, 0.f, 0.f};
  float ls = 0.f;
#pragma unroll
  for (int s = 0; s < NS; ++s) {
    const size_t row = (size_t)(s * 16 + bh) * S_TOK + q;
    ls += Lpart[row];
    const float4 o0 = *(const float4*)&Opart[row * 64 + d0];
    const float4 o1 = *(const float4*)&Opart[row * 64 + d0 + 4];
    v[0] += o0.x; v[1] += o0.y; v[2] += o0.z; v[3] += o0.w;
    v[4] += o1.x; v[5] += o1.y; v[6] += o1.z; v[7] += o1.w;
  }
  const float inv = 1.0f / ls;
  union { unsigned short s[8]; short8 vv; } hh, ll;
#pragma unroll
  for (int e = 0; e < 8; ++e) {
    float f = v[e] * inv;
    hh.s[e] = f2bf(f);
    ll.s[e] = f2bf(f - bf2f(hh.s[e]));
  }
  const size_t dst = (size_t)m * 512 + (col8 ^ ((m & 7) << 3));
  *(short8*)&ch[dst] = hh.vv;
  *(short8*)&cl[dst] = ll.vv;
}

extern "C" void kernel_launch(void* const* d_in, const int* in_sizes, int n_in,
                              void* d_out, int out_size, void* d_ws,
                              size_t ws_size, hipStream_t stream) {
  const float* x = (const float*)d_in[0];       // [2,64,48,512]
  const float* w_qkv = (const float*)d_in[1];   // [512,1536]
  const float* w_out = (const float*)d_in[2];   // [512,512]
  const float* rrow = (const float*)d_in[3];    // [127,8]
  const float* rcol = (const float*)d_in[4];    // [95,8]
  float* out = (float*)d_out;                   // [6144,512]

  unsigned short* ws16 = (unsigned short*)d_ws;
  unsigned short* xh = ws16;                    // 3145728 (later ctx_hi)
  unsigned short* xl = xh + 3145728;            // 3145728 (later ctx_lo)
  unsigned short* wqh = xl + 3145728;           // 786432
  unsigned short* wql = wqh + 786432;
  unsigned short* woh = wql + 786432;           // 262144
  unsigned short* wol = woh + 262144;
  unsigned short* Qb = wol + 262144;            // 3145728
  unsigned short* Kb = Qb + 3145728;
  unsigned short* Vb = Kb + 3145728;
  unsigned short* Vt2 = Vb + 3145728;           // 4194304
  float* Opart = (float*)(Vt2 + 4194304);
  const size_t base_bytes = (size_t)22020096 * 2;
  const size_t per_split = (size_t)(3145728 + 49152) * 4;
  int nsplit = (ws_size >= base_bytes + 4 * per_split) ? 4
             : (ws_size >= base_bytes + 2 * per_split) ? 2 : 1;
  float* Lpart = Opart + (size_t)nsplit * 3145728;

  ga_conv_all<<<1792, 256, 0, stream>>>(x, w_qkv, w_out, xh, xl, wqh, wql, woh,
                                        wol);
  ga_mm3<128, 128, 0><<<dim3(48, 12), 256, 0, stream>>>(
      xh, xl, wqh, wql, Qb, Kb, Vb, nullptr);
  ga_vtrans<<<dim3(32, 16), 256, 0, stream>>>(Vb, Vt2);
  ga_attn16<<<dim3(24, 16, nsplit), 256, 0, stream>>>(
      Qb, Kb, Vt2, rrow, rcol, Opart, Lpart, 32 / nsplit);
  if (nsplit == 4)
    ga_combine<4><<<1536, 256, 0, stream>>>(Opart, Lpart, xh, xl);
  else if (nsplit == 2)
    ga_combine<2><<<1536, 256, 0, stream>>>(Opart, Lpart, xh, xl);
  else
    ga_combine<1><<<1536, 256, 0, stream>>>(Opart, Lpart, xh, xl);
  ga_mm3<64, 64, 1><<<dim3(96, 8), 256, 0, stream>>>(
      xh, xl, woh, wol, nullptr, nullptr, nullptr, out);
}

// Round 11
// 131.094 us; speedup vs baseline: 1.5055x; 1.0310x over previous
//
#include <hip/hip_runtime.h>
#include <hip/hip_bf16.h>

#define S_TOK 3072   // 64*48
#define NHEADS 8

typedef __attribute__((ext_vector_type(8))) short short8;
typedef __attribute__((ext_vector_type(4))) float floatx4;
typedef __attribute__((ext_vector_type(4))) unsigned short ushortx4;

__device__ __forceinline__ unsigned short f2bf(float f) {
  union { float f; unsigned u; } v; v.f = f;
  unsigned r = v.u + 0x7fffu + ((v.u >> 16) & 1u);   // RTN-even
  return (unsigned short)(r >> 16);
}
__device__ __forceinline__ float bf2f(unsigned short h) {
  union { unsigned u; float f; } v; v.u = (unsigned)h << 16;
  return v.f;
}
__device__ __forceinline__ unsigned pack2bf(float a, float b) {
  __hip_bfloat162 h = __float22bfloat162_rn(make_float2(a, b));
  union { __hip_bfloat162 h; unsigned u; } c; c.h = h;
  return c.u;
}
__device__ __forceinline__ void gload16(const void* g, void* l) {
  __builtin_amdgcn_global_load_lds(
      (const __attribute__((address_space(1))) unsigned int*)g,
      (__attribute__((address_space(3))) unsigned int*)l, 16, 0, 0);
}

// ---- merged converter: X hi/lo (blocks 0..1535), w_qkv^T (1536..1727),
// w_out^T (1728..1791); all outputs pre-swizzled for gload_lds staging ----
__global__ __launch_bounds__(256) void ga_conv_all(
    const float* __restrict__ X, const float* __restrict__ Wq,
    const float* __restrict__ Wo, unsigned short* __restrict__ xh,
    unsigned short* __restrict__ xl, unsigned short* __restrict__ wqh,
    unsigned short* __restrict__ wql, unsigned short* __restrict__ woh,
    unsigned short* __restrict__ wol) {
  const int blk = blockIdx.x;
  const int t = threadIdx.x;
  if (blk < 1536) {
    const int c = blk * 256 + t;
    const int m = c >> 6;
    const int c8 = (c & 63) << 3;
    const float* src = X + (size_t)m * 512 + c8;
    float4 v0 = *(const float4*)src, v1 = *(const float4*)(src + 4);
    float vv[8] = {v0.x, v0.y, v0.z, v0.w, v1.x, v1.y, v1.z, v1.w};
    union { unsigned short s[8]; short8 v; } hh, ll;
#pragma unroll
    for (int e = 0; e < 8; ++e) {
      hh.s[e] = f2bf(vv[e]);
      ll.s[e] = f2bf(vv[e] - bf2f(hh.s[e]));
    }
    const size_t dst = (size_t)m * 512 + (c8 ^ ((m & 7) << 3));
    *(short8*)&xh[dst] = hh.v;
    *(short8*)&xl[dst] = ll.v;
    return;
  }
  const int wq = (blk < 1728);
  const int b2 = wq ? (blk - 1536) : (blk - 1728);
  const int N = wq ? 1536 : 512;
  const float* W = wq ? Wq : Wo;
  unsigned short* th = wq ? wqh : woh;
  unsigned short* tl = wq ? wql : wol;
  const int k0 = (b2 & 7) * 64, n0 = (b2 >> 3) * 64;
  __shared__ float Ts[64][65];
#pragma unroll
  for (int i = 0; i < 4; ++i) {
    const int r = (t >> 4) + i * 16, c4 = (t & 15) * 4;
    float4 v = *(const float4*)&W[(size_t)(k0 + r) * N + n0 + c4];
    Ts[r][c4] = v.x; Ts[r][c4 + 1] = v.y; Ts[r][c4 + 2] = v.z; Ts[r][c4 + 3] = v.w;
  }
  __syncthreads();
#pragma unroll
  for (int j = 0; j < 2; ++j) {
    const int chunk = t * 2 + j;
    const int nl = chunk >> 3, m8 = chunk & 7;
    const int n = n0 + nl;
    const int ks = (m8 * 8) ^ ((n & 7) << 3);
    union { unsigned short s[8]; short8 v; } hh, ll;
#pragma unroll
    for (int e = 0; e < 8; ++e) {
      float f = Ts[ks + e][nl];
      hh.s[e] = f2bf(f);
      ll.s[e] = f2bf(f - bf2f(hh.s[e]));
    }
    const size_t dst = (size_t)n * 512 + k0 + m8 * 8;
    *(short8*)&th[dst] = hh.v;
    *(short8*)&tl[dst] = ll.v;
  }
}

// ---- bf16x3 MFMA GEMM for QKV (R8) ----
template <int BM, int BN>
__global__ __launch_bounds__(256, 2) void ga_mm3(
    const unsigned short* __restrict__ Ah, const unsigned short* __restrict__ Al,
    const unsigned short* __restrict__ Bh, const unsigned short* __restrict__ Bl,
    unsigned short* __restrict__ Qd, unsigned short* __restrict__ Kd,
    unsigned short* __restrict__ Vd) {
  const int tid = threadIdx.x;
  const int w = tid >> 6, l = tid & 63;
  const int g = l >> 4, ln = l & 15;
  const int wm = w >> 1, wn = w & 1;
  const int m0 = blockIdx.x * BM;
  const int n0 = blockIdx.y * BN;
  constexpr int MI = BM / 32;
  constexpr int NI = BN / 32;
  __shared__ unsigned short Alds[2][BM * 64];
  __shared__ unsigned short Blds[2][BN * 64];
  floatx4 acc[MI][NI];
#pragma unroll
  for (int mi = 0; mi < MI; ++mi)
#pragma unroll
    for (int ni = 0; ni < NI; ++ni)
#pragma unroll
      for (int r = 0; r < 4; ++r) acc[mi][ni][r] = 0.f;

  for (int k0 = 0; k0 < 512; k0 += 64) {
    __syncthreads();
    {
      constexpr int PWA = (BM * 128) / 4096;
      constexpr int PWB = (BN * 128) / 4096;
      const char* ga_h = (const char*)(Ah + (size_t)m0 * 512 + k0);
      const char* ga_l = (const char*)(Al + (size_t)m0 * 512 + k0);
      const char* gb_h = (const char*)(Bh + (size_t)n0 * 512 + k0);
      const char* gb_l = (const char*)(Bl + (size_t)n0 * 512 + k0);
#pragma unroll
      for (int i = 0; i < PWA; ++i) {
        const int off = (w * PWA + i) * 1024;
        const int gb = ((off >> 7) + (l >> 3)) * 1024 + (l & 7) * 16;
        gload16(ga_h + gb, (char*)&Alds[0][0] + off);
        gload16(ga_l + gb, (char*)&Alds[1][0] + off);
      }
#pragma unroll
      for (int i = 0; i < PWB; ++i) {
        const int off = (w * PWB + i) * 1024;
        const int gb = ((off >> 7) + (l >> 3)) * 1024 + (l & 7) * 16;
        gload16(gb_h + gb, (char*)&Blds[0][0] + off);
        gload16(gb_l + gb, (char*)&Blds[1][0] + off);
      }
    }
    asm volatile("s_waitcnt vmcnt(0)" ::: "memory");
    __syncthreads();
#pragma unroll
    for (int kk = 0; kk < 64; kk += 32) {
      const int kbase = kk + g * 8;
      short8 ah[MI], al[MI], bh[NI], bl[NI];
#pragma unroll
      for (int mi = 0; mi < MI; ++mi) {
        const int row = wm * (BM / 2) + mi * 16 + ln;
        const int a = row * 64 + (kbase ^ ((row & 7) << 3));
        ah[mi] = *(const short8*)&Alds[0][a];
        al[mi] = *(const short8*)&Alds[1][a];
      }
#pragma unroll
      for (int ni = 0; ni < NI; ++ni) {
        const int row = wn * (BN / 2) + ni * 16 + ln;
        const int a = row * 64 + (kbase ^ ((row & 7) << 3));
        bh[ni] = *(const short8*)&Blds[0][a];
        bl[ni] = *(const short8*)&Blds[1][a];
      }
#pragma unroll
      for (int mi = 0; mi < MI; ++mi)
#pragma unroll
        for (int ni = 0; ni < NI; ++ni) {
          acc[mi][ni] = __builtin_amdgcn_mfma_f32_16x16x32_bf16(
              ah[mi], bh[ni], acc[mi][ni], 0, 0, 0);
          acc[mi][ni] = __builtin_amdgcn_mfma_f32_16x16x32_bf16(
              al[mi], bh[ni], acc[mi][ni], 0, 0, 0);
          acc[mi][ni] = __builtin_amdgcn_mfma_f32_16x16x32_bf16(
              ah[mi], bl[ni], acc[mi][ni], 0, 0, 0);
        }
    }
  }
  // QKV scatter epilogue
  const int b = m0 / S_TOK;
  const int s_base = (m0 % S_TOK) + wm * (BM / 2);
#pragma unroll
  for (int ni = 0; ni < NI; ++ni) {
    const int ng = n0 + wn * (BN / 2) + ni * 16;
    const int which = ng >> 9;
    const int h = (ng >> 6) & 7;
    const int d = (ng & 63) + ln;
    unsigned short* hp = (which == 0 ? Qd : which == 1 ? Kd : Vd) +
                         (size_t)(b * 8 + h) * S_TOK * 64;
    const float qs = (which == 0) ? 0.18033688f : 1.0f;  // 1/8*log2e
#pragma unroll
    for (int mi = 0; mi < MI; ++mi)
#pragma unroll
      for (int r = 0; r < 4; ++r) {
        const int s = s_base + mi * 16 + g * 4 + r;
        const size_t idx =
            (size_t)s * 64 + ((which == 1) ? (d ^ ((s & 7) << 3)) : d);
        hp[idx] = f2bf(acc[mi][ni][r] * qs);
      }
  }
}

// ---- Pass A2: V -> tiled/transposed/pre-swizzled, key-permuted Vt2 (R8) ----
__global__ __launch_bounds__(256) void ga_vtrans(
    const unsigned short* __restrict__ V, unsigned short* __restrict__ Vt2) {
  const int t = threadIdx.x;
  const int tile = blockIdx.x;
  const int bh = blockIdx.y;
  __shared__ unsigned short Ts[96][72];
  const unsigned short* vp = V + ((size_t)bh * S_TOK + tile * 96) * 64;
#pragma unroll
  for (int it = 0; it < 3; ++it) {
    int c = it * 256 + t;
    int s = c >> 3, d8 = c & 7;
    short8 v = *(const short8*)&vp[(size_t)s * 64 + d8 * 8];
    *(short8*)&Ts[s][d8 * 8] = v;
  }
  __syncthreads();
  unsigned short* op = Vt2 + ((size_t)bh * 32 + tile) * 8192;
#pragma unroll
  for (int it = 0; it < 4; ++it) {
    int c2 = it * 256 + t;
    int a = c2 * 8;
    int d = a >> 7;
    int pos0 = (a & 127) ^ ((d & 7) << 3);
    short8 o;
    if (pos0 < 96) {
      const int base = (pos0 & 96) + ((pos0 >> 3) & 3) * 4;
#pragma unroll
      for (int j = 0; j < 8; ++j) {
        const int key = base + ((j >> 2) << 4) + (j & 3);
        o[j] = (short)Ts[key][d];
      }
    } else {
#pragma unroll
      for (int j = 0; j < 8; ++j) o[j] = 0;
    }
    *(short8*)&op[a] = o;
  }
}

// ------- Pass B: R8/R10 attention (gload_lds staging, reg-P, ones-MFMA l) ----
__global__ __launch_bounds__(256) void ga_attn16(
    const unsigned short* __restrict__ Q, const unsigned short* __restrict__ Kg,
    const unsigned short* __restrict__ Vt2, const float* __restrict__ rowtab,
    const float* __restrict__ coltab, float* __restrict__ Opart,
    float* __restrict__ Lpart, int tiles_per_split) {
  const int tid = threadIdx.x;
  const int w = tid >> 6;
  const int l = tid & 63;
  const int g = l >> 4;
  const int ln = l & 15;
  const int bh = blockIdx.y;
  const int sp = blockIdx.z;
  const int h = bh & 7;
  const int q0 = blockIdx.x * 128 + w * 32;

  __shared__ float rtab[127];
  __shared__ float ctab[95];
  __shared__ unsigned short Klds[6144];
  __shared__ unsigned short Vlds[8192];
  for (int i = tid; i < 127; i += 256) rtab[i] = rowtab[i * 8 + h] * 1.44269504f;
  for (int i = tid; i < 95; i += 256) ctab[i] = coltab[i * 8 + h] * 1.44269504f;
  __syncthreads();

  const unsigned short* Qp = Q + (size_t)bh * S_TOK * 64;
  const unsigned short* Kp = Kg + (size_t)bh * S_TOK * 64;
  const unsigned short* Vp = Vt2 + (size_t)bh * 32 * 8192;

  int qr[2], qc[2];
  short8 qf[2][2];
  float ctr[2][3][4];
#pragma unroll
  for (int u = 0; u < 2; ++u) {
    const int q = q0 + u * 16 + ln;
    qr[u] = q / 48;
    qc[u] = q - qr[u] * 48;
    qf[u][0] = *(const short8*)&Qp[(size_t)q * 64 + g * 8];
    qf[u][1] = *(const short8*)&Qp[(size_t)q * 64 + 32 + g * 8];
    const float* cb = &ctab[qc[u] - g * 4 + 47];
#pragma unroll
    for (int m = 0; m < 3; ++m)
#pragma unroll
      for (int r = 0; r < 4; ++r) ctr[u][m][r] = cb[-(16 * m + r)];
  }

  short8 ones;
  {
    union { unsigned short s[8]; short8 v; } on;
#pragma unroll
    for (int j = 0; j < 8; ++j) on.s[j] = 0x3F80;  // bf16 1.0
    ones = on.v;
  }

  floatx4 o_acc[2][4];
  floatx4 o5[2];
#pragma unroll
  for (int u = 0; u < 2; ++u) {
#pragma unroll
    for (int r = 0; r < 4; ++r) o5[u][r] = 0.f;
#pragma unroll
    for (int dt = 0; dt < 4; ++dt)
#pragma unroll
      for (int r = 0; r < 4; ++r) o_acc[u][dt][r] = 0.f;
  }

  const int t0 = sp * tiles_per_split;
  for (int t = t0; t < t0 + tiles_per_split; ++t) {
    __syncthreads();
    {
      const char* kg = (const char*)(Kp + (size_t)t * 96 * 64);
      const char* vg = (const char*)(Vp + (size_t)t * 8192);
#pragma unroll
      for (int i = 0; i < 3; ++i) {
        const int off = w * 3072 + i * 1024;
        gload16(kg + off + l * 16, (char*)Klds + off);
      }
#pragma unroll
      for (int i = 0; i < 4; ++i) {
        const int off = w * 4096 + i * 1024;
        gload16(vg + off + l * 16, (char*)Vlds + off);
      }
      asm volatile("s_waitcnt vmcnt(0)" ::: "memory");
      __syncthreads();
    }
    float rt[2][2];
#pragma unroll
    for (int u = 0; u < 2; ++u) {
      rt[u][0] = rtab[qr[u] + 63 - 2 * t] - 12.0f;
      rt[u][1] = rtab[qr[u] + 62 - 2 * t] - 12.0f;
    }
    const int swz = (ln & 7) << 3;
#pragma unroll
    for (int kc32 = 0; kc32 < 3; ++kc32) {
      float e[2][2][4];
#pragma unroll
      for (int kh = 0; kh < 2; ++kh) {
        const int kt = kc32 * 2 + kh;
        const int rb = (kt * 16 + ln) * 64;
        short8 kf0 = *(const short8*)&Klds[rb + ((g * 8) ^ swz)];
        short8 kf1 = *(const short8*)&Klds[rb + ((32 + g * 8) ^ swz)];
        const int m = kt % 3, wrap = kt / 3;
#pragma unroll
        for (int u = 0; u < 2; ++u) {
          floatx4 s = {0.f, 0.f, 0.f, 0.f};
          s = __builtin_amdgcn_mfma_f32_16x16x32_bf16(kf0, qf[u][0], s, 0, 0, 0);
          s = __builtin_amdgcn_mfma_f32_16x16x32_bf16(kf1, qf[u][1], s, 0, 0, 0);
          const float rtw = rt[u][wrap];
#pragma unroll
          for (int r = 0; r < 4; ++r)
            e[u][kh][r] = __builtin_amdgcn_exp2f(s[r] + rtw + ctr[u][m][r]);
        }
      }
      short8 pf[2];
#pragma unroll
      for (int u = 0; u < 2; ++u) {
        union { unsigned uu[4]; short8 v; } pk;
        pk.uu[0] = pack2bf(e[u][0][0], e[u][0][1]);
        pk.uu[1] = pack2bf(e[u][0][2], e[u][0][3]);
        pk.uu[2] = pack2bf(e[u][1][0], e[u][1][1]);
        pk.uu[3] = pack2bf(e[u][1][2], e[u][1][3]);
        pf[u] = pk.v;
      }
#pragma unroll
      for (int dt = 0; dt < 4; ++dt) {
        const int vrow = dt * 16 + ln;
        short8 vf = *(const short8*)&Vlds[vrow * 128 +
                                          ((kc32 * 32 + g * 8) ^ swz)];
        o_acc[0][dt] =
            __builtin_amdgcn_mfma_f32_16x16x32_bf16(pf[0], vf, o_acc[0][dt], 0, 0, 0);
        o_acc[1][dt] =
            __builtin_amdgcn_mfma_f32_16x16x32_bf16(pf[1], vf, o_acc[1][dt], 0, 0, 0);
      }
      o5[0] = __builtin_amdgcn_mfma_f32_16x16x32_bf16(pf[0], ones, o5[0], 0, 0, 0);
      o5[1] = __builtin_amdgcn_mfma_f32_16x16x32_bf16(pf[1], ones, o5[1], 0, 0, 0);
    }
  }
  const size_t rowbase = (size_t)(sp * 16 + bh) * S_TOK;
#pragma unroll
  for (int u = 0; u < 2; ++u) {
    if (ln == 0) {
#pragma unroll
      for (int r = 0; r < 4; ++r)
        Lpart[rowbase + q0 + u * 16 + g * 4 + r] = o5[u][r];
    }
#pragma unroll
    for (int dt = 0; dt < 4; ++dt)
#pragma unroll
      for (int r = 0; r < 4; ++r)
        Opart[(rowbase + q0 + u * 16 + g * 4 + r) * 64 + dt * 16 + ln] =
            o_acc[u][dt][r];
  }
}

// ------- Pass C: output GEMM (plain bf16) with FUSED split-K combine --------
// A[m][k=bh*64+d] = (sum_s Opart_s) / (sum_s L_s), converted to bf16 in-stage.
// B = woh (pre-swizzled [n][512]). Out f32 [6144][512].
template <int NS>
__global__ __launch_bounds__(256, 2) void ga_outmm(
    const float* __restrict__ Opart, const float* __restrict__ Lpart,
    const unsigned short* __restrict__ Bh_, float* __restrict__ Out) {
  const int tid = threadIdx.x;
  const int w = tid >> 6, l = tid & 63;
  const int g = l >> 4, ln = l & 15;
  const int wm = w >> 1, wn = w & 1;
  const int m0 = blockIdx.x * 64;
  const int n0 = blockIdx.y * 64;
  __shared__ unsigned short Alds[64 * 64];
  __shared__ unsigned short Blds[64 * 64];
  floatx4 acc[2][2];
#pragma unroll
  for (int mi = 0; mi < 2; ++mi)
#pragma unroll
    for (int ni = 0; ni < 2; ++ni)
#pragma unroll
      for (int r = 0; r < 4; ++r) acc[mi][ni][r] = 0.f;

  const int lm = tid >> 2, lk4 = tid & 3;
  const int m = m0 + lm;
  const int b = (m >= S_TOK) ? 1 : 0;
  const int q = m - b * S_TOK;

  for (int h = 0; h < 8; ++h) {
    __syncthreads();
    // B stage via gload16 (8KB)
    {
      const char* gb = (const char*)(Bh_ + (size_t)n0 * 512 + h * 64);
#pragma unroll
      for (int i = 0; i < 2; ++i) {
        const int off = (w * 2 + i) * 1024;
        const int gbo = ((off >> 7) + (l >> 3)) * 1024 + (l & 7) * 16;
        gload16(gb + gbo, (char*)Blds + off);
      }
    }
    // A stage: combine NS splits + normalize + bf16, swizzled ds_write
    {
      const int bh = b * 8 + h;
      float v[16];
      float ls = 0.f;
#pragma unroll
      for (int s = 0; s < NS; ++s) {
        const size_t row = (size_t)(s * 16 + bh) * S_TOK + q;
        ls += Lpart[row];
        const float* op = &Opart[row * 64 + lk4 * 16];
#pragma unroll
        for (int j = 0; j < 4; ++j) {
          float4 o = *(const float4*)(op + j * 4);
          if (s == 0) {
            v[j * 4] = o.x; v[j * 4 + 1] = o.y;
            v[j * 4 + 2] = o.z; v[j * 4 + 3] = o.w;
          } else {
            v[j * 4] += o.x; v[j * 4 + 1] += o.y;
            v[j * 4 + 2] += o.z; v[j * 4 + 3] += o.w;
          }
        }
      }
      const float inv = 1.0f / ls;
      unsigned pk[8];
#pragma unroll
      for (int j = 0; j < 8; ++j)
        pk[j] = pack2bf(v[2 * j] * inv, v[2 * j + 1] * inv);
      const int sw = (lm & 7) << 3;
      unsigned short* ab = &Alds[lm * 64];
#pragma unroll
      for (int j = 0; j < 4; ++j)
        *(uint2*)&ab[(lk4 * 16 + j * 4) ^ sw] = make_uint2(pk[2 * j], pk[2 * j + 1]);
    }
    asm volatile("s_waitcnt vmcnt(0)" ::: "memory");
    __syncthreads();
#pragma unroll
    for (int kk = 0; kk < 64; kk += 32) {
      const int kbase = kk + g * 8;
      short8 af[2], bf[2];
#pragma unroll
      for (int mi = 0; mi < 2; ++mi) {
        const int row = wm * 32 + mi * 16 + ln;
        af[mi] = *(const short8*)&Alds[row * 64 + (kbase ^ ((row & 7) << 3))];
      }
#pragma unroll
      for (int ni = 0; ni < 2; ++ni) {
        const int row = wn * 32 + ni * 16 + ln;
        bf[ni] = *(const short8*)&Blds[row * 64 + (kbase ^ ((row & 7) << 3))];
      }
#pragma unroll
      for (int mi = 0; mi < 2; ++mi)
#pragma unroll
        for (int ni = 0; ni < 2; ++ni)
          acc[mi][ni] = __builtin_amdgcn_mfma_f32_16x16x32_bf16(
              af[mi], bf[ni], acc[mi][ni], 0, 0, 0);
    }
  }
#pragma unroll
  for (int mi = 0; mi < 2; ++mi)
#pragma unroll
    for (int ni = 0; ni < 2; ++ni)
#pragma unroll
      for (int r = 0; r < 4; ++r)
        Out[(size_t)(m0 + wm * 32 + mi * 16 + g * 4 + r) * 512 + n0 +
            wn * 32 + ni * 16 + ln] = acc[mi][ni][r];
}

extern "C" void kernel_launch(void* const* d_in, const int* in_sizes, int n_in,
                              void* d_out, int out_size, void* d_ws,
                              size_t ws_size, hipStream_t stream) {
  const float* x = (const float*)d_in[0];       // [2,64,48,512]
  const float* w_qkv = (const float*)d_in[1];   // [512,1536]
  const float* w_out = (const float*)d_in[2];   // [512,512]
  const float* rrow = (const float*)d_in[3];    // [127,8]
  const float* rcol = (const float*)d_in[4];    // [95,8]
  float* out = (float*)d_out;                   // [6144,512]

  unsigned short* ws16 = (unsigned short*)d_ws;
  unsigned short* xh = ws16;                    // 3145728
  unsigned short* xl = xh + 3145728;            // 3145728
  unsigned short* wqh = xl + 3145728;           // 786432
  unsigned short* wql = wqh + 786432;
  unsigned short* woh = wql + 786432;           // 262144
  unsigned short* wol = woh + 262144;
  unsigned short* Qb = wol + 262144;            // 3145728
  unsigned short* Kb = Qb + 3145728;
  unsigned short* Vb = Kb + 3145728;
  unsigned short* Vt2 = Vb + 3145728;           // 4194304
  float* Opart = (float*)(Vt2 + 4194304);
  const size_t base_bytes = (size_t)22020096 * 2;
  const size_t per_split = (size_t)(3145728 + 49152) * 4;
  const int nsplit = (ws_size >= base_bytes + 2 * per_split) ? 2 : 1;
  float* Lpart = Opart + (size_t)nsplit * 3145728;

  ga_conv_all<<<1792, 256, 0, stream>>>(x, w_qkv, w_out, xh, xl, wqh, wql, woh,
                                        wol);
  ga_mm3<128, 128><<<dim3(48, 12), 256, 0, stream>>>(
      xh, xl, wqh, wql, Qb, Kb, Vb);
  ga_vtrans<<<dim3(32, 16), 256, 0, stream>>>(Vb, Vt2);
  ga_attn16<<<dim3(24, 16, nsplit), 256, 0, stream>>>(
      Qb, Kb, Vt2, rrow, rcol, Opart, Lpart, 32 / nsplit);
  if (nsplit == 2)
    ga_outmm<2><<<dim3(96, 8), 256, 0, stream>>>(Opart, Lpart, woh, out);
  else
    ga_outmm<1><<<dim3(96, 8), 256, 0, stream>>>(Opart, Lpart, woh, out);
}

// Round 12
// 126.146 us; speedup vs baseline: 1.5646x; 1.0392x over previous
//
#include <hip/hip_runtime.h>
#include <hip/hip_bf16.h>

#define S_TOK 3072   // 64*48
#define NHEADS 8
#define KVT 12800    // u16 per KV tile: K 6144 ([96][64] swz) + V 6656 ([64][104])

typedef __attribute__((ext_vector_type(8))) short short8;
typedef __attribute__((ext_vector_type(4))) float floatx4;
typedef __attribute__((ext_vector_type(4))) unsigned short ushortx4;

__device__ __forceinline__ unsigned short f2bf(float f) {
  union { float f; unsigned u; } v; v.f = f;
  unsigned r = v.u + 0x7fffu + ((v.u >> 16) & 1u);   // RTN-even
  return (unsigned short)(r >> 16);
}
__device__ __forceinline__ float bf2f(unsigned short h) {
  union { unsigned u; float f; } v; v.u = (unsigned)h << 16;
  return v.f;
}
__device__ __forceinline__ unsigned pack2bf(float a, float b) {
  __hip_bfloat162 h = __float22bfloat162_rn(make_float2(a, b));
  union { __hip_bfloat162 h; unsigned u; } c; c.h = h;
  return c.u;
}
__device__ __forceinline__ void gload16(const void* g, void* l) {
  __builtin_amdgcn_global_load_lds(
      (const __attribute__((address_space(1))) unsigned int*)g,
      (__attribute__((address_space(3))) unsigned int*)l, 16, 0, 0);
}

// ---- merged converter: X hi/lo (blocks 0..1535), w_qkv^T (1536..1727),
// w_out^T (1728..1791); all outputs pre-swizzled for gload_lds staging ----
__global__ __launch_bounds__(256) void ga_conv_all(
    const float* __restrict__ X, const float* __restrict__ Wq,
    const float* __restrict__ Wo, unsigned short* __restrict__ xh,
    unsigned short* __restrict__ xl, unsigned short* __restrict__ wqh,
    unsigned short* __restrict__ wql, unsigned short* __restrict__ woh,
    unsigned short* __restrict__ wol) {
  const int blk = blockIdx.x;
  const int t = threadIdx.x;
  if (blk < 1536) {
    const int c = blk * 256 + t;
    const int m = c >> 6;
    const int c8 = (c & 63) << 3;
    const float* src = X + (size_t)m * 512 + c8;
    float4 v0 = *(const float4*)src, v1 = *(const float4*)(src + 4);
    float vv[8] = {v0.x, v0.y, v0.z, v0.w, v1.x, v1.y, v1.z, v1.w};
    union { unsigned short s[8]; short8 v; } hh, ll;
#pragma unroll
    for (int e = 0; e < 8; ++e) {
      hh.s[e] = f2bf(vv[e]);
      ll.s[e] = f2bf(vv[e] - bf2f(hh.s[e]));
    }
    const size_t dst = (size_t)m * 512 + (c8 ^ ((m & 7) << 3));
    *(short8*)&xh[dst] = hh.v;
    *(short8*)&xl[dst] = ll.v;
    return;
  }
  const int wq = (blk < 1728);
  const int b2 = wq ? (blk - 1536) : (blk - 1728);
  const int N = wq ? 1536 : 512;
  const float* W = wq ? Wq : Wo;
  unsigned short* th = wq ? wqh : woh;
  unsigned short* tl = wq ? wql : wol;
  const int k0 = (b2 & 7) * 64, n0 = (b2 >> 3) * 64;
  __shared__ float Ts[64][65];
#pragma unroll
  for (int i = 0; i < 4; ++i) {
    const int r = (t >> 4) + i * 16, c4 = (t & 15) * 4;
    float4 v = *(const float4*)&W[(size_t)(k0 + r) * N + n0 + c4];
    Ts[r][c4] = v.x; Ts[r][c4 + 1] = v.y; Ts[r][c4 + 2] = v.z; Ts[r][c4 + 3] = v.w;
  }
  __syncthreads();
#pragma unroll
  for (int j = 0; j < 2; ++j) {
    const int chunk = t * 2 + j;
    const int nl = chunk >> 3, m8 = chunk & 7;
    const int n = n0 + nl;
    const int ks = (m8 * 8) ^ ((n & 7) << 3);
    union { unsigned short s[8]; short8 v; } hh, ll;
#pragma unroll
    for (int e = 0; e < 8; ++e) {
      float f = Ts[ks + e][nl];
      hh.s[e] = f2bf(f);
      ll.s[e] = f2bf(f - bf2f(hh.s[e]));
    }
    const size_t dst = (size_t)n * 512 + k0 + m8 * 8;
    *(short8*)&th[dst] = hh.v;
    *(short8*)&tl[dst] = ll.v;
  }
}

// ---- bf16x3 MFMA GEMM for QKV; K goes into tiled KV buffer ----
template <int BM, int BN>
__global__ __launch_bounds__(256, 2) void ga_mm3(
    const unsigned short* __restrict__ Ah, const unsigned short* __restrict__ Al,
    const unsigned short* __restrict__ Bh, const unsigned short* __restrict__ Bl,
    unsigned short* __restrict__ Qd, unsigned short* __restrict__ KV,
    unsigned short* __restrict__ Vd) {
  const int tid = threadIdx.x;
  const int w = tid >> 6, l = tid & 63;
  const int g = l >> 4, ln = l & 15;
  const int wm = w >> 1, wn = w & 1;
  const int m0 = blockIdx.x * BM;
  const int n0 = blockIdx.y * BN;
  constexpr int MI = BM / 32;
  constexpr int NI = BN / 32;
  __shared__ unsigned short Alds[2][BM * 64];
  __shared__ unsigned short Blds[2][BN * 64];
  floatx4 acc[MI][NI];
#pragma unroll
  for (int mi = 0; mi < MI; ++mi)
#pragma unroll
    for (int ni = 0; ni < NI; ++ni)
#pragma unroll
      for (int r = 0; r < 4; ++r) acc[mi][ni][r] = 0.f;

  for (int k0 = 0; k0 < 512; k0 += 64) {
    __syncthreads();
    {
      constexpr int PWA = (BM * 128) / 4096;
      constexpr int PWB = (BN * 128) / 4096;
      const char* ga_h = (const char*)(Ah + (size_t)m0 * 512 + k0);
      const char* ga_l = (const char*)(Al + (size_t)m0 * 512 + k0);
      const char* gb_h = (const char*)(Bh + (size_t)n0 * 512 + k0);
      const char* gb_l = (const char*)(Bl + (size_t)n0 * 512 + k0);
#pragma unroll
      for (int i = 0; i < PWA; ++i) {
        const int off = (w * PWA + i) * 1024;
        const int gb = ((off >> 7) + (l >> 3)) * 1024 + (l & 7) * 16;
        gload16(ga_h + gb, (char*)&Alds[0][0] + off);
        gload16(ga_l + gb, (char*)&Alds[1][0] + off);
      }
#pragma unroll
      for (int i = 0; i < PWB; ++i) {
        const int off = (w * PWB + i) * 1024;
        const int gb = ((off >> 7) + (l >> 3)) * 1024 + (l & 7) * 16;
        gload16(gb_h + gb, (char*)&Blds[0][0] + off);
        gload16(gb_l + gb, (char*)&Blds[1][0] + off);
      }
    }
    asm volatile("s_waitcnt vmcnt(0)" ::: "memory");
    __syncthreads();
#pragma unroll
    for (int kk = 0; kk < 64; kk += 32) {
      const int kbase = kk + g * 8;
      short8 ah[MI], al[MI], bh[NI], bl[NI];
#pragma unroll
      for (int mi = 0; mi < MI; ++mi) {
        const int row = wm * (BM / 2) + mi * 16 + ln;
        const int a = row * 64 + (kbase ^ ((row & 7) << 3));
        ah[mi] = *(const short8*)&Alds[0][a];
        al[mi] = *(const short8*)&Alds[1][a];
      }
#pragma unroll
      for (int ni = 0; ni < NI; ++ni) {
        const int row = wn * (BN / 2) + ni * 16 + ln;
        const int a = row * 64 + (kbase ^ ((row & 7) << 3));
        bh[ni] = *(const short8*)&Blds[0][a];
        bl[ni] = *(const short8*)&Blds[1][a];
      }
#pragma unroll
      for (int mi = 0; mi < MI; ++mi)
#pragma unroll
        for (int ni = 0; ni < NI; ++ni) {
          acc[mi][ni] = __builtin_amdgcn_mfma_f32_16x16x32_bf16(
              ah[mi], bh[ni], acc[mi][ni], 0, 0, 0);
          acc[mi][ni] = __builtin_amdgcn_mfma_f32_16x16x32_bf16(
              al[mi], bh[ni], acc[mi][ni], 0, 0, 0);
          acc[mi][ni] = __builtin_amdgcn_mfma_f32_16x16x32_bf16(
              ah[mi], bl[ni], acc[mi][ni], 0, 0, 0);
        }
    }
  }
  // QKV scatter epilogue
  const int b = m0 / S_TOK;
  const int s_base = (m0 % S_TOK) + wm * (BM / 2);
#pragma unroll
  for (int ni = 0; ni < NI; ++ni) {
    const int ng = n0 + wn * (BN / 2) + ni * 16;
    const int which = ng >> 9;
    const int h = (ng >> 6) & 7;
    const int d = (ng & 63) + ln;
    const int bh = b * 8 + h;
    const float qs = (which == 0) ? 0.18033688f : 1.0f;  // 1/8*log2e
    if (which == 1) {
      unsigned short* kp = KV + (size_t)bh * 32 * KVT;
#pragma unroll
      for (int mi = 0; mi < MI; ++mi)
#pragma unroll
        for (int r = 0; r < 4; ++r) {
          const int s = s_base + mi * 16 + g * 4 + r;
          const int tile = s / 96;
          const int r96 = s - tile * 96;
          kp[tile * KVT + r96 * 64 + (d ^ ((s & 7) << 3))] =
              f2bf(acc[mi][ni][r]);
        }
    } else {
      unsigned short* hp =
          (which == 0 ? Qd : Vd) + (size_t)bh * S_TOK * 64;
#pragma unroll
      for (int mi = 0; mi < MI; ++mi)
#pragma unroll
        for (int r = 0; r < 4; ++r) {
          const int s = s_base + mi * 16 + g * 4 + r;
          hp[(size_t)s * 64 + d] = f2bf(acc[mi][ni][r] * qs);
        }
    }
  }
}

// ---- Pass A2: V -> KV V-region [64 d][104 k], key-permuted (lane-local P) ----
// stored pos p (0..95) <-> actual key (p>>5)*32 + ((p>>2)&1)*16 + ((p>>3)&3)*4 + (p&3)
__global__ __launch_bounds__(256) void ga_vtrans(
    const unsigned short* __restrict__ V, unsigned short* __restrict__ KV) {
  const int t = threadIdx.x;
  const int tile = blockIdx.x;
  const int bh = blockIdx.y;
  __shared__ unsigned short Ts[96][72];
  const unsigned short* vp = V + ((size_t)bh * S_TOK + tile * 96) * 64;
#pragma unroll
  for (int it = 0; it < 3; ++it) {
    int c = it * 256 + t;
    int s = c >> 3, d8 = c & 7;
    short8 v = *(const short8*)&vp[(size_t)s * 64 + d8 * 8];
    *(short8*)&Ts[s][d8 * 8] = v;
  }
  __syncthreads();
  unsigned short* op = KV + ((size_t)bh * 32 + tile) * KVT + 6144;
#pragma unroll
  for (int it = 0; it < 4; ++it) {
    int c2 = it * 256 + t;           // 832 chunks of 8 u16 (64 d x 13)
    if (c2 < 832) {
      const int d = c2 / 13;
      const int kc8 = (c2 - d * 13) * 8;
      short8 o;
      if (kc8 < 96) {
#pragma unroll
        for (int j = 0; j < 8; ++j) {
          const int p = kc8 + j;
          const int key =
              (p >> 5) * 32 + ((p >> 2) & 1) * 16 + ((p >> 3) & 3) * 4 + (p & 3);
          o[j] = (short)Ts[key][d];
        }
      } else {
#pragma unroll
        for (int j = 0; j < 8; ++j) o[j] = 0;
      }
      *(short8*)&op[d * 104 + kc8] = o;
    }
  }
}

// ------- Pass B: attention; DOUBLE-BUFFERED KV staging (counted overlap) -----
__global__ __launch_bounds__(256) void ga_attn16(
    const unsigned short* __restrict__ Q, const unsigned short* __restrict__ KVg,
    const float* __restrict__ rowtab, const float* __restrict__ coltab,
    float* __restrict__ Opart, float* __restrict__ Lpart,
    int tiles_per_split) {
  const int tid = threadIdx.x;
  const int w = tid >> 6;
  const int l = tid & 63;
  const int g = l >> 4;
  const int ln = l & 15;
  const int bh = blockIdx.y;
  const int sp = blockIdx.z;
  const int h = bh & 7;
  const int q0 = blockIdx.x * 128 + w * 32;

  __shared__ float rtab[127];
  __shared__ float ctab[95];
  __shared__ unsigned short KVlds[2][KVT];   // 2 x 25600 B
  for (int i = tid; i < 127; i += 256) rtab[i] = rowtab[i * 8 + h] * 1.44269504f;
  for (int i = tid; i < 95; i += 256) ctab[i] = coltab[i * 8 + h] * 1.44269504f;

  const unsigned short* Qp = Q + (size_t)bh * S_TOK * 64;
  const unsigned short* KVp = KVg + (size_t)bh * 32 * KVT;

  const int t0 = sp * tiles_per_split;
  const int tend = t0 + tiles_per_split;

  auto STAGE = [&](int b, int t) {
    const char* src = (const char*)(KVp + (size_t)t * KVT);
    char* dst = (char*)&KVlds[b][0];
#pragma unroll
    for (int i = 0; i < 6; ++i)
      gload16(src + i * 4096 + tid * 16, dst + i * 4096 + tid * 16);
    if (tid < 64) gload16(src + 24576 + tid * 16, dst + 24576 + tid * 16);
  };

  STAGE(0, t0);
  asm volatile("s_waitcnt vmcnt(0)" ::: "memory");
  __syncthreads();

  int qr[2], qc[2];
  short8 qf[2][2];
  float ctr[2][3][4];
#pragma unroll
  for (int u = 0; u < 2; ++u) {
    const int q = q0 + u * 16 + ln;
    qr[u] = q / 48;
    qc[u] = q - qr[u] * 48;
    qf[u][0] = *(const short8*)&Qp[(size_t)q * 64 + g * 8];
    qf[u][1] = *(const short8*)&Qp[(size_t)q * 64 + 32 + g * 8];
    const float* cb = &ctab[qc[u] - g * 4 + 47];
#pragma unroll
    for (int m = 0; m < 3; ++m)
#pragma unroll
      for (int r = 0; r < 4; ++r) ctr[u][m][r] = cb[-(16 * m + r)];
  }

  short8 ones;
  {
    union { unsigned short s[8]; short8 v; } on;
#pragma unroll
    for (int j = 0; j < 8; ++j) on.s[j] = 0x3F80;  // bf16 1.0
    ones = on.v;
  }

  floatx4 o_acc[2][4];
  floatx4 o5[2];
#pragma unroll
  for (int u = 0; u < 2; ++u) {
#pragma unroll
    for (int r = 0; r < 4; ++r) o5[u][r] = 0.f;
#pragma unroll
    for (int dt = 0; dt < 4; ++dt)
#pragma unroll
      for (int r = 0; r < 4; ++r) o_acc[u][dt][r] = 0.f;
  }

  int cur = 0;
  for (int t = t0; t < tend; ++t) {
    if (t + 1 < tend) STAGE(cur ^ 1, t + 1);   // loads fly under compute
    const unsigned short* kb = &KVlds[cur][0];
    const unsigned short* vb = &KVlds[cur][6144];
    float rt[2][2];
#pragma unroll
    for (int u = 0; u < 2; ++u) {
      rt[u][0] = rtab[qr[u] + 63 - 2 * t] - 12.0f;
      rt[u][1] = rtab[qr[u] + 62 - 2 * t] - 12.0f;
    }
    const int swz = (ln & 7) << 3;
#pragma unroll
    for (int kc32 = 0; kc32 < 3; ++kc32) {
      float e[2][2][4];
#pragma unroll
      for (int kh = 0; kh < 2; ++kh) {
        const int kt = kc32 * 2 + kh;
        const int rb = (kt * 16 + ln) * 64;
        short8 kf0 = *(const short8*)&kb[rb + ((g * 8) ^ swz)];
        short8 kf1 = *(const short8*)&kb[rb + ((32 + g * 8) ^ swz)];
        const int m = kt % 3, wrap = kt / 3;
#pragma unroll
        for (int u = 0; u < 2; ++u) {
          floatx4 s = {0.f, 0.f, 0.f, 0.f};
          s = __builtin_amdgcn_mfma_f32_16x16x32_bf16(kf0, qf[u][0], s, 0, 0, 0);
          s = __builtin_amdgcn_mfma_f32_16x16x32_bf16(kf1, qf[u][1], s, 0, 0, 0);
          const float rtw = rt[u][wrap];
#pragma unroll
          for (int r = 0; r < 4; ++r)
            e[u][kh][r] = __builtin_amdgcn_exp2f(s[r] + rtw + ctr[u][m][r]);
        }
      }
      short8 pf[2];
#pragma unroll
      for (int u = 0; u < 2; ++u) {
        union { unsigned uu[4]; short8 v; } pk;
        pk.uu[0] = pack2bf(e[u][0][0], e[u][0][1]);
        pk.uu[1] = pack2bf(e[u][0][2], e[u][0][3]);
        pk.uu[2] = pack2bf(e[u][1][0], e[u][1][1]);
        pk.uu[3] = pack2bf(e[u][1][2], e[u][1][3]);
        pf[u] = pk.v;
      }
#pragma unroll
      for (int dt = 0; dt < 4; ++dt) {
        const int vrow = dt * 16 + ln;
        short8 vf = *(const short8*)&vb[vrow * 104 + kc32 * 32 + g * 8];
        o_acc[0][dt] =
            __builtin_amdgcn_mfma_f32_16x16x32_bf16(pf[0], vf, o_acc[0][dt], 0, 0, 0);
        o_acc[1][dt] =
            __builtin_amdgcn_mfma_f32_16x16x32_bf16(pf[1], vf, o_acc[1][dt], 0, 0, 0);
      }
      o5[0] = __builtin_amdgcn_mfma_f32_16x16x32_bf16(pf[0], ones, o5[0], 0, 0, 0);
      o5[1] = __builtin_amdgcn_mfma_f32_16x16x32_bf16(pf[1], ones, o5[1], 0, 0, 0);
    }
    asm volatile("s_waitcnt vmcnt(0)" ::: "memory");  // my stage loads landed
    __syncthreads();            // everyone's landed; everyone done reading cur
    cur ^= 1;
  }
  const size_t rowbase = (size_t)(sp * 16 + bh) * S_TOK;
#pragma unroll
  for (int u = 0; u < 2; ++u) {
    if (ln == 0) {
#pragma unroll
      for (int r = 0; r < 4; ++r)
        Lpart[rowbase + q0 + u * 16 + g * 4 + r] = o5[u][r];
    }
#pragma unroll
    for (int dt = 0; dt < 4; ++dt)
#pragma unroll
      for (int r = 0; r < 4; ++r)
        Opart[(rowbase + q0 + u * 16 + g * 4 + r) * 64 + dt * 16 + ln] =
            o_acc[u][dt][r];
  }
}

// ------- Pass C: output GEMM (plain bf16) with FUSED split-K combine --------
template <int NS>
__global__ __launch_bounds__(256, 2) void ga_outmm(
    const float* __restrict__ Opart, const float* __restrict__ Lpart,
    const unsigned short* __restrict__ Bh_, float* __restrict__ Out) {
  const int tid = threadIdx.x;
  const int w = tid >> 6, l = tid & 63;
  const int g = l >> 4, ln = l & 15;
  const int wm = w >> 1, wn = w & 1;
  const int m0 = blockIdx.x * 64;
  const int n0 = blockIdx.y * 64;
  __shared__ unsigned short Alds[64 * 64];
  __shared__ unsigned short Blds[64 * 64];
  floatx4 acc[2][2];
#pragma unroll
  for (int mi = 0; mi < 2; ++mi)
#pragma unroll
    for (int ni = 0; ni < 2; ++ni)
#pragma unroll
      for (int r = 0; r < 4; ++r) acc[mi][ni][r] = 0.f;

  const int lm = tid >> 2, lk4 = tid & 3;
  const int m = m0 + lm;
  const int b = (m >= S_TOK) ? 1 : 0;
  const int q = m - b * S_TOK;

  for (int h = 0; h < 8; ++h) {
    __syncthreads();
    {
      const char* gb = (const char*)(Bh_ + (size_t)n0 * 512 + h * 64);
#pragma unroll
      for (int i = 0; i < 2; ++i) {
        const int off = (w * 2 + i) * 1024;
        const int gbo = ((off >> 7) + (l >> 3)) * 1024 + (l & 7) * 16;
        gload16(gb + gbo, (char*)Blds + off);
      }
    }
    {
      const int bh = b * 8 + h;
      float v[16];
      float ls = 0.f;
#pragma unroll
      for (int s = 0; s < NS; ++s) {
        const size_t row = (size_t)(s * 16 + bh) * S_TOK + q;
        ls += Lpart[row];
        const float* op = &Opart[row * 64 + lk4 * 16];
#pragma unroll
        for (int j = 0; j < 4; ++j) {
          float4 o = *(const float4*)(op + j * 4);
          if (s == 0) {
            v[j * 4] = o.x; v[j * 4 + 1] = o.y;
            v[j * 4 + 2] = o.z; v[j * 4 + 3] = o.w;
          } else {
            v[j * 4] += o.x; v[j * 4 + 1] += o.y;
            v[j * 4 + 2] += o.z; v[j * 4 + 3] += o.w;
          }
        }
      }
      const float inv = 1.0f / ls;
      unsigned pk[8];
#pragma unroll
      for (int j = 0; j < 8; ++j)
        pk[j] = pack2bf(v[2 * j] * inv, v[2 * j + 1] * inv);
      const int sw = (lm & 7) << 3;
      unsigned short* ab = &Alds[lm * 64];
#pragma unroll
      for (int j = 0; j < 4; ++j)
        *(uint2*)&ab[(lk4 * 16 + j * 4) ^ sw] = make_uint2(pk[2 * j], pk[2 * j + 1]);
    }
    asm volatile("s_waitcnt vmcnt(0)" ::: "memory");
    __syncthreads();
#pragma unroll
    for (int kk = 0; kk < 64; kk += 32) {
      const int kbase = kk + g * 8;
      short8 af[2], bf[2];
#pragma unroll
      for (int mi = 0; mi < 2; ++mi) {
        const int row = wm * 32 + mi * 16 + ln;
        af[mi] = *(const short8*)&Alds[row * 64 + (kbase ^ ((row & 7) << 3))];
      }
#pragma unroll
      for (int ni = 0; ni < 2; ++ni) {
        const int row = wn * 32 + ni * 16 + ln;
        bf[ni] = *(const short8*)&Blds[row * 64 + (kbase ^ ((row & 7) << 3))];
      }
#pragma unroll
      for (int mi = 0; mi < 2; ++mi)
#pragma unroll
        for (int ni = 0; ni < 2; ++ni)
          acc[mi][ni] = __builtin_amdgcn_mfma_f32_16x16x32_bf16(
              af[mi], bf[ni], acc[mi][ni], 0, 0, 0);
    }
  }
#pragma unroll
  for (int mi = 0; mi < 2; ++mi)
#pragma unroll
    for (int ni = 0; ni < 2; ++ni)
#pragma unroll
      for (int r = 0; r < 4; ++r)
        Out[(size_t)(m0 + wm * 32 + mi * 16 + g * 4 + r) * 512 + n0 +
            wn * 32 + ni * 16 + ln] = acc[mi][ni][r];
}

extern "C" void kernel_launch(void* const* d_in, const int* in_sizes, int n_in,
                              void* d_out, int out_size, void* d_ws,
                              size_t ws_size, hipStream_t stream) {
  const float* x = (const float*)d_in[0];       // [2,64,48,512]
  const float* w_qkv = (const float*)d_in[1];   // [512,1536]
  const float* w_out = (const float*)d_in[2];   // [512,512]
  const float* rrow = (const float*)d_in[3];    // [127,8]
  const float* rcol = (const float*)d_in[4];    // [95,8]
  float* out = (float*)d_out;                   // [6144,512]

  unsigned short* ws16 = (unsigned short*)d_ws;
  unsigned short* xh = ws16;                    // 3145728
  unsigned short* xl = xh + 3145728;            // 3145728
  unsigned short* wqh = xl + 3145728;           // 786432
  unsigned short* wql = wqh + 786432;
  unsigned short* woh = wql + 786432;           // 262144
  unsigned short* wol = woh + 262144;
  unsigned short* Qb = wol + 262144;            // 3145728
  unsigned short* Vb = Qb + 3145728;            // 3145728
  unsigned short* KV = Vb + 3145728;            // 16*32*12800 = 6553600
  float* Opart = (float*)(KV + 6553600);
  const size_t base_bytes =
      ((size_t)3145728 * 4 + 786432 * 2 + 262144 * 2 + 6553600) * 2;
  const size_t per_split = (size_t)(3145728 + 49152) * 4;
  const int nsplit = (ws_size >= base_bytes + 2 * per_split) ? 2 : 1;
  float* Lpart = Opart + (size_t)nsplit * 3145728;

  ga_conv_all<<<1792, 256, 0, stream>>>(x, w_qkv, w_out, xh, xl, wqh, wql, woh,
                                        wol);
  ga_mm3<128, 128><<<dim3(48, 12), 256, 0, stream>>>(
      xh, xl, wqh, wql, Qb, KV, Vb);
  ga_vtrans<<<dim3(32, 16), 256, 0, stream>>>(Vb, KV);
  ga_attn16<<<dim3(24, 16, nsplit), 256, 0, stream>>>(
      Qb, KV, rrow, rcol, Opart, Lpart, 32 / nsplit);
  if (nsplit == 2)
    ga_outmm<2><<<dim3(96, 8), 256, 0, stream>>>(Opart, Lpart, woh, out);
  else
    ga_outmm<1><<<dim3(96, 8), 256, 0, stream>>>(Opart, Lpart, woh, out);
}

// Round 13
// 124.232 us; speedup vs baseline: 1.5887x; 1.0154x over previous
//
#include <hip/hip_runtime.h>
#include <hip/hip_bf16.h>

#define S_TOK 3072   // 64*48
#define NHEADS 8
#define KVT 12800    // u16 per KV tile: K 6144 ([96][64] swz) + V 6656 ([64][104])

typedef __attribute__((ext_vector_type(8))) short short8;
typedef __attribute__((ext_vector_type(4))) float floatx4;
typedef __attribute__((ext_vector_type(4))) unsigned short ushortx4;

__device__ __forceinline__ unsigned short f2bf(float f) {
  union { float f; unsigned u; } v; v.f = f;
  unsigned r = v.u + 0x7fffu + ((v.u >> 16) & 1u);   // RTN-even
  return (unsigned short)(r >> 16);
}
__device__ __forceinline__ float bf2f(unsigned short h) {
  union { unsigned u; float f; } v; v.u = (unsigned)h << 16;
  return v.f;
}
__device__ __forceinline__ unsigned pack2bf(float a, float b) {
  __hip_bfloat162 h = __float22bfloat162_rn(make_float2(a, b));
  union { __hip_bfloat162 h; unsigned u; } c; c.h = h;
  return c.u;
}
__device__ __forceinline__ void gload16(const void* g, void* l) {
  __builtin_amdgcn_global_load_lds(
      (const __attribute__((address_space(1))) unsigned int*)g,
      (__attribute__((address_space(3))) unsigned int*)l, 16, 0, 0);
}

// ---- merged converter: X hi/lo (blocks 0..1535), w_qkv^T (1536..1727),
// w_out^T (1728..1791); all outputs pre-swizzled for gload_lds staging ----
__global__ __launch_bounds__(256) void ga_conv_all(
    const float* __restrict__ X, const float* __restrict__ Wq,
    const float* __restrict__ Wo, unsigned short* __restrict__ xh,
    unsigned short* __restrict__ xl, unsigned short* __restrict__ wqh,
    unsigned short* __restrict__ wql, unsigned short* __restrict__ woh,
    unsigned short* __restrict__ wol) {
  const int blk = blockIdx.x;
  const int t = threadIdx.x;
  if (blk < 1536) {
    const int c = blk * 256 + t;
    const int m = c >> 6;
    const int c8 = (c & 63) << 3;
    const float* src = X + (size_t)m * 512 + c8;
    float4 v0 = *(const float4*)src, v1 = *(const float4*)(src + 4);
    float vv[8] = {v0.x, v0.y, v0.z, v0.w, v1.x, v1.y, v1.z, v1.w};
    union { unsigned short s[8]; short8 v; } hh, ll;
#pragma unroll
    for (int e = 0; e < 8; ++e) {
      hh.s[e] = f2bf(vv[e]);
      ll.s[e] = f2bf(vv[e] - bf2f(hh.s[e]));
    }
    const size_t dst = (size_t)m * 512 + (c8 ^ ((m & 7) << 3));
    *(short8*)&xh[dst] = hh.v;
    *(short8*)&xl[dst] = ll.v;
    return;
  }
  const int wq = (blk < 1728);
  const int b2 = wq ? (blk - 1536) : (blk - 1728);
  const int N = wq ? 1536 : 512;
  const float* W = wq ? Wq : Wo;
  unsigned short* th = wq ? wqh : woh;
  unsigned short* tl = wq ? wql : wol;
  const int k0 = (b2 & 7) * 64, n0 = (b2 >> 3) * 64;
  __shared__ float Ts[64][65];
#pragma unroll
  for (int i = 0; i < 4; ++i) {
    const int r = (t >> 4) + i * 16, c4 = (t & 15) * 4;
    float4 v = *(const float4*)&W[(size_t)(k0 + r) * N + n0 + c4];
    Ts[r][c4] = v.x; Ts[r][c4 + 1] = v.y; Ts[r][c4 + 2] = v.z; Ts[r][c4 + 3] = v.w;
  }
  __syncthreads();
#pragma unroll
  for (int j = 0; j < 2; ++j) {
    const int chunk = t * 2 + j;
    const int nl = chunk >> 3, m8 = chunk & 7;
    const int n = n0 + nl;
    const int ks = (m8 * 8) ^ ((n & 7) << 3);
    union { unsigned short s[8]; short8 v; } hh, ll;
#pragma unroll
    for (int e = 0; e < 8; ++e) {
      float f = Ts[ks + e][nl];
      hh.s[e] = f2bf(f);
      ll.s[e] = f2bf(f - bf2f(hh.s[e]));
    }
    const size_t dst = (size_t)n * 512 + k0 + m8 * 8;
    *(short8*)&th[dst] = hh.v;
    *(short8*)&tl[dst] = ll.v;
  }
}

// ---- bf16x3 MFMA GEMM for QKV; K goes into tiled KV buffer ----
template <int BM, int BN>
__global__ __launch_bounds__(256, 2) void ga_mm3(
    const unsigned short* __restrict__ Ah, const unsigned short* __restrict__ Al,
    const unsigned short* __restrict__ Bh, const unsigned short* __restrict__ Bl,
    unsigned short* __restrict__ Qd, unsigned short* __restrict__ KV,
    unsigned short* __restrict__ Vd) {
  const int tid = threadIdx.x;
  const int w = tid >> 6, l = tid & 63;
  const int g = l >> 4, ln = l & 15;
  const int wm = w >> 1, wn = w & 1;
  const int m0 = blockIdx.x * BM;
  const int n0 = blockIdx.y * BN;
  constexpr int MI = BM / 32;
  constexpr int NI = BN / 32;
  __shared__ unsigned short Alds[2][BM * 64];
  __shared__ unsigned short Blds[2][BN * 64];
  floatx4 acc[MI][NI];
#pragma unroll
  for (int mi = 0; mi < MI; ++mi)
#pragma unroll
    for (int ni = 0; ni < NI; ++ni)
#pragma unroll
      for (int r = 0; r < 4; ++r) acc[mi][ni][r] = 0.f;

  for (int k0 = 0; k0 < 512; k0 += 64) {
    __syncthreads();
    {
      constexpr int PWA = (BM * 128) / 4096;
      constexpr int PWB = (BN * 128) / 4096;
      const char* ga_h = (const char*)(Ah + (size_t)m0 * 512 + k0);
      const char* ga_l = (const char*)(Al + (size_t)m0 * 512 + k0);
      const char* gb_h = (const char*)(Bh + (size_t)n0 * 512 + k0);
      const char* gb_l = (const char*)(Bl + (size_t)n0 * 512 + k0);
#pragma unroll
      for (int i = 0; i < PWA; ++i) {
        const int off = (w * PWA + i) * 1024;
        const int gb = ((off >> 7) + (l >> 3)) * 1024 + (l & 7) * 16;
        gload16(ga_h + gb, (char*)&Alds[0][0] + off);
        gload16(ga_l + gb, (char*)&Alds[1][0] + off);
      }
#pragma unroll
      for (int i = 0; i < PWB; ++i) {
        const int off = (w * PWB + i) * 1024;
        const int gb = ((off >> 7) + (l >> 3)) * 1024 + (l & 7) * 16;
        gload16(gb_h + gb, (char*)&Blds[0][0] + off);
        gload16(gb_l + gb, (char*)&Blds[1][0] + off);
      }
    }
    asm volatile("s_waitcnt vmcnt(0)" ::: "memory");
    __syncthreads();
#pragma unroll
    for (int kk = 0; kk < 64; kk += 32) {
      const int kbase = kk + g * 8;
      short8 ah[MI], al[MI], bh[NI], bl[NI];
#pragma unroll
      for (int mi = 0; mi < MI; ++mi) {
        const int row = wm * (BM / 2) + mi * 16 + ln;
        const int a = row * 64 + (kbase ^ ((row & 7) << 3));
        ah[mi] = *(const short8*)&Alds[0][a];
        al[mi] = *(const short8*)&Alds[1][a];
      }
#pragma unroll
      for (int ni = 0; ni < NI; ++ni) {
        const int row = wn * (BN / 2) + ni * 16 + ln;
        const int a = row * 64 + (kbase ^ ((row & 7) << 3));
        bh[ni] = *(const short8*)&Blds[0][a];
        bl[ni] = *(const short8*)&Blds[1][a];
      }
#pragma unroll
      for (int mi = 0; mi < MI; ++mi)
#pragma unroll
        for (int ni = 0; ni < NI; ++ni) {
          acc[mi][ni] = __builtin_amdgcn_mfma_f32_16x16x32_bf16(
              ah[mi], bh[ni], acc[mi][ni], 0, 0, 0);
          acc[mi][ni] = __builtin_amdgcn_mfma_f32_16x16x32_bf16(
              al[mi], bh[ni], acc[mi][ni], 0, 0, 0);
          acc[mi][ni] = __builtin_amdgcn_mfma_f32_16x16x32_bf16(
              ah[mi], bl[ni], acc[mi][ni], 0, 0, 0);
        }
    }
  }
  // QKV scatter epilogue
  const int b = m0 / S_TOK;
  const int s_base = (m0 % S_TOK) + wm * (BM / 2);
#pragma unroll
  for (int ni = 0; ni < NI; ++ni) {
    const int ng = n0 + wn * (BN / 2) + ni * 16;
    const int which = ng >> 9;
    const int h = (ng >> 6) & 7;
    const int d = (ng & 63) + ln;
    const int bh = b * 8 + h;
    const float qs = (which == 0) ? 0.18033688f : 1.0f;  // 1/8*log2e
    if (which == 1) {
      unsigned short* kp = KV + (size_t)bh * 32 * KVT;
#pragma unroll
      for (int mi = 0; mi < MI; ++mi)
#pragma unroll
        for (int r = 0; r < 4; ++r) {
          const int s = s_base + mi * 16 + g * 4 + r;
          const int tile = s / 96;
          const int r96 = s - tile * 96;
          kp[tile * KVT + r96 * 64 + (d ^ ((s & 7) << 3))] =
              f2bf(acc[mi][ni][r]);
        }
    } else {
      unsigned short* hp =
          (which == 0 ? Qd : Vd) + (size_t)bh * S_TOK * 64;
#pragma unroll
      for (int mi = 0; mi < MI; ++mi)
#pragma unroll
        for (int r = 0; r < 4; ++r) {
          const int s = s_base + mi * 16 + g * 4 + r;
          hp[(size_t)s * 64 + d] = f2bf(acc[mi][ni][r] * qs);
        }
    }
  }
}

// ---- Pass A2: V -> KV V-region [64 d][104 k], key-permuted (lane-local P) ----
__global__ __launch_bounds__(256) void ga_vtrans(
    const unsigned short* __restrict__ V, unsigned short* __restrict__ KV) {
  const int t = threadIdx.x;
  const int tile = blockIdx.x;
  const int bh = blockIdx.y;
  __shared__ unsigned short Ts[96][72];
  const unsigned short* vp = V + ((size_t)bh * S_TOK + tile * 96) * 64;
#pragma unroll
  for (int it = 0; it < 3; ++it) {
    int c = it * 256 + t;
    int s = c >> 3, d8 = c & 7;
    short8 v = *(const short8*)&vp[(size_t)s * 64 + d8 * 8];
    *(short8*)&Ts[s][d8 * 8] = v;
  }
  __syncthreads();
  unsigned short* op = KV + ((size_t)bh * 32 + tile) * KVT + 6144;
#pragma unroll
  for (int it = 0; it < 4; ++it) {
    int c2 = it * 256 + t;           // 832 chunks of 8 u16 (64 d x 13)
    if (c2 < 832) {
      const int d = c2 / 13;
      const int kc8 = (c2 - d * 13) * 8;
      short8 o;
      if (kc8 < 96) {
#pragma unroll
        for (int j = 0; j < 8; ++j) {
          const int p = kc8 + j;
          const int key =
              (p >> 5) * 32 + ((p >> 2) & 1) * 16 + ((p >> 3) & 3) * 4 + (p & 3);
          o[j] = (short)Ts[key][d];
        }
      } else {
#pragma unroll
        for (int j = 0; j < 8; ++j) o[j] = 0;
      }
      *(short8*)&op[d * 104 + kc8] = o;
    }
  }
}

// ------- Pass B: attention; dbuf KV staging + bias folded into MFMA C -------
__global__ __launch_bounds__(256) void ga_attn16(
    const unsigned short* __restrict__ Q, const unsigned short* __restrict__ KVg,
    const float* __restrict__ rowtab, const float* __restrict__ coltab,
    float* __restrict__ Opart, float* __restrict__ Lpart,
    int tiles_per_split) {
  const int tid = threadIdx.x;
  const int w = tid >> 6;
  const int l = tid & 63;
  const int g = l >> 4;
  const int ln = l & 15;
  const int bh = blockIdx.y;
  const int sp = blockIdx.z;
  const int h = bh & 7;
  const int q0 = blockIdx.x * 128 + w * 32;

  __shared__ float rtab[127];
  __shared__ float ctab[95];
  __shared__ unsigned short KVlds[2][KVT];   // 2 x 25600 B
  for (int i = tid; i < 127; i += 256) rtab[i] = rowtab[i * 8 + h] * 1.44269504f;
  for (int i = tid; i < 95; i += 256) ctab[i] = coltab[i * 8 + h] * 1.44269504f;

  const unsigned short* Qp = Q + (size_t)bh * S_TOK * 64;
  const unsigned short* KVp = KVg + (size_t)bh * 32 * KVT;

  const int t0 = sp * tiles_per_split;
  const int tend = t0 + tiles_per_split;

  auto STAGE = [&](int b, int t) {
    const char* src = (const char*)(KVp + (size_t)t * KVT);
    char* dst = (char*)&KVlds[b][0];
#pragma unroll
    for (int i = 0; i < 6; ++i)
      gload16(src + i * 4096 + tid * 16, dst + i * 4096 + tid * 16);
    if (tid < 64) gload16(src + 24576 + tid * 16, dst + 24576 + tid * 16);
  };

  STAGE(0, t0);
  asm volatile("s_waitcnt vmcnt(0)" ::: "memory");
  __syncthreads();

  int qr[2], qc[2];
  short8 qf[2][2];
  float ctr[2][3][4];
#pragma unroll
  for (int u = 0; u < 2; ++u) {
    const int q = q0 + u * 16 + ln;
    qr[u] = q / 48;
    qc[u] = q - qr[u] * 48;
    qf[u][0] = *(const short8*)&Qp[(size_t)q * 64 + g * 8];
    qf[u][1] = *(const short8*)&Qp[(size_t)q * 64 + 32 + g * 8];
    const float* cb = &ctab[qc[u] - g * 4 + 47];
#pragma unroll
    for (int m = 0; m < 3; ++m)
#pragma unroll
      for (int r = 0; r < 4; ++r) ctr[u][m][r] = cb[-(16 * m + r)];
  }

  short8 ones;
  {
    union { unsigned short s[8]; short8 v; } on;
#pragma unroll
    for (int j = 0; j < 8; ++j) on.s[j] = 0x3F80;  // bf16 1.0
    ones = on.v;
  }

  floatx4 o_acc[2][4];
  floatx4 o5[2];
#pragma unroll
  for (int u = 0; u < 2; ++u) {
#pragma unroll
    for (int r = 0; r < 4; ++r) o5[u][r] = 0.f;
#pragma unroll
    for (int dt = 0; dt < 4; ++dt)
#pragma unroll
      for (int r = 0; r < 4; ++r) o_acc[u][dt][r] = 0.f;
  }

  int cur = 0;
  for (int t = t0; t < tend; ++t) {
    if (t + 1 < tend) STAGE(cur ^ 1, t + 1);   // loads fly under compute
    const unsigned short* kb = &KVlds[cur][0];
    const unsigned short* vb = &KVlds[cur][6144];
    float rt[2][2];
#pragma unroll
    for (int u = 0; u < 2; ++u) {
      rt[u][0] = rtab[qr[u] + 63 - 2 * t] - 12.0f;
      rt[u][1] = rtab[qr[u] + 62 - 2 * t] - 12.0f;
    }
    const int swz = (ln & 7) << 3;
#pragma unroll
    for (int kc32 = 0; kc32 < 3; ++kc32) {
      float e[2][2][4];
#pragma unroll
      for (int kh = 0; kh < 2; ++kh) {
        const int kt = kc32 * 2 + kh;
        const int rb = (kt * 16 + ln) * 64;
        short8 kf0 = *(const short8*)&kb[rb + ((g * 8) ^ swz)];
        short8 kf1 = *(const short8*)&kb[rb + ((32 + g * 8) ^ swz)];
        const int m = kt % 3, wrap = kt / 3;
#pragma unroll
        for (int u = 0; u < 2; ++u) {
          // bias folded into the MFMA C-operand: D = K·Q^T + bias
          floatx4 s;
#pragma unroll
          for (int r = 0; r < 4; ++r) s[r] = rt[u][wrap] + ctr[u][m][r];
          s = __builtin_amdgcn_mfma_f32_16x16x32_bf16(kf0, qf[u][0], s, 0, 0, 0);
          s = __builtin_amdgcn_mfma_f32_16x16x32_bf16(kf1, qf[u][1], s, 0, 0, 0);
#pragma unroll
          for (int r = 0; r < 4; ++r)
            e[u][kh][r] = __builtin_amdgcn_exp2f(s[r]);
        }
      }
      short8 pf[2];
#pragma unroll
      for (int u = 0; u < 2; ++u) {
        union { unsigned uu[4]; short8 v; } pk;
        pk.uu[0] = pack2bf(e[u][0][0], e[u][0][1]);
        pk.uu[1] = pack2bf(e[u][0][2], e[u][0][3]);
        pk.uu[2] = pack2bf(e[u][1][0], e[u][1][1]);
        pk.uu[3] = pack2bf(e[u][1][2], e[u][1][3]);
        pf[u] = pk.v;
      }
#pragma unroll
      for (int dt = 0; dt < 4; ++dt) {
        const int vrow = dt * 16 + ln;
        short8 vf = *(const short8*)&vb[vrow * 104 + kc32 * 32 + g * 8];
        o_acc[0][dt] =
            __builtin_amdgcn_mfma_f32_16x16x32_bf16(pf[0], vf, o_acc[0][dt], 0, 0, 0);
        o_acc[1][dt] =
            __builtin_amdgcn_mfma_f32_16x16x32_bf16(pf[1], vf, o_acc[1][dt], 0, 0, 0);
      }
      o5[0] = __builtin_amdgcn_mfma_f32_16x16x32_bf16(pf[0], ones, o5[0], 0, 0, 0);
      o5[1] = __builtin_amdgcn_mfma_f32_16x16x32_bf16(pf[1], ones, o5[1], 0, 0, 0);
    }
    asm volatile("s_waitcnt vmcnt(0)" ::: "memory");  // my stage loads landed
    __syncthreads();            // everyone's landed; everyone done reading cur
    cur ^= 1;
  }
  const size_t rowbase = (size_t)(sp * 16 + bh) * S_TOK;
#pragma unroll
  for (int u = 0; u < 2; ++u) {
    if (ln == 0) {
#pragma unroll
      for (int r = 0; r < 4; ++r)
        Lpart[rowbase + q0 + u * 16 + g * 4 + r] = o5[u][r];
    }
#pragma unroll
    for (int dt = 0; dt < 4; ++dt)
#pragma unroll
      for (int r = 0; r < 4; ++r)
        Opart[(rowbase + q0 + u * 16 + g * 4 + r) * 64 + dt * 16 + ln] =
            o_acc[u][dt][r];
  }
}

// --- Pass C: output GEMM (bf16) + fused split-K combine, load-overlapped ----
template <int NS>
__global__ __launch_bounds__(256, 2) void ga_outmm(
    const float* __restrict__ Opart, const float* __restrict__ Lpart,
    const unsigned short* __restrict__ Bh_, float* __restrict__ Out) {
  const int tid = threadIdx.x;
  const int w = tid >> 6, l = tid & 63;
  const int g = l >> 4, ln = l & 15;
  const int wm = w >> 1, wn = w & 1;
  const int m0 = blockIdx.x * 64;
  const int n0 = blockIdx.y * 64;
  __shared__ unsigned short Alds[64 * 64];
  __shared__ unsigned short Blds[2][64 * 64];
  floatx4 acc[2][2];
#pragma unroll
  for (int mi = 0; mi < 2; ++mi)
#pragma unroll
    for (int ni = 0; ni < 2; ++ni)
#pragma unroll
      for (int r = 0; r < 4; ++r) acc[mi][ni][r] = 0.f;

  const int lm = tid >> 2, lk4 = tid & 3;
  const int m = m0 + lm;
  const int b = (m >= S_TOK) ? 1 : 0;
  const int q = m - b * S_TOK;

  float v[16];
  float ls;
  auto ALOAD = [&](int h) {
    const int bh = b * 8 + h;
    ls = 0.f;
#pragma unroll
    for (int s = 0; s < NS; ++s) {
      const size_t row = (size_t)(s * 16 + bh) * S_TOK + q;
      ls += Lpart[row];
      const float* op = &Opart[row * 64 + lk4 * 16];
#pragma unroll
      for (int j = 0; j < 4; ++j) {
        float4 o = *(const float4*)(op + j * 4);
        if (s == 0) {
          v[j * 4] = o.x; v[j * 4 + 1] = o.y;
          v[j * 4 + 2] = o.z; v[j * 4 + 3] = o.w;
        } else {
          v[j * 4] += o.x; v[j * 4 + 1] += o.y;
          v[j * 4 + 2] += o.z; v[j * 4 + 3] += o.w;
        }
      }
    }
  };
  auto BISSUE = [&](int h, int buf) {
    const char* gb = (const char*)(Bh_ + (size_t)n0 * 512 + h * 64);
#pragma unroll
    for (int i = 0; i < 2; ++i) {
      const int off = (w * 2 + i) * 1024;
      const int gbo = ((off >> 7) + (l >> 3)) * 1024 + (l & 7) * 16;
      gload16(gb + gbo, (char*)&Blds[buf][0] + off);
    }
  };
  auto AWRITE = [&]() {
    const float inv = 1.0f / ls;
    unsigned pk[8];
#pragma unroll
    for (int j = 0; j < 8; ++j)
      pk[j] = pack2bf(v[2 * j] * inv, v[2 * j + 1] * inv);
    const int sw = (lm & 7) << 3;
    unsigned short* ab = &Alds[lm * 64];
#pragma unroll
    for (int j = 0; j < 4; ++j)
      *(uint2*)&ab[(lk4 * 16 + j * 4) ^ sw] = make_uint2(pk[2 * j], pk[2 * j + 1]);
  };

  // prologue: A(0), B(0)
  ALOAD(0);
  BISSUE(0, 0);
  AWRITE();                                          // waits on v automatically
  asm volatile("s_waitcnt vmcnt(0)" ::: "memory");   // B(0) landed
  __syncthreads();                                   // Alds(0)+Blds[0] visible

  int cur = 0;
  for (int h = 0; h < 8; ++h) {
    if (h < 7) {               // next panel's loads fly under this compute
      ALOAD(h + 1);
      BISSUE(h + 1, cur ^ 1);
    }
#pragma unroll
    for (int kk = 0; kk < 64; kk += 32) {
      const int kbase = kk + g * 8;
      short8 af[2], bf[2];
#pragma unroll
      for (int mi = 0; mi < 2; ++mi) {
        const int row = wm * 32 + mi * 16 + ln;
        af[mi] = *(const short8*)&Alds[row * 64 + (kbase ^ ((row & 7) << 3))];
      }
#pragma unroll
      for (int ni = 0; ni < 2; ++ni) {
        const int row = wn * 32 + ni * 16 + ln;
        bf[ni] =
            *(const short8*)&Blds[cur][row * 64 + (kbase ^ ((row & 7) << 3))];
      }
#pragma unroll
      for (int mi = 0; mi < 2; ++mi)
#pragma unroll
        for (int ni = 0; ni < 2; ++ni)
          acc[mi][ni] = __builtin_amdgcn_mfma_f32_16x16x32_bf16(
              af[mi], bf[ni], acc[mi][ni], 0, 0, 0);
    }
    if (h < 7) {
      __syncthreads();   // all waves done reading Alds; B(h+1) long since landed
      AWRITE();          // stage A(h+1) into Alds
      __syncthreads();   // Alds(h+1) visible
      cur ^= 1;
    }
  }
#pragma unroll
  for (int mi = 0; mi < 2; ++mi)
#pragma unroll
    for (int ni = 0; ni < 2; ++ni)
#pragma unroll
      for (int r = 0; r < 4; ++r)
        Out[(size_t)(m0 + wm * 32 + mi * 16 + g * 4 + r) * 512 + n0 +
            wn * 32 + ni * 16 + ln] = acc[mi][ni][r];
}

extern "C" void kernel_launch(void* const* d_in, const int* in_sizes, int n_in,
                              void* d_out, int out_size, void* d_ws,
                              size_t ws_size, hipStream_t stream) {
  const float* x = (const float*)d_in[0];       // [2,64,48,512]
  const float* w_qkv = (const float*)d_in[1];   // [512,1536]
  const float* w_out = (const float*)d_in[2];   // [512,512]
  const float* rrow = (const float*)d_in[3];    // [127,8]
  const float* rcol = (const float*)d_in[4];    // [95,8]
  float* out = (float*)d_out;                   // [6144,512]

  unsigned short* ws16 = (unsigned short*)d_ws;
  unsigned short* xh = ws16;                    // 3145728
  unsigned short* xl = xh + 3145728;            // 3145728
  unsigned short* wqh = xl + 3145728;           // 786432
  unsigned short* wql = wqh + 786432;
  unsigned short* woh = wql + 786432;           // 262144
  unsigned short* wol = woh + 262144;
  unsigned short* Qb = wol + 262144;            // 3145728
  unsigned short* Vb = Qb + 3145728;            // 3145728
  unsigned short* KV = Vb + 3145728;            // 16*32*12800 = 6553600
  float* Opart = (float*)(KV + 6553600);
  const size_t base_bytes =
      ((size_t)3145728 * 4 + 786432 * 2 + 262144 * 2 + 6553600) * 2;
  const size_t per_split = (size_t)(3145728 + 49152) * 4;
  const int nsplit = (ws_size >= base_bytes + 2 * per_split) ? 2 : 1;
  float* Lpart = Opart + (size_t)nsplit * 3145728;

  ga_conv_all<<<1792, 256, 0, stream>>>(x, w_qkv, w_out, xh, xl, wqh, wql, woh,
                                        wol);
  ga_mm3<128, 128><<<dim3(48, 12), 256, 0, stream>>>(
      xh, xl, wqh, wql, Qb, KV, Vb);
  ga_vtrans<<<dim3(32, 16), 256, 0, stream>>>(Vb, KV);
  ga_attn16<<<dim3(24, 16, nsplit), 256, 0, stream>>>(
      Qb, KV, rrow, rcol, Opart, Lpart, 32 / nsplit);
  if (nsplit == 2)
    ga_outmm<2><<<dim3(96, 8), 256, 0, stream>>>(Opart, Lpart, woh, out);
  else
    ga_outmm<1><<<dim3(96, 8), 256, 0, stream>>>(Opart, Lpart, woh, out);
}

// Round 14
// 121.117 us; speedup vs baseline: 1.6295x; 1.0257x over previous
//
#include <hip/hip_runtime.h>
#include <hip/hip_bf16.h>

#define S_TOK 3072   // 64*48
#define NHEADS 8
#define KVT 12800    // u16 per KV tile: K 6144 ([96][64] swz) + V 6656 ([64][104])

typedef __attribute__((ext_vector_type(8))) short short8;
typedef __attribute__((ext_vector_type(4))) float floatx4;
typedef __attribute__((ext_vector_type(4))) unsigned short ushortx4;

__device__ __forceinline__ unsigned short f2bf(float f) {
  union { float f; unsigned u; } v; v.f = f;
  unsigned r = v.u + 0x7fffu + ((v.u >> 16) & 1u);   // RTN-even
  return (unsigned short)(r >> 16);
}
__device__ __forceinline__ float bf2f(unsigned short h) {
  union { unsigned u; float f; } v; v.u = (unsigned)h << 16;
  return v.f;
}
__device__ __forceinline__ unsigned pack2bf(float a, float b) {
  __hip_bfloat162 h = __float22bfloat162_rn(make_float2(a, b));
  union { __hip_bfloat162 h; unsigned u; } c; c.h = h;
  return c.u;
}
__device__ __forceinline__ void gload16(const void* g, void* l) {
  __builtin_amdgcn_global_load_lds(
      (const __attribute__((address_space(1))) unsigned int*)g,
      (__attribute__((address_space(3))) unsigned int*)l, 16, 0, 0);
}

// ---- merged converter: X hi/lo (blocks 0..1535), w_qkv^T (1536..1727),
// w_out^T (1728..1791); all outputs pre-swizzled for gload_lds staging ----
__global__ __launch_bounds__(256) void ga_conv_all(
    const float* __restrict__ X, const float* __restrict__ Wq,
    const float* __restrict__ Wo, unsigned short* __restrict__ xh,
    unsigned short* __restrict__ xl, unsigned short* __restrict__ wqh,
    unsigned short* __restrict__ wql, unsigned short* __restrict__ woh,
    unsigned short* __restrict__ wol) {
  const int blk = blockIdx.x;
  const int t = threadIdx.x;
  if (blk < 1536) {
    const int c = blk * 256 + t;
    const int m = c >> 6;
    const int c8 = (c & 63) << 3;
    const float* src = X + (size_t)m * 512 + c8;
    float4 v0 = *(const float4*)src, v1 = *(const float4*)(src + 4);
    float vv[8] = {v0.x, v0.y, v0.z, v0.w, v1.x, v1.y, v1.z, v1.w};
    union { unsigned short s[8]; short8 v; } hh, ll;
#pragma unroll
    for (int e = 0; e < 8; ++e) {
      hh.s[e] = f2bf(vv[e]);
      ll.s[e] = f2bf(vv[e] - bf2f(hh.s[e]));
    }
    const size_t dst = (size_t)m * 512 + (c8 ^ ((m & 7) << 3));
    *(short8*)&xh[dst] = hh.v;
    *(short8*)&xl[dst] = ll.v;
    return;
  }
  const int wq = (blk < 1728);
  const int b2 = wq ? (blk - 1536) : (blk - 1728);
  const int N = wq ? 1536 : 512;
  const float* W = wq ? Wq : Wo;
  unsigned short* th = wq ? wqh : woh;
  unsigned short* tl = wq ? wql : wol;
  const int k0 = (b2 & 7) * 64, n0 = (b2 >> 3) * 64;
  __shared__ float Ts[64][65];
#pragma unroll
  for (int i = 0; i < 4; ++i) {
    const int r = (t >> 4) + i * 16, c4 = (t & 15) * 4;
    float4 v = *(const float4*)&W[(size_t)(k0 + r) * N + n0 + c4];
    Ts[r][c4] = v.x; Ts[r][c4 + 1] = v.y; Ts[r][c4 + 2] = v.z; Ts[r][c4 + 3] = v.w;
  }
  __syncthreads();
#pragma unroll
  for (int j = 0; j < 2; ++j) {
    const int chunk = t * 2 + j;
    const int nl = chunk >> 3, m8 = chunk & 7;
    const int n = n0 + nl;
    const int ks = (m8 * 8) ^ ((n & 7) << 3);
    union { unsigned short s[8]; short8 v; } hh, ll;
#pragma unroll
    for (int e = 0; e < 8; ++e) {
      float f = Ts[ks + e][nl];
      hh.s[e] = f2bf(f);
      ll.s[e] = f2bf(f - bf2f(hh.s[e]));
    }
    const size_t dst = (size_t)n * 512 + k0 + m8 * 8;
    *(short8*)&th[dst] = hh.v;
    *(short8*)&tl[dst] = ll.v;
  }
}

// ---- bf16x3 MFMA GEMM for QKV; K goes into tiled KV buffer.
// Q/K column-blocks (blockIdx.y<8) use 2 terms (drop x_hi*w_lo: score error
// ~3e-3 in log2-space, softmax-normalized => negligible); V keeps 3 terms.
template <int BM, int BN>
__global__ __launch_bounds__(256, 2) void ga_mm3(
    const unsigned short* __restrict__ Ah, const unsigned short* __restrict__ Al,
    const unsigned short* __restrict__ Bh, const unsigned short* __restrict__ Bl,
    unsigned short* __restrict__ Qd, unsigned short* __restrict__ KV,
    unsigned short* __restrict__ Vd) {
  const int tid = threadIdx.x;
  const int w = tid >> 6, l = tid & 63;
  const int g = l >> 4, ln = l & 15;
  const int wm = w >> 1, wn = w & 1;
  const int m0 = blockIdx.x * BM;
  const int n0 = blockIdx.y * BN;
  const bool full3 = (n0 >= 1024);   // V blocks only
  constexpr int MI = BM / 32;
  constexpr int NI = BN / 32;
  __shared__ unsigned short Alds[2][BM * 64];
  __shared__ unsigned short Blds[2][BN * 64];
  floatx4 acc[MI][NI];
#pragma unroll
  for (int mi = 0; mi < MI; ++mi)
#pragma unroll
    for (int ni = 0; ni < NI; ++ni)
#pragma unroll
      for (int r = 0; r < 4; ++r) acc[mi][ni][r] = 0.f;

  for (int k0 = 0; k0 < 512; k0 += 64) {
    __syncthreads();
    {
      constexpr int PWA = (BM * 128) / 4096;
      constexpr int PWB = (BN * 128) / 4096;
      const char* ga_h = (const char*)(Ah + (size_t)m0 * 512 + k0);
      const char* ga_l = (const char*)(Al + (size_t)m0 * 512 + k0);
      const char* gb_h = (const char*)(Bh + (size_t)n0 * 512 + k0);
      const char* gb_l = (const char*)(Bl + (size_t)n0 * 512 + k0);
#pragma unroll
      for (int i = 0; i < PWA; ++i) {
        const int off = (w * PWA + i) * 1024;
        const int gb = ((off >> 7) + (l >> 3)) * 1024 + (l & 7) * 16;
        gload16(ga_h + gb, (char*)&Alds[0][0] + off);
        gload16(ga_l + gb, (char*)&Alds[1][0] + off);
      }
#pragma unroll
      for (int i = 0; i < PWB; ++i) {
        const int off = (w * PWB + i) * 1024;
        const int gb = ((off >> 7) + (l >> 3)) * 1024 + (l & 7) * 16;
        gload16(gb_h + gb, (char*)&Blds[0][0] + off);
        gload16(gb_l + gb, (char*)&Blds[1][0] + off);
      }
    }
    asm volatile("s_waitcnt vmcnt(0)" ::: "memory");
    __syncthreads();
#pragma unroll
    for (int kk = 0; kk < 64; kk += 32) {
      const int kbase = kk + g * 8;
      short8 ah[MI], al[MI], bh[NI], bl[NI];
#pragma unroll
      for (int mi = 0; mi < MI; ++mi) {
        const int row = wm * (BM / 2) + mi * 16 + ln;
        const int a = row * 64 + (kbase ^ ((row & 7) << 3));
        ah[mi] = *(const short8*)&Alds[0][a];
        al[mi] = *(const short8*)&Alds[1][a];
      }
#pragma unroll
      for (int ni = 0; ni < NI; ++ni) {
        const int row = wn * (BN / 2) + ni * 16 + ln;
        const int a = row * 64 + (kbase ^ ((row & 7) << 3));
        bh[ni] = *(const short8*)&Blds[0][a];
        bl[ni] = *(const short8*)&Blds[1][a];
      }
#pragma unroll
      for (int mi = 0; mi < MI; ++mi)
#pragma unroll
        for (int ni = 0; ni < NI; ++ni) {
          acc[mi][ni] = __builtin_amdgcn_mfma_f32_16x16x32_bf16(
              ah[mi], bh[ni], acc[mi][ni], 0, 0, 0);
          acc[mi][ni] = __builtin_amdgcn_mfma_f32_16x16x32_bf16(
              al[mi], bh[ni], acc[mi][ni], 0, 0, 0);
          if (full3)
            acc[mi][ni] = __builtin_amdgcn_mfma_f32_16x16x32_bf16(
                ah[mi], bl[ni], acc[mi][ni], 0, 0, 0);
        }
    }
  }
  // QKV scatter epilogue
  const int b = m0 / S_TOK;
  const int s_base = (m0 % S_TOK) + wm * (BM / 2);
#pragma unroll
  for (int ni = 0; ni < NI; ++ni) {
    const int ng = n0 + wn * (BN / 2) + ni * 16;
    const int which = ng >> 9;
    const int h = (ng >> 6) & 7;
    const int d = (ng & 63) + ln;
    const int bh = b * 8 + h;
    const float qs = (which == 0) ? 0.18033688f : 1.0f;  // 1/8*log2e
    if (which == 1) {
      unsigned short* kp = KV + (size_t)bh * 32 * KVT;
#pragma unroll
      for (int mi = 0; mi < MI; ++mi)
#pragma unroll
        for (int r = 0; r < 4; ++r) {
          const int s = s_base + mi * 16 + g * 4 + r;
          const int tile = s / 96;
          const int r96 = s - tile * 96;
          kp[tile * KVT + r96 * 64 + (d ^ ((s & 7) << 3))] =
              f2bf(acc[mi][ni][r]);
        }
    } else {
      unsigned short* hp =
          (which == 0 ? Qd : Vd) + (size_t)bh * S_TOK * 64;
#pragma unroll
      for (int mi = 0; mi < MI; ++mi)
#pragma unroll
        for (int r = 0; r < 4; ++r) {
          const int s = s_base + mi * 16 + g * 4 + r;
          hp[(size_t)s * 64 + d] = f2bf(acc[mi][ni][r] * qs);
        }
    }
  }
}

// ---- Pass A2: V -> KV V-region [64 d][104 k], key-permuted (lane-local P) ----
__global__ __launch_bounds__(256) void ga_vtrans(
    const unsigned short* __restrict__ V, unsigned short* __restrict__ KV) {
  const int t = threadIdx.x;
  const int tile = blockIdx.x;
  const int bh = blockIdx.y;
  __shared__ unsigned short Ts[96][72];
  const unsigned short* vp = V + ((size_t)bh * S_TOK + tile * 96) * 64;
#pragma unroll
  for (int it = 0; it < 3; ++it) {
    int c = it * 256 + t;
    int s = c >> 3, d8 = c & 7;
    short8 v = *(const short8*)&vp[(size_t)s * 64 + d8 * 8];
    *(short8*)&Ts[s][d8 * 8] = v;
  }
  __syncthreads();
  unsigned short* op = KV + ((size_t)bh * 32 + tile) * KVT + 6144;
#pragma unroll
  for (int it = 0; it < 4; ++it) {
    int c2 = it * 256 + t;           // 832 chunks of 8 u16 (64 d x 13)
    if (c2 < 832) {
      const int d = c2 / 13;
      const int kc8 = (c2 - d * 13) * 8;
      short8 o;
      if (kc8 < 96) {
#pragma unroll
        for (int j = 0; j < 8; ++j) {
          const int p = kc8 + j;
          const int key =
              (p >> 5) * 32 + ((p >> 2) & 1) * 16 + ((p >> 3) & 3) * 4 + (p & 3);
          o[j] = (short)Ts[key][d];
        }
      } else {
#pragma unroll
        for (int j = 0; j < 8; ++j) o[j] = 0;
      }
      *(short8*)&op[d * 104 + kc8] = o;
    }
  }
}

// -- Pass B: attention; dbuf KV staging, bias-in-C, XCD-local grid, setprio --
__global__ __launch_bounds__(256) void ga_attn16(
    const unsigned short* __restrict__ Q, const unsigned short* __restrict__ KVg,
    const float* __restrict__ rowtab, const float* __restrict__ coltab,
    float* __restrict__ Opart, float* __restrict__ Lpart, int nsplit) {
  const int tid = threadIdx.x;
  const int w = tid >> 6;
  const int l = tid & 63;
  const int g = l >> 4;
  const int ln = l & 15;
  // XCD-aware decode (R9-proven): all blocks of one bh land on one XCD
  const int wgid = blockIdx.x;
  const int idx = wgid >> 3;
  const int bpb = 24 * nsplit;                  // blocks per bh
  const int bh = ((wgid & 7) << 1) + idx / bpb;
  const int rem = idx % bpb;
  const int sp = rem / 24;
  const int qb = rem % 24;
  const int h = bh & 7;
  const int q0 = qb * 128 + w * 32;
  const int tiles_per_split = 32 / nsplit;

  __shared__ float rtab[127];
  __shared__ float ctab[95];
  __shared__ unsigned short KVlds[2][KVT];   // 2 x 25600 B
  for (int i = tid; i < 127; i += 256) rtab[i] = rowtab[i * 8 + h] * 1.44269504f;
  for (int i = tid; i < 95; i += 256) ctab[i] = coltab[i * 8 + h] * 1.44269504f;

  const unsigned short* Qp = Q + (size_t)bh * S_TOK * 64;
  const unsigned short* KVp = KVg + (size_t)bh * 32 * KVT;

  const int t0 = sp * tiles_per_split;
  const int tend = t0 + tiles_per_split;

  auto STAGE = [&](int b, int t) {
    const char* src = (const char*)(KVp + (size_t)t * KVT);
    char* dst = (char*)&KVlds[b][0];
#pragma unroll
    for (int i = 0; i < 6; ++i)
      gload16(src + i * 4096 + tid * 16, dst + i * 4096 + tid * 16);
    if (tid < 64) gload16(src + 24576 + tid * 16, dst + 24576 + tid * 16);
  };

  STAGE(0, t0);
  asm volatile("s_waitcnt vmcnt(0)" ::: "memory");
  __syncthreads();

  int qr[2], qc[2];
  short8 qf[2][2];
  float ctr[2][3][4];
#pragma unroll
  for (int u = 0; u < 2; ++u) {
    const int q = q0 + u * 16 + ln;
    qr[u] = q / 48;
    qc[u] = q - qr[u] * 48;
    qf[u][0] = *(const short8*)&Qp[(size_t)q * 64 + g * 8];
    qf[u][1] = *(const short8*)&Qp[(size_t)q * 64 + 32 + g * 8];
    const float* cb = &ctab[qc[u] - g * 4 + 47];
#pragma unroll
    for (int m = 0; m < 3; ++m)
#pragma unroll
      for (int r = 0; r < 4; ++r) ctr[u][m][r] = cb[-(16 * m + r)];
  }

  short8 ones;
  {
    union { unsigned short s[8]; short8 v; } on;
#pragma unroll
    for (int j = 0; j < 8; ++j) on.s[j] = 0x3F80;  // bf16 1.0
    ones = on.v;
  }

  floatx4 o_acc[2][4];
  floatx4 o5[2];
#pragma unroll
  for (int u = 0; u < 2; ++u) {
#pragma unroll
    for (int r = 0; r < 4; ++r) o5[u][r] = 0.f;
#pragma unroll
    for (int dt = 0; dt < 4; ++dt)
#pragma unroll
      for (int r = 0; r < 4; ++r) o_acc[u][dt][r] = 0.f;
  }

  int cur = 0;
  for (int t = t0; t < tend; ++t) {
    if (t + 1 < tend) STAGE(cur ^ 1, t + 1);   // loads fly under compute
    const unsigned short* kb = &KVlds[cur][0];
    const unsigned short* vb = &KVlds[cur][6144];
    float rt[2][2];
#pragma unroll
    for (int u = 0; u < 2; ++u) {
      rt[u][0] = rtab[qr[u] + 63 - 2 * t] - 12.0f;
      rt[u][1] = rtab[qr[u] + 62 - 2 * t] - 12.0f;
    }
    const int swz = (ln & 7) << 3;
#pragma unroll
    for (int kc32 = 0; kc32 < 3; ++kc32) {
      float e[2][2][4];
#pragma unroll
      for (int kh = 0; kh < 2; ++kh) {
        const int kt = kc32 * 2 + kh;
        const int rb = (kt * 16 + ln) * 64;
        short8 kf0 = *(const short8*)&kb[rb + ((g * 8) ^ swz)];
        short8 kf1 = *(const short8*)&kb[rb + ((32 + g * 8) ^ swz)];
        const int m = kt % 3, wrap = kt / 3;
#pragma unroll
        for (int u = 0; u < 2; ++u) {
          // bias folded into the MFMA C-operand: D = K·Q^T + bias
          floatx4 s;
#pragma unroll
          for (int r = 0; r < 4; ++r) s[r] = rt[u][wrap] + ctr[u][m][r];
          s = __builtin_amdgcn_mfma_f32_16x16x32_bf16(kf0, qf[u][0], s, 0, 0, 0);
          s = __builtin_amdgcn_mfma_f32_16x16x32_bf16(kf1, qf[u][1], s, 0, 0, 0);
#pragma unroll
          for (int r = 0; r < 4; ++r)
            e[u][kh][r] = __builtin_amdgcn_exp2f(s[r]);
        }
      }
      short8 pf[2];
#pragma unroll
      for (int u = 0; u < 2; ++u) {
        union { unsigned uu[4]; short8 v; } pk;
        pk.uu[0] = pack2bf(e[u][0][0], e[u][0][1]);
        pk.uu[1] = pack2bf(e[u][0][2], e[u][0][3]);
        pk.uu[2] = pack2bf(e[u][1][0], e[u][1][1]);
        pk.uu[3] = pack2bf(e[u][1][2], e[u][1][3]);
        pf[u] = pk.v;
      }
      __builtin_amdgcn_s_setprio(1);   // favor the MFMA-feeding wave (T5)
#pragma unroll
      for (int dt = 0; dt < 4; ++dt) {
        const int vrow = dt * 16 + ln;
        short8 vf = *(const short8*)&vb[vrow * 104 + kc32 * 32 + g * 8];
        o_acc[0][dt] =
            __builtin_amdgcn_mfma_f32_16x16x32_bf16(pf[0], vf, o_acc[0][dt], 0, 0, 0);
        o_acc[1][dt] =
            __builtin_amdgcn_mfma_f32_16x16x32_bf16(pf[1], vf, o_acc[1][dt], 0, 0, 0);
      }
      o5[0] = __builtin_amdgcn_mfma_f32_16x16x32_bf16(pf[0], ones, o5[0], 0, 0, 0);
      o5[1] = __builtin_amdgcn_mfma_f32_16x16x32_bf16(pf[1], ones, o5[1], 0, 0, 0);
      __builtin_amdgcn_s_setprio(0);
    }
    asm volatile("s_waitcnt vmcnt(0)" ::: "memory");  // my stage loads landed
    __syncthreads();            // everyone's landed; everyone done reading cur
    cur ^= 1;
  }
  const size_t rowbase = (size_t)(sp * 16 + bh) * S_TOK;
#pragma unroll
  for (int u = 0; u < 2; ++u) {
    if (ln == 0) {
#pragma unroll
      for (int r = 0; r < 4; ++r)
        Lpart[rowbase + q0 + u * 16 + g * 4 + r] = o5[u][r];
    }
#pragma unroll
    for (int dt = 0; dt < 4; ++dt)
#pragma unroll
      for (int r = 0; r < 4; ++r)
        Opart[(rowbase + q0 + u * 16 + g * 4 + r) * 64 + dt * 16 + ln] =
            o_acc[u][dt][r];
  }
}

// --- Pass C: output GEMM (bf16) + fused split-K combine, load-overlapped ----
template <int NS>
__global__ __launch_bounds__(256, 2) void ga_outmm(
    const float* __restrict__ Opart, const float* __restrict__ Lpart,
    const unsigned short* __restrict__ Bh_, float* __restrict__ Out) {
  const int tid = threadIdx.x;
  const int w = tid >> 6, l = tid & 63;
  const int g = l >> 4, ln = l & 15;
  const int wm = w >> 1, wn = w & 1;
  const int m0 = blockIdx.x * 64;
  const int n0 = blockIdx.y * 64;
  __shared__ unsigned short Alds[64 * 64];
  __shared__ unsigned short Blds[2][64 * 64];
  floatx4 acc[2][2];
#pragma unroll
  for (int mi = 0; mi < 2; ++mi)
#pragma unroll
    for (int ni = 0; ni < 2; ++ni)
#pragma unroll
      for (int r = 0; r < 4; ++r) acc[mi][ni][r] = 0.f;

  const int lm = tid >> 2, lk4 = tid & 3;
  const int m = m0 + lm;
  const int b = (m >= S_TOK) ? 1 : 0;
  const int q = m - b * S_TOK;

  float v[16];
  float ls;
  auto ALOAD = [&](int h) {
    const int bh = b * 8 + h;
    ls = 0.f;
#pragma unroll
    for (int s = 0; s < NS; ++s) {
      const size_t row = (size_t)(s * 16 + bh) * S_TOK + q;
      ls += Lpart[row];
      const float* op = &Opart[row * 64 + lk4 * 16];
#pragma unroll
      for (int j = 0; j < 4; ++j) {
        float4 o = *(const float4*)(op + j * 4);
        if (s == 0) {
          v[j * 4] = o.x; v[j * 4 + 1] = o.y;
          v[j * 4 + 2] = o.z; v[j * 4 + 3] = o.w;
        } else {
          v[j * 4] += o.x; v[j * 4 + 1] += o.y;
          v[j * 4 + 2] += o.z; v[j * 4 + 3] += o.w;
        }
      }
    }
  };
  auto BISSUE = [&](int h, int buf) {
    const char* gb = (const char*)(Bh_ + (size_t)n0 * 512 + h * 64);
#pragma unroll
    for (int i = 0; i < 2; ++i) {
      const int off = (w * 2 + i) * 1024;
      const int gbo = ((off >> 7) + (l >> 3)) * 1024 + (l & 7) * 16;
      gload16(gb + gbo, (char*)&Blds[buf][0] + off);
    }
  };
  auto AWRITE = [&]() {
    const float inv = 1.0f / ls;
    unsigned pk[8];
#pragma unroll
    for (int j = 0; j < 8; ++j)
      pk[j] = pack2bf(v[2 * j] * inv, v[2 * j + 1] * inv);
    const int sw = (lm & 7) << 3;
    unsigned short* ab = &Alds[lm * 64];
#pragma unroll
    for (int j = 0; j < 4; ++j)
      *(uint2*)&ab[(lk4 * 16 + j * 4) ^ sw] = make_uint2(pk[2 * j], pk[2 * j + 1]);
  };

  // prologue: A(0), B(0)
  ALOAD(0);
  BISSUE(0, 0);
  AWRITE();                                          // waits on v automatically
  asm volatile("s_waitcnt vmcnt(0)" ::: "memory");   // B(0) landed
  __syncthreads();                                   // Alds(0)+Blds[0] visible

  int cur = 0;
  for (int h = 0; h < 8; ++h) {
    if (h < 7) {               // next panel's loads fly under this compute
      ALOAD(h + 1);
      BISSUE(h + 1, cur ^ 1);
    }
#pragma unroll
    for (int kk = 0; kk < 64; kk += 32) {
      const int kbase = kk + g * 8;
      short8 af[2], bf[2];
#pragma unroll
      for (int mi = 0; mi < 2; ++mi) {
        const int row = wm * 32 + mi * 16 + ln;
        af[mi] = *(const short8*)&Alds[row * 64 + (kbase ^ ((row & 7) << 3))];
      }
#pragma unroll
      for (int ni = 0; ni < 2; ++ni) {
        const int row = wn * 32 + ni * 16 + ln;
        bf[ni] =
            *(const short8*)&Blds[cur][row * 64 + (kbase ^ ((row & 7) << 3))];
      }
#pragma unroll
      for (int mi = 0; mi < 2; ++mi)
#pragma unroll
        for (int ni = 0; ni < 2; ++ni)
          acc[mi][ni] = __builtin_amdgcn_mfma_f32_16x16x32_bf16(
              af[mi], bf[ni], acc[mi][ni], 0, 0, 0);
    }
    if (h < 7) {
      __syncthreads();   // all waves done reading Alds; B(h+1) long since landed
      AWRITE();          // stage A(h+1) into Alds
      __syncthreads();   // Alds(h+1) visible
      cur ^= 1;
    }
  }
#pragma unroll
  for (int mi = 0; mi < 2; ++mi)
#pragma unroll
    for (int ni = 0; ni < 2; ++ni)
#pragma unroll
      for (int r = 0; r < 4; ++r)
        Out[(size_t)(m0 + wm * 32 + mi * 16 + g * 4 + r) * 512 + n0 +
            wn * 32 + ni * 16 + ln] = acc[mi][ni][r];
}

extern "C" void kernel_launch(void* const* d_in, const int* in_sizes, int n_in,
                              void* d_out, int out_size, void* d_ws,
                              size_t ws_size, hipStream_t stream) {
  const float* x = (const float*)d_in[0];       // [2,64,48,512]
  const float* w_qkv = (const float*)d_in[1];   // [512,1536]
  const float* w_out = (const float*)d_in[2];   // [512,512]
  const float* rrow = (const float*)d_in[3];    // [127,8]
  const float* rcol = (const float*)d_in[4];    // [95,8]
  float* out = (float*)d_out;                   // [6144,512]

  unsigned short* ws16 = (unsigned short*)d_ws;
  unsigned short* xh = ws16;                    // 3145728
  unsigned short* xl = xh + 3145728;            // 3145728
  unsigned short* wqh = xl + 3145728;           // 786432
  unsigned short* wql = wqh + 786432;
  unsigned short* woh = wql + 786432;           // 262144
  unsigned short* wol = woh + 262144;
  unsigned short* Qb = wol + 262144;            // 3145728
  unsigned short* Vb = Qb + 3145728;            // 3145728
  unsigned short* KV = Vb + 3145728;            // 16*32*12800 = 6553600
  float* Opart = (float*)(KV + 6553600);
  const size_t base_bytes =
      ((size_t)3145728 * 4 + 786432 * 2 + 262144 * 2 + 6553600) * 2;
  const size_t per_split = (size_t)(3145728 + 49152) * 4;
  const int nsplit = (ws_size >= base_bytes + 2 * per_split) ? 2 : 1;
  float* Lpart = Opart + (size_t)nsplit * 3145728;

  ga_conv_all<<<1792, 256, 0, stream>>>(x, w_qkv, w_out, xh, xl, wqh, wql, woh,
                                        wol);
  ga_mm3<128, 128><<<dim3(48, 12), 256, 0, stream>>>(
      xh, xl, wqh, wql, Qb, KV, Vb);
  ga_vtrans<<<dim3(32, 16), 256, 0, stream>>>(Vb, KV);
  ga_attn16<<<24 * 16 * nsplit, 256, 0, stream>>>(
      Qb, KV, rrow, rcol, Opart, Lpart, nsplit);
  if (nsplit == 2)
    ga_outmm<2><<<dim3(96, 8), 256, 0, stream>>>(Opart, Lpart, woh, out);
  else
    ga_outmm<1><<<dim3(96, 8), 256, 0, stream>>>(Opart, Lpart, woh, out);
}

// Round 15
// 117.048 us; speedup vs baseline: 1.6862x; 1.0348x over previous
//
#include <hip/hip_runtime.h>
#include <hip/hip_bf16.h>

#define S_TOK 3072   // 64*48
#define NHEADS 8
#define KVT 12800    // u16 per KV tile: K 6144 ([96][64] swz) + V 6656 ([64][104])

typedef __attribute__((ext_vector_type(8))) short short8;
typedef __attribute__((ext_vector_type(4))) float floatx4;
typedef __attribute__((ext_vector_type(4))) unsigned short ushortx4;

__device__ __forceinline__ unsigned short f2bf(float f) {
  union { float f; unsigned u; } v; v.f = f;
  unsigned r = v.u + 0x7fffu + ((v.u >> 16) & 1u);   // RTN-even
  return (unsigned short)(r >> 16);
}
__device__ __forceinline__ float bf2f(unsigned short h) {
  union { unsigned u; float f; } v; v.u = (unsigned)h << 16;
  return v.f;
}
__device__ __forceinline__ unsigned pack2bf(float a, float b) {
  __hip_bfloat162 h = __float22bfloat162_rn(make_float2(a, b));
  union { __hip_bfloat162 h; unsigned u; } c; c.h = h;
  return c.u;
}
__device__ __forceinline__ void gload16(const void* g, void* l) {
  __builtin_amdgcn_global_load_lds(
      (const __attribute__((address_space(1))) unsigned int*)g,
      (__attribute__((address_space(3))) unsigned int*)l, 16, 0, 0);
}

// ---- merged converter: X hi/lo (blocks 0..1535), w_qkv^T (1536..1727),
// w_out^T (1728..1791); all outputs pre-swizzled for gload_lds staging ----
__global__ __launch_bounds__(256) void ga_conv_all(
    const float* __restrict__ X, const float* __restrict__ Wq,
    const float* __restrict__ Wo, unsigned short* __restrict__ xh,
    unsigned short* __restrict__ xl, unsigned short* __restrict__ wqh,
    unsigned short* __restrict__ wql, unsigned short* __restrict__ woh,
    unsigned short* __restrict__ wol) {
  const int blk = blockIdx.x;
  const int t = threadIdx.x;
  if (blk < 1536) {
    const int c = blk * 256 + t;
    const int m = c >> 6;
    const int c8 = (c & 63) << 3;
    const float* src = X + (size_t)m * 512 + c8;
    float4 v0 = *(const float4*)src, v1 = *(const float4*)(src + 4);
    float vv[8] = {v0.x, v0.y, v0.z, v0.w, v1.x, v1.y, v1.z, v1.w};
    union { unsigned short s[8]; short8 v; } hh, ll;
#pragma unroll
    for (int e = 0; e < 8; ++e) {
      hh.s[e] = f2bf(vv[e]);
      ll.s[e] = f2bf(vv[e] - bf2f(hh.s[e]));
    }
    const size_t dst = (size_t)m * 512 + (c8 ^ ((m & 7) << 3));
    *(short8*)&xh[dst] = hh.v;
    *(short8*)&xl[dst] = ll.v;
    return;
  }
  const int wq = (blk < 1728);
  const int b2 = wq ? (blk - 1536) : (blk - 1728);
  const int N = wq ? 1536 : 512;
  const float* W = wq ? Wq : Wo;
  unsigned short* th = wq ? wqh : woh;
  unsigned short* tl = wq ? wql : wol;
  const int k0 = (b2 & 7) * 64, n0 = (b2 >> 3) * 64;
  __shared__ float Ts[64][65];
#pragma unroll
  for (int i = 0; i < 4; ++i) {
    const int r = (t >> 4) + i * 16, c4 = (t & 15) * 4;
    float4 v = *(const float4*)&W[(size_t)(k0 + r) * N + n0 + c4];
    Ts[r][c4] = v.x; Ts[r][c4 + 1] = v.y; Ts[r][c4 + 2] = v.z; Ts[r][c4 + 3] = v.w;
  }
  __syncthreads();
#pragma unroll
  for (int j = 0; j < 2; ++j) {
    const int chunk = t * 2 + j;
    const int nl = chunk >> 3, m8 = chunk & 7;
    const int n = n0 + nl;
    const int ks = (m8 * 8) ^ ((n & 7) << 3);
    union { unsigned short s[8]; short8 v; } hh, ll;
#pragma unroll
    for (int e = 0; e < 8; ++e) {
      float f = Ts[ks + e][nl];
      hh.s[e] = f2bf(f);
      ll.s[e] = f2bf(f - bf2f(hh.s[e]));
    }
    const size_t dst = (size_t)n * 512 + k0 + m8 * 8;
    *(short8*)&th[dst] = hh.v;
    *(short8*)&tl[dst] = ll.v;
  }
}

// ---- bf16x3 MFMA GEMM for QKV; K goes into tiled KV buffer.
// 1D grid, XCD y-chunk swizzle (72 blocks/XCD) for B-panel L2 locality.
// Q/K column-blocks use 2 terms; V keeps 3 terms.
template <int BM, int BN>
__global__ __launch_bounds__(256, 2) void ga_mm3(
    const unsigned short* __restrict__ Ah, const unsigned short* __restrict__ Al,
    const unsigned short* __restrict__ Bh, const unsigned short* __restrict__ Bl,
    unsigned short* __restrict__ Qd, unsigned short* __restrict__ KV,
    unsigned short* __restrict__ Vd) {
  const int tid = threadIdx.x;
  const int w = tid >> 6, l = tid & 63;
  const int g = l >> 4, ln = l & 15;
  const int wm = w >> 1, wn = w & 1;
  // XCD swizzle: 576 blocks, 72 per XCD, y-major within XCD chunk
  const int wgid = blockIdx.x;
  const int jj = (wgid & 7) * 72 + (wgid >> 3);
  const int m0 = (jj % 48) * BM;
  const int n0 = (jj / 48) * BN;
  const bool full3 = (n0 >= 1024);   // V blocks only
  constexpr int MI = BM / 32;
  constexpr int NI = BN / 32;
  __shared__ unsigned short Alds[2][BM * 64];
  __shared__ unsigned short Blds[2][BN * 64];
  floatx4 acc[MI][NI];
#pragma unroll
  for (int mi = 0; mi < MI; ++mi)
#pragma unroll
    for (int ni = 0; ni < NI; ++ni)
#pragma unroll
      for (int r = 0; r < 4; ++r) acc[mi][ni][r] = 0.f;

  for (int k0 = 0; k0 < 512; k0 += 64) {
    __syncthreads();
    {
      constexpr int PWA = (BM * 128) / 4096;
      constexpr int PWB = (BN * 128) / 4096;
      const char* ga_h = (const char*)(Ah + (size_t)m0 * 512 + k0);
      const char* ga_l = (const char*)(Al + (size_t)m0 * 512 + k0);
      const char* gb_h = (const char*)(Bh + (size_t)n0 * 512 + k0);
      const char* gb_l = (const char*)(Bl + (size_t)n0 * 512 + k0);
#pragma unroll
      for (int i = 0; i < PWA; ++i) {
        const int off = (w * PWA + i) * 1024;
        const int gb = ((off >> 7) + (l >> 3)) * 1024 + (l & 7) * 16;
        gload16(ga_h + gb, (char*)&Alds[0][0] + off);
        gload16(ga_l + gb, (char*)&Alds[1][0] + off);
      }
#pragma unroll
      for (int i = 0; i < PWB; ++i) {
        const int off = (w * PWB + i) * 1024;
        const int gb = ((off >> 7) + (l >> 3)) * 1024 + (l & 7) * 16;
        gload16(gb_h + gb, (char*)&Blds[0][0] + off);
        gload16(gb_l + gb, (char*)&Blds[1][0] + off);
      }
    }
    asm volatile("s_waitcnt vmcnt(0)" ::: "memory");
    __syncthreads();
#pragma unroll
    for (int kk = 0; kk < 64; kk += 32) {
      const int kbase = kk + g * 8;
      short8 ah[MI], al[MI], bh[NI], bl[NI];
#pragma unroll
      for (int mi = 0; mi < MI; ++mi) {
        const int row = wm * (BM / 2) + mi * 16 + ln;
        const int a = row * 64 + (kbase ^ ((row & 7) << 3));
        ah[mi] = *(const short8*)&Alds[0][a];
        al[mi] = *(const short8*)&Alds[1][a];
      }
#pragma unroll
      for (int ni = 0; ni < NI; ++ni) {
        const int row = wn * (BN / 2) + ni * 16 + ln;
        const int a = row * 64 + (kbase ^ ((row & 7) << 3));
        bh[ni] = *(const short8*)&Blds[0][a];
        bl[ni] = *(const short8*)&Blds[1][a];
      }
#pragma unroll
      for (int mi = 0; mi < MI; ++mi)
#pragma unroll
        for (int ni = 0; ni < NI; ++ni) {
          acc[mi][ni] = __builtin_amdgcn_mfma_f32_16x16x32_bf16(
              ah[mi], bh[ni], acc[mi][ni], 0, 0, 0);
          acc[mi][ni] = __builtin_amdgcn_mfma_f32_16x16x32_bf16(
              al[mi], bh[ni], acc[mi][ni], 0, 0, 0);
          if (full3)
            acc[mi][ni] = __builtin_amdgcn_mfma_f32_16x16x32_bf16(
                ah[mi], bl[ni], acc[mi][ni], 0, 0, 0);
        }
    }
  }
  // QKV scatter epilogue
  const int b = m0 / S_TOK;
  const int s_base = (m0 % S_TOK) + wm * (BM / 2);
#pragma unroll
  for (int ni = 0; ni < NI; ++ni) {
    const int ng = n0 + wn * (BN / 2) + ni * 16;
    const int which = ng >> 9;
    const int h = (ng >> 6) & 7;
    const int d = (ng & 63) + ln;
    const int bh = b * 8 + h;
    const float qs = (which == 0) ? 0.18033688f : 1.0f;  // 1/8*log2e
    if (which == 1) {
      unsigned short* kp = KV + (size_t)bh * 32 * KVT;
#pragma unroll
      for (int mi = 0; mi < MI; ++mi)
#pragma unroll
        for (int r = 0; r < 4; ++r) {
          const int s = s_base + mi * 16 + g * 4 + r;
          const int tile = s / 96;
          const int r96 = s - tile * 96;
          kp[tile * KVT + r96 * 64 + (d ^ ((s & 7) << 3))] =
              f2bf(acc[mi][ni][r]);
        }
    } else {
      unsigned short* hp =
          (which == 0 ? Qd : Vd) + (size_t)bh * S_TOK * 64;
#pragma unroll
      for (int mi = 0; mi < MI; ++mi)
#pragma unroll
        for (int r = 0; r < 4; ++r) {
          const int s = s_base + mi * 16 + g * 4 + r;
          hp[(size_t)s * 64 + d] = f2bf(acc[mi][ni][r] * qs);
        }
    }
  }
}

// ---- Pass A2: V -> KV V-region [64 d][104 k], key-permuted; XCD-local ----
__global__ __launch_bounds__(256) void ga_vtrans(
    const unsigned short* __restrict__ V, unsigned short* __restrict__ KV) {
  const int t = threadIdx.x;
  const int wgid = blockIdx.x;           // 512 = 8 XCD x 64
  const int i = wgid >> 3;
  const int bh = (wgid & 7) * 2 + (i >> 5);   // matches attn bh->XCD map
  const int tile = i & 31;
  __shared__ unsigned short Ts[96][72];
  const unsigned short* vp = V + ((size_t)bh * S_TOK + tile * 96) * 64;
#pragma unroll
  for (int it = 0; it < 3; ++it) {
    int c = it * 256 + t;
    int s = c >> 3, d8 = c & 7;
    short8 v = *(const short8*)&vp[(size_t)s * 64 + d8 * 8];
    *(short8*)&Ts[s][d8 * 8] = v;
  }
  __syncthreads();
  unsigned short* op = KV + ((size_t)bh * 32 + tile) * KVT + 6144;
#pragma unroll
  for (int it = 0; it < 4; ++it) {
    int c2 = it * 256 + t;           // 832 chunks of 8 u16 (64 d x 13)
    if (c2 < 832) {
      const int d = c2 / 13;
      const int kc8 = (c2 - d * 13) * 8;
      short8 o;
      if (kc8 < 96) {
#pragma unroll
        for (int j = 0; j < 8; ++j) {
          const int p = kc8 + j;
          const int key =
              (p >> 5) * 32 + ((p >> 2) & 1) * 16 + ((p >> 3) & 3) * 4 + (p & 3);
          o[j] = (short)Ts[key][d];
        }
      } else {
#pragma unroll
        for (int j = 0; j < 8; ++j) o[j] = 0;
      }
      *(short8*)&op[d * 104 + kc8] = o;
    }
  }
}

// -- Pass B: attention; dbuf KV staging, bias-in-C, XCD-local grid, setprio --
// Opart written as bf16 (l stays f32).
__global__ __launch_bounds__(256) void ga_attn16(
    const unsigned short* __restrict__ Q, const unsigned short* __restrict__ KVg,
    const float* __restrict__ rowtab, const float* __restrict__ coltab,
    unsigned short* __restrict__ Opart, float* __restrict__ Lpart, int nsplit) {
  const int tid = threadIdx.x;
  const int w = tid >> 6;
  const int l = tid & 63;
  const int g = l >> 4;
  const int ln = l & 15;
  // XCD-aware decode: all blocks of one bh land on one XCD
  const int wgid = blockIdx.x;
  const int idx = wgid >> 3;
  const int bpb = 24 * nsplit;                  // blocks per bh
  const int bh = ((wgid & 7) << 1) + idx / bpb;
  const int rem = idx % bpb;
  const int sp = rem / 24;
  const int qb = rem % 24;
  const int h = bh & 7;
  const int q0 = qb * 128 + w * 32;
  const int tiles_per_split = 32 / nsplit;

  __shared__ float rtab[127];
  __shared__ float ctab[95];
  __shared__ unsigned short KVlds[2][KVT];   // 2 x 25600 B
  for (int i = tid; i < 127; i += 256) rtab[i] = rowtab[i * 8 + h] * 1.44269504f;
  for (int i = tid; i < 95; i += 256) ctab[i] = coltab[i * 8 + h] * 1.44269504f;

  const unsigned short* Qp = Q + (size_t)bh * S_TOK * 64;
  const unsigned short* KVp = KVg + (size_t)bh * 32 * KVT;

  const int t0 = sp * tiles_per_split;
  const int tend = t0 + tiles_per_split;

  auto STAGE = [&](int b, int t) {
    const char* src = (const char*)(KVp + (size_t)t * KVT);
    char* dst = (char*)&KVlds[b][0];
#pragma unroll
    for (int i = 0; i < 6; ++i)
      gload16(src + i * 4096 + tid * 16, dst + i * 4096 + tid * 16);
    if (tid < 64) gload16(src + 24576 + tid * 16, dst + 24576 + tid * 16);
  };

  STAGE(0, t0);
  asm volatile("s_waitcnt vmcnt(0)" ::: "memory");
  __syncthreads();

  int qr[2], qc[2];
  short8 qf[2][2];
  float ctr[2][3][4];
#pragma unroll
  for (int u = 0; u < 2; ++u) {
    const int q = q0 + u * 16 + ln;
    qr[u] = q / 48;
    qc[u] = q - qr[u] * 48;
    qf[u][0] = *(const short8*)&Qp[(size_t)q * 64 + g * 8];
    qf[u][1] = *(const short8*)&Qp[(size_t)q * 64 + 32 + g * 8];
    const float* cb = &ctab[qc[u] - g * 4 + 47];
#pragma unroll
    for (int m = 0; m < 3; ++m)
#pragma unroll
      for (int r = 0; r < 4; ++r) ctr[u][m][r] = cb[-(16 * m + r)];
  }

  short8 ones;
  {
    union { unsigned short s[8]; short8 v; } on;
#pragma unroll
    for (int j = 0; j < 8; ++j) on.s[j] = 0x3F80;  // bf16 1.0
    ones = on.v;
  }

  floatx4 o_acc[2][4];
  floatx4 o5[2];
#pragma unroll
  for (int u = 0; u < 2; ++u) {
#pragma unroll
    for (int r = 0; r < 4; ++r) o5[u][r] = 0.f;
#pragma unroll
    for (int dt = 0; dt < 4; ++dt)
#pragma unroll
      for (int r = 0; r < 4; ++r) o_acc[u][dt][r] = 0.f;
  }

  int cur = 0;
  for (int t = t0; t < tend; ++t) {
    if (t + 1 < tend) STAGE(cur ^ 1, t + 1);   // loads fly under compute
    const unsigned short* kb = &KVlds[cur][0];
    const unsigned short* vb = &KVlds[cur][6144];
    float rt[2][2];
#pragma unroll
    for (int u = 0; u < 2; ++u) {
      rt[u][0] = rtab[qr[u] + 63 - 2 * t] - 12.0f;
      rt[u][1] = rtab[qr[u] + 62 - 2 * t] - 12.0f;
    }
    const int swz = (ln & 7) << 3;
#pragma unroll
    for (int kc32 = 0; kc32 < 3; ++kc32) {
      float e[2][2][4];
#pragma unroll
      for (int kh = 0; kh < 2; ++kh) {
        const int kt = kc32 * 2 + kh;
        const int rb = (kt * 16 + ln) * 64;
        short8 kf0 = *(const short8*)&kb[rb + ((g * 8) ^ swz)];
        short8 kf1 = *(const short8*)&kb[rb + ((32 + g * 8) ^ swz)];
        const int m = kt % 3, wrap = kt / 3;
#pragma unroll
        for (int u = 0; u < 2; ++u) {
          // bias folded into the MFMA C-operand: D = K·Q^T + bias
          floatx4 s;
#pragma unroll
          for (int r = 0; r < 4; ++r) s[r] = rt[u][wrap] + ctr[u][m][r];
          s = __builtin_amdgcn_mfma_f32_16x16x32_bf16(kf0, qf[u][0], s, 0, 0, 0);
          s = __builtin_amdgcn_mfma_f32_16x16x32_bf16(kf1, qf[u][1], s, 0, 0, 0);
#pragma unroll
          for (int r = 0; r < 4; ++r)
            e[u][kh][r] = __builtin_amdgcn_exp2f(s[r]);
        }
      }
      short8 pf[2];
#pragma unroll
      for (int u = 0; u < 2; ++u) {
        union { unsigned uu[4]; short8 v; } pk;
        pk.uu[0] = pack2bf(e[u][0][0], e[u][0][1]);
        pk.uu[1] = pack2bf(e[u][0][2], e[u][0][3]);
        pk.uu[2] = pack2bf(e[u][1][0], e[u][1][1]);
        pk.uu[3] = pack2bf(e[u][1][2], e[u][1][3]);
        pf[u] = pk.v;
      }
      __builtin_amdgcn_s_setprio(1);   // favor the MFMA-feeding wave (T5)
#pragma unroll
      for (int dt = 0; dt < 4; ++dt) {
        const int vrow = dt * 16 + ln;
        short8 vf = *(const short8*)&vb[vrow * 104 + kc32 * 32 + g * 8];
        o_acc[0][dt] =
            __builtin_amdgcn_mfma_f32_16x16x32_bf16(pf[0], vf, o_acc[0][dt], 0, 0, 0);
        o_acc[1][dt] =
            __builtin_amdgcn_mfma_f32_16x16x32_bf16(pf[1], vf, o_acc[1][dt], 0, 0, 0);
      }
      o5[0] = __builtin_amdgcn_mfma_f32_16x16x32_bf16(pf[0], ones, o5[0], 0, 0, 0);
      o5[1] = __builtin_amdgcn_mfma_f32_16x16x32_bf16(pf[1], ones, o5[1], 0, 0, 0);
      __builtin_amdgcn_s_setprio(0);
    }
    asm volatile("s_waitcnt vmcnt(0)" ::: "memory");  // my stage loads landed
    __syncthreads();            // everyone's landed; everyone done reading cur
    cur ^= 1;
  }
  const size_t rowbase = (size_t)(sp * 16 + bh) * S_TOK;
#pragma unroll
  for (int u = 0; u < 2; ++u) {
    if (ln == 0) {
#pragma unroll
      for (int r = 0; r < 4; ++r)
        Lpart[rowbase + q0 + u * 16 + g * 4 + r] = o5[u][r];
    }
#pragma unroll
    for (int dt = 0; dt < 4; ++dt)
#pragma unroll
      for (int r = 0; r < 4; ++r)
        Opart[(rowbase + q0 + u * 16 + g * 4 + r) * 64 + dt * 16 + ln] =
            f2bf(o_acc[u][dt][r]);
  }
}

// --- Pass C: output GEMM (bf16) + fused split-K combine (bf16 Opart) --------
template <int NS>
__global__ __launch_bounds__(256, 2) void ga_outmm(
    const unsigned short* __restrict__ Opart, const float* __restrict__ Lpart,
    const unsigned short* __restrict__ Bh_, float* __restrict__ Out) {
  const int tid = threadIdx.x;
  const int w = tid >> 6, l = tid & 63;
  const int g = l >> 4, ln = l & 15;
  const int wm = w >> 1, wn = w & 1;
  const int m0 = blockIdx.x * 64;
  const int n0 = blockIdx.y * 64;
  __shared__ unsigned short Alds[64 * 64];
  __shared__ unsigned short Blds[2][64 * 64];
  floatx4 acc[2][2];
#pragma unroll
  for (int mi = 0; mi < 2; ++mi)
#pragma unroll
    for (int ni = 0; ni < 2; ++ni)
#pragma unroll
      for (int r = 0; r < 4; ++r) acc[mi][ni][r] = 0.f;

  const int lm = tid >> 2, lk4 = tid & 3;
  const int m = m0 + lm;
  const int b = (m >= S_TOK) ? 1 : 0;
  const int q = m - b * S_TOK;

  float v[16];
  float ls;
  auto ALOAD = [&](int h) {
    const int bh = b * 8 + h;
    ls = 0.f;
#pragma unroll
    for (int s = 0; s < NS; ++s) {
      const size_t row = (size_t)(s * 16 + bh) * S_TOK + q;
      ls += Lpart[row];
      const unsigned short* op = &Opart[row * 64 + lk4 * 16];
      short8 a0 = *(const short8*)op;
      short8 a1 = *(const short8*)(op + 8);
#pragma unroll
      for (int j = 0; j < 8; ++j) {
        float f0 = bf2f((unsigned short)a0[j]);
        float f1 = bf2f((unsigned short)a1[j]);
        if (s == 0) {
          v[j] = f0;
          v[8 + j] = f1;
        } else {
          v[j] += f0;
          v[8 + j] += f1;
        }
      }
    }
  };
  auto BISSUE = [&](int h, int buf) {
    const char* gb = (const char*)(Bh_ + (size_t)n0 * 512 + h * 64);
#pragma unroll
    for (int i = 0; i < 2; ++i) {
      const int off = (w * 2 + i) * 1024;
      const int gbo = ((off >> 7) + (l >> 3)) * 1024 + (l & 7) * 16;
      gload16(gb + gbo, (char*)&Blds[buf][0] + off);
    }
  };
  auto AWRITE = [&]() {
    const float inv = 1.0f / ls;
    unsigned pk[8];
#pragma unroll
    for (int j = 0; j < 8; ++j)
      pk[j] = pack2bf(v[2 * j] * inv, v[2 * j + 1] * inv);
    const int sw = (lm & 7) << 3;
    unsigned short* ab = &Alds[lm * 64];
#pragma unroll
    for (int j = 0; j < 4; ++j)
      *(uint2*)&ab[(lk4 * 16 + j * 4) ^ sw] = make_uint2(pk[2 * j], pk[2 * j + 1]);
  };

  // prologue: A(0), B(0)
  ALOAD(0);
  BISSUE(0, 0);
  AWRITE();                                          // waits on v automatically
  asm volatile("s_waitcnt vmcnt(0)" ::: "memory");   // B(0) landed
  __syncthreads();                                   // Alds(0)+Blds[0] visible

  int cur = 0;
  for (int h = 0; h < 8; ++h) {
    if (h < 7) {               // next panel's loads fly under this compute
      ALOAD(h + 1);
      BISSUE(h + 1, cur ^ 1);
    }
#pragma unroll
    for (int kk = 0; kk < 64; kk += 32) {
      const int kbase = kk + g * 8;
      short8 af[2], bf[2];
#pragma unroll
      for (int mi = 0; mi < 2; ++mi) {
        const int row = wm * 32 + mi * 16 + ln;
        af[mi] = *(const short8*)&Alds[row * 64 + (kbase ^ ((row & 7) << 3))];
      }
#pragma unroll
      for (int ni = 0; ni < 2; ++ni) {
        const int row = wn * 32 + ni * 16 + ln;
        bf[ni] =
            *(const short8*)&Blds[cur][row * 64 + (kbase ^ ((row & 7) << 3))];
      }
#pragma unroll
      for (int mi = 0; mi < 2; ++mi)
#pragma unroll
        for (int ni = 0; ni < 2; ++ni)
          acc[mi][ni] = __builtin_amdgcn_mfma_f32_16x16x32_bf16(
              af[mi], bf[ni], acc[mi][ni], 0, 0, 0);
    }
    if (h < 7) {
      __syncthreads();   // all waves done reading Alds; B(h+1) long since landed
      AWRITE();          // stage A(h+1) into Alds
      __syncthreads();   // Alds(h+1) visible
      cur ^= 1;
    }
  }
#pragma unroll
  for (int mi = 0; mi < 2; ++mi)
#pragma unroll
    for (int ni = 0; ni < 2; ++ni)
#pragma unroll
      for (int r = 0; r < 4; ++r)
        Out[(size_t)(m0 + wm * 32 + mi * 16 + g * 4 + r) * 512 + n0 +
            wn * 32 + ni * 16 + ln] = acc[mi][ni][r];
}

extern "C" void kernel_launch(void* const* d_in, const int* in_sizes, int n_in,
                              void* d_out, int out_size, void* d_ws,
                              size_t ws_size, hipStream_t stream) {
  const float* x = (const float*)d_in[0];       // [2,64,48,512]
  const float* w_qkv = (const float*)d_in[1];   // [512,1536]
  const float* w_out = (const float*)d_in[2];   // [512,512]
  const float* rrow = (const float*)d_in[3];    // [127,8]
  const float* rcol = (const float*)d_in[4];    // [95,8]
  float* out = (float*)d_out;                   // [6144,512]

  unsigned short* ws16 = (unsigned short*)d_ws;
  unsigned short* xh = ws16;                    // 3145728
  unsigned short* xl = xh + 3145728;            // 3145728
  unsigned short* wqh = xl + 3145728;           // 786432
  unsigned short* wql = wqh + 786432;
  unsigned short* woh = wql + 786432;           // 262144
  unsigned short* wol = woh + 262144;
  unsigned short* Qb = wol + 262144;            // 3145728
  unsigned short* Vb = Qb + 3145728;            // 3145728
  unsigned short* KV = Vb + 3145728;            // 16*32*12800 = 6553600
  unsigned short* Opart = KV + 6553600;         // bf16 now
  const size_t base_bytes =
      ((size_t)3145728 * 4 + 786432 * 2 + 262144 * 2 + 6553600) * 2;
  const size_t per_split = (size_t)3145728 * 2 + (size_t)49152 * 4;
  const int nsplit = (ws_size >= base_bytes + 2 * per_split) ? 2 : 1;
  float* Lpart = (float*)(Opart + (size_t)nsplit * 3145728);

  ga_conv_all<<<1792, 256, 0, stream>>>(x, w_qkv, w_out, xh, xl, wqh, wql, woh,
                                        wol);
  ga_mm3<128, 128><<<576, 256, 0, stream>>>(xh, xl, wqh, wql, Qb, KV, Vb);
  ga_vtrans<<<512, 256, 0, stream>>>(Vb, KV);
  ga_attn16<<<24 * 16 * nsplit, 256, 0, stream>>>(
      Qb, KV, rrow, rcol, Opart, Lpart, nsplit);
  if (nsplit == 2)
    ga_outmm<2><<<dim3(96, 8), 256, 0, stream>>>(Opart, Lpart, woh, out);
  else
    ga_outmm<1><<<dim3(96, 8), 256, 0, stream>>>(Opart, Lpart, woh, out);
}

// Round 17
// 115.231 us; speedup vs baseline: 1.7128x; 1.0158x over previous
//
#include <hip/hip_runtime.h>
#include <hip/hip_bf16.h>

#define S_TOK 3072   // 64*48
#define NHEADS 8
#define KVT 12800    // u16 per KV tile: K 6144 ([96][64] swz) + V 6656 ([64][104])

typedef __attribute__((ext_vector_type(8))) short short8;
typedef __attribute__((ext_vector_type(4))) float floatx4;
typedef __attribute__((ext_vector_type(4))) unsigned short ushortx4;

__device__ __forceinline__ unsigned short f2bf(float f) {
  union { float f; unsigned u; } v; v.f = f;
  unsigned r = v.u + 0x7fffu + ((v.u >> 16) & 1u);   // RTN-even
  return (unsigned short)(r >> 16);
}
__device__ __forceinline__ float bf2f(unsigned short h) {
  union { unsigned u; float f; } v; v.u = (unsigned)h << 16;
  return v.f;
}
__device__ __forceinline__ unsigned pack2bf(float a, float b) {
  __hip_bfloat162 h = __float22bfloat162_rn(make_float2(a, b));
  union { __hip_bfloat162 h; unsigned u; } c; c.h = h;
  return c.u;
}
__device__ __forceinline__ void gload16(const void* g, void* l) {
  __builtin_amdgcn_global_load_lds(
      (const __attribute__((address_space(1))) unsigned int*)g,
      (__attribute__((address_space(3))) unsigned int*)l, 16, 0, 0);
}

// ---- merged converter: X hi/lo (blocks 0..1535), w_qkv^T (1536..1727),
// w_out^T (1728..1791); all outputs pre-swizzled for gload_lds staging ----
__global__ __launch_bounds__(256) void ga_conv_all(
    const float* __restrict__ X, const float* __restrict__ Wq,
    const float* __restrict__ Wo, unsigned short* __restrict__ xh,
    unsigned short* __restrict__ xl, unsigned short* __restrict__ wqh,
    unsigned short* __restrict__ wql, unsigned short* __restrict__ woh,
    unsigned short* __restrict__ wol) {
  const int blk = blockIdx.x;
  const int t = threadIdx.x;
  if (blk < 1536) {
    const int c = blk * 256 + t;
    const int m = c >> 6;
    const int c8 = (c & 63) << 3;
    const float* src = X + (size_t)m * 512 + c8;
    float4 v0 = *(const float4*)src, v1 = *(const float4*)(src + 4);
    float vv[8] = {v0.x, v0.y, v0.z, v0.w, v1.x, v1.y, v1.z, v1.w};
    union { unsigned short s[8]; short8 v; } hh, ll;
#pragma unroll
    for (int e = 0; e < 8; ++e) {
      hh.s[e] = f2bf(vv[e]);
      ll.s[e] = f2bf(vv[e] - bf2f(hh.s[e]));
    }
    const size_t dst = (size_t)m * 512 + (c8 ^ ((m & 7) << 3));
    *(short8*)&xh[dst] = hh.v;
    *(short8*)&xl[dst] = ll.v;
    return;
  }
  const int wq = (blk < 1728);
  const int b2 = wq ? (blk - 1536) : (blk - 1728);
  const int N = wq ? 1536 : 512;
  const float* W = wq ? Wq : Wo;
  unsigned short* th = wq ? wqh : woh;
  unsigned short* tl = wq ? wql : wol;
  const int k0 = (b2 & 7) * 64, n0 = (b2 >> 3) * 64;
  __shared__ float Ts[64][65];
#pragma unroll
  for (int i = 0; i < 4; ++i) {
    const int r = (t >> 4) + i * 16, c4 = (t & 15) * 4;
    float4 v = *(const float4*)&W[(size_t)(k0 + r) * N + n0 + c4];
    Ts[r][c4] = v.x; Ts[r][c4 + 1] = v.y; Ts[r][c4 + 2] = v.z; Ts[r][c4 + 3] = v.w;
  }
  __syncthreads();
#pragma unroll
  for (int j = 0; j < 2; ++j) {
    const int chunk = t * 2 + j;
    const int nl = chunk >> 3, m8 = chunk & 7;
    const int n = n0 + nl;
    const int ks = (m8 * 8) ^ ((n & 7) << 3);
    union { unsigned short s[8]; short8 v; } hh, ll;
#pragma unroll
    for (int e = 0; e < 8; ++e) {
      float f = Ts[ks + e][nl];
      hh.s[e] = f2bf(f);
      ll.s[e] = f2bf(f - bf2f(hh.s[e]));
    }
    const size_t dst = (size_t)n * 512 + k0 + m8 * 8;
    *(short8*)&th[dst] = hh.v;
    *(short8*)&tl[dst] = ll.v;
  }
}

// ---- bf16x3 MFMA GEMM for QKV; K AND V go directly into tiled KV buffer.
// V epilogue fuses the transpose+key-permute (vtrans kernel deleted).
// Q/K column-blocks use 2 terms; V keeps 3 terms.
template <int BM, int BN>
__global__ __launch_bounds__(256, 2) void ga_mm3(
    const unsigned short* __restrict__ Ah, const unsigned short* __restrict__ Al,
    const unsigned short* __restrict__ Bh, const unsigned short* __restrict__ Bl,
    unsigned short* __restrict__ Qd, unsigned short* __restrict__ KV) {
  const int tid = threadIdx.x;
  const int w = tid >> 6, l = tid & 63;
  const int g = l >> 4, ln = l & 15;
  const int wm = w >> 1, wn = w & 1;
  // XCD swizzle: 576 blocks, 72 per XCD, y-major within XCD chunk
  const int wgid = blockIdx.x;
  const int jj = (wgid & 7) * 72 + (wgid >> 3);
  const int m0 = (jj % 48) * BM;
  const int n0 = (jj / 48) * BN;
  const bool full3 = (n0 >= 1024);   // V blocks only
  constexpr int MI = BM / 32;
  constexpr int NI = BN / 32;
  __shared__ unsigned short Alds[2][BM * 64];
  __shared__ unsigned short Blds[2][BN * 64];
  floatx4 acc[MI][NI];
#pragma unroll
  for (int mi = 0; mi < MI; ++mi)
#pragma unroll
    for (int ni = 0; ni < NI; ++ni)
#pragma unroll
      for (int r = 0; r < 4; ++r) acc[mi][ni][r] = 0.f;

  for (int k0 = 0; k0 < 512; k0 += 64) {
    __syncthreads();
    {
      constexpr int PWA = (BM * 128) / 4096;
      constexpr int PWB = (BN * 128) / 4096;
      const char* ga_h = (const char*)(Ah + (size_t)m0 * 512 + k0);
      const char* ga_l = (const char*)(Al + (size_t)m0 * 512 + k0);
      const char* gb_h = (const char*)(Bh + (size_t)n0 * 512 + k0);
      const char* gb_l = (const char*)(Bl + (size_t)n0 * 512 + k0);
#pragma unroll
      for (int i = 0; i < PWA; ++i) {
        const int off = (w * PWA + i) * 1024;
        const int gb = ((off >> 7) + (l >> 3)) * 1024 + (l & 7) * 16;
        gload16(ga_h + gb, (char*)&Alds[0][0] + off);
        gload16(ga_l + gb, (char*)&Alds[1][0] + off);
      }
#pragma unroll
      for (int i = 0; i < PWB; ++i) {
        const int off = (w * PWB + i) * 1024;
        const int gb = ((off >> 7) + (l >> 3)) * 1024 + (l & 7) * 16;
        gload16(gb_h + gb, (char*)&Blds[0][0] + off);
        gload16(gb_l + gb, (char*)&Blds[1][0] + off);
      }
    }
    asm volatile("s_waitcnt vmcnt(0)" ::: "memory");
    __syncthreads();
#pragma unroll
    for (int kk = 0; kk < 64; kk += 32) {
      const int kbase = kk + g * 8;
      short8 ah[MI], al[MI], bh[NI], bl[NI];
#pragma unroll
      for (int mi = 0; mi < MI; ++mi) {
        const int row = wm * (BM / 2) + mi * 16 + ln;
        const int a = row * 64 + (kbase ^ ((row & 7) << 3));
        ah[mi] = *(const short8*)&Alds[0][a];
        al[mi] = *(const short8*)&Alds[1][a];
      }
#pragma unroll
      for (int ni = 0; ni < NI; ++ni) {
        const int row = wn * (BN / 2) + ni * 16 + ln;
        const int a = row * 64 + (kbase ^ ((row & 7) << 3));
        bh[ni] = *(const short8*)&Blds[0][a];
        bl[ni] = *(const short8*)&Blds[1][a];
      }
#pragma unroll
      for (int mi = 0; mi < MI; ++mi)
#pragma unroll
        for (int ni = 0; ni < NI; ++ni) {
          acc[mi][ni] = __builtin_amdgcn_mfma_f32_16x16x32_bf16(
              ah[mi], bh[ni], acc[mi][ni], 0, 0, 0);
          acc[mi][ni] = __builtin_amdgcn_mfma_f32_16x16x32_bf16(
              al[mi], bh[ni], acc[mi][ni], 0, 0, 0);
          if (full3)
            acc[mi][ni] = __builtin_amdgcn_mfma_f32_16x16x32_bf16(
                ah[mi], bl[ni], acc[mi][ni], 0, 0, 0);
        }
    }
  }
  // QKV scatter epilogue
  const int b = m0 / S_TOK;
  const int s_base = (m0 % S_TOK) + wm * (BM / 2);
#pragma unroll
  for (int ni = 0; ni < NI; ++ni) {
    const int ng = n0 + wn * (BN / 2) + ni * 16;
    const int which = ng >> 9;
    const int h = (ng >> 6) & 7;
    const int d = (ng & 63) + ln;
    const int bh = b * 8 + h;
    if (which == 1) {            // K: swizzled rows into KV K-region
      unsigned short* kp = KV + (size_t)bh * 32 * KVT;
#pragma unroll
      for (int mi = 0; mi < MI; ++mi)
#pragma unroll
        for (int r = 0; r < 4; ++r) {
          const int s = s_base + mi * 16 + g * 4 + r;
          const int tile = s / 96;
          const int r96 = s - tile * 96;
          kp[tile * KVT + r96 * 64 + (d ^ ((s & 7) << 3))] =
              f2bf(acc[mi][ni][r]);
        }
    } else if (which == 2) {     // V: transposed + key-permuted into KV V-region
      unsigned short* vt = KV + (size_t)bh * 32 * KVT + 6144;
#pragma unroll
      for (int mi = 0; mi < MI; ++mi) {
        const int s0 = s_base + mi * 16 + g * 4;   // 4 consecutive keys
        const int tile = s0 / 96;
        const int k96 = s0 - tile * 96;
        // inverse of vtrans perm: p = (k>>5)*32 + ((k>>2)&3)*8 + ((k>>4)&1)*4 + r
        const int pb = (k96 >> 5) * 32 + ((k96 >> 2) & 3) * 8 + ((k96 >> 4) & 1) * 4;
        ushortx4 o = {f2bf(acc[mi][ni][0]), f2bf(acc[mi][ni][1]),
                      f2bf(acc[mi][ni][2]), f2bf(acc[mi][ni][3])};
        *(ushortx4*)&vt[(size_t)tile * KVT + d * 104 + pb] = o;
      }
    } else {                     // Q: pre-scaled row-major
      unsigned short* hp = Qd + (size_t)bh * S_TOK * 64;
#pragma unroll
      for (int mi = 0; mi < MI; ++mi)
#pragma unroll
        for (int r = 0; r < 4; ++r) {
          const int s = s_base + mi * 16 + g * 4 + r;
          hp[(size_t)s * 64 + d] = f2bf(acc[mi][ni][r] * 0.18033688f);
        }
    }
  }
}

// -- Pass B: attention; dbuf KV staging, bias-in-C, XCD-local grid, setprio --
// Opart written as bf16 (l stays f32).
__global__ __launch_bounds__(256) void ga_attn16(
    const unsigned short* __restrict__ Q, const unsigned short* __restrict__ KVg,
    const float* __restrict__ rowtab, const float* __restrict__ coltab,
    unsigned short* __restrict__ Opart, float* __restrict__ Lpart, int nsplit) {
  const int tid = threadIdx.x;
  const int w = tid >> 6;
  const int l = tid & 63;
  const int g = l >> 4;
  const int ln = l & 15;
  // XCD-aware decode: all blocks of one bh land on one XCD
  const int wgid = blockIdx.x;
  const int idx = wgid >> 3;
  const int bpb = 24 * nsplit;                  // blocks per bh
  const int bh = ((wgid & 7) << 1) + idx / bpb;
  const int rem = idx % bpb;
  const int sp = rem / 24;
  const int qb = rem % 24;
  const int h = bh & 7;
  const int q0 = qb * 128 + w * 32;
  const int tiles_per_split = 32 / nsplit;

  __shared__ float rtab[127];
  __shared__ float ctab[95];
  __shared__ unsigned short KVlds[2][KVT];   // 2 x 25600 B
  for (int i = tid; i < 127; i += 256) rtab[i] = rowtab[i * 8 + h] * 1.44269504f;
  for (int i = tid; i < 95; i += 256) ctab[i] = coltab[i * 8 + h] * 1.44269504f;

  const unsigned short* Qp = Q + (size_t)bh * S_TOK * 64;
  const unsigned short* KVp = KVg + (size_t)bh * 32 * KVT;

  const int t0 = sp * tiles_per_split;
  const int tend = t0 + tiles_per_split;

  auto STAGE = [&](int b, int t) {
    const char* src = (const char*)(KVp + (size_t)t * KVT);
    char* dst = (char*)&KVlds[b][0];
#pragma unroll
    for (int i = 0; i < 6; ++i)
      gload16(src + i * 4096 + tid * 16, dst + i * 4096 + tid * 16);
    if (tid < 64) gload16(src + 24576 + tid * 16, dst + 24576 + tid * 16);
  };

  STAGE(0, t0);
  asm volatile("s_waitcnt vmcnt(0)" ::: "memory");
  __syncthreads();

  int qr[2], qc[2];
  short8 qf[2][2];
  float ctr[2][3][4];
#pragma unroll
  for (int u = 0; u < 2; ++u) {
    const int q = q0 + u * 16 + ln;
    qr[u] = q / 48;
    qc[u] = q - qr[u] * 48;
    qf[u][0] = *(const short8*)&Qp[(size_t)q * 64 + g * 8];
    qf[u][1] = *(const short8*)&Qp[(size_t)q * 64 + 32 + g * 8];
    const float* cb = &ctab[qc[u] - g * 4 + 47];
#pragma unroll
    for (int m = 0; m < 3; ++m)
#pragma unroll
      for (int r = 0; r < 4; ++r) ctr[u][m][r] = cb[-(16 * m + r)];
  }

  short8 ones;
  {
    union { unsigned short s[8]; short8 v; } on;
#pragma unroll
    for (int j = 0; j < 8; ++j) on.s[j] = 0x3F80;  // bf16 1.0
    ones = on.v;
  }

  floatx4 o_acc[2][4];
  floatx4 o5[2];
#pragma unroll
  for (int u = 0; u < 2; ++u) {
#pragma unroll
    for (int r = 0; r < 4; ++r) o5[u][r] = 0.f;
#pragma unroll
    for (int dt = 0; dt < 4; ++dt)
#pragma unroll
      for (int r = 0; r < 4; ++r) o_acc[u][dt][r] = 0.f;
  }

  int cur = 0;
  for (int t = t0; t < tend; ++t) {
    if (t + 1 < tend) STAGE(cur ^ 1, t + 1);   // loads fly under compute
    const unsigned short* kb = &KVlds[cur][0];
    const unsigned short* vb = &KVlds[cur][6144];
    float rt[2][2];
#pragma unroll
    for (int u = 0; u < 2; ++u) {
      rt[u][0] = rtab[qr[u] + 63 - 2 * t] - 12.0f;
      rt[u][1] = rtab[qr[u] + 62 - 2 * t] - 12.0f;
    }
    const int swz = (ln & 7) << 3;
#pragma unroll
    for (int kc32 = 0; kc32 < 3; ++kc32) {
      float e[2][2][4];
#pragma unroll
      for (int kh = 0; kh < 2; ++kh) {
        const int kt = kc32 * 2 + kh;
        const int rb = (kt * 16 + ln) * 64;
        short8 kf0 = *(const short8*)&kb[rb + ((g * 8) ^ swz)];
        short8 kf1 = *(const short8*)&kb[rb + ((32 + g * 8) ^ swz)];
        const int m = kt % 3, wrap = kt / 3;
#pragma unroll
        for (int u = 0; u < 2; ++u) {
          // bias folded into the MFMA C-operand: D = K·Q^T + bias
          floatx4 s;
#pragma unroll
          for (int r = 0; r < 4; ++r) s[r] = rt[u][wrap] + ctr[u][m][r];
          s = __builtin_amdgcn_mfma_f32_16x16x32_bf16(kf0, qf[u][0], s, 0, 0, 0);
          s = __builtin_amdgcn_mfma_f32_16x16x32_bf16(kf1, qf[u][1], s, 0, 0, 0);
#pragma unroll
          for (int r = 0; r < 4; ++r)
            e[u][kh][r] = __builtin_amdgcn_exp2f(s[r]);
        }
      }
      short8 pf[2];
#pragma unroll
      for (int u = 0; u < 2; ++u) {
        union { unsigned uu[4]; short8 v; } pk;
        pk.uu[0] = pack2bf(e[u][0][0], e[u][0][1]);
        pk.uu[1] = pack2bf(e[u][0][2], e[u][0][3]);
        pk.uu[2] = pack2bf(e[u][1][0], e[u][1][1]);
        pk.uu[3] = pack2bf(e[u][1][2], e[u][1][3]);
        pf[u] = pk.v;
      }
      __builtin_amdgcn_s_setprio(1);   // favor the MFMA-feeding wave (T5)
#pragma unroll
      for (int dt = 0; dt < 4; ++dt) {
        const int vrow = dt * 16 + ln;
        short8 vf = *(const short8*)&vb[vrow * 104 + kc32 * 32 + g * 8];
        o_acc[0][dt] =
            __builtin_amdgcn_mfma_f32_16x16x32_bf16(pf[0], vf, o_acc[0][dt], 0, 0, 0);
        o_acc[1][dt] =
            __builtin_amdgcn_mfma_f32_16x16x32_bf16(pf[1], vf, o_acc[1][dt], 0, 0, 0);
      }
      o5[0] = __builtin_amdgcn_mfma_f32_16x16x32_bf16(pf[0], ones, o5[0], 0, 0, 0);
      o5[1] = __builtin_amdgcn_mfma_f32_16x16x32_bf16(pf[1], ones, o5[1], 0, 0, 0);
      __builtin_amdgcn_s_setprio(0);
    }
    asm volatile("s_waitcnt vmcnt(0)" ::: "memory");  // my stage loads landed
    __syncthreads();            // everyone's landed; everyone done reading cur
    cur ^= 1;
  }
  const size_t rowbase = (size_t)(sp * 16 + bh) * S_TOK;
#pragma unroll
  for (int u = 0; u < 2; ++u) {
    if (ln == 0) {
#pragma unroll
      for (int r = 0; r < 4; ++r)
        Lpart[rowbase + q0 + u * 16 + g * 4 + r] = o5[u][r];
    }
#pragma unroll
    for (int dt = 0; dt < 4; ++dt)
#pragma unroll
      for (int r = 0; r < 4; ++r)
        Opart[(rowbase + q0 + u * 16 + g * 4 + r) * 64 + dt * 16 + ln] =
            f2bf(o_acc[u][dt][r]);
  }
}

// --- Pass C: output GEMM (bf16) + fused split-K combine; XCD m-chunk grid ---
template <int NS>
__global__ __launch_bounds__(256, 2) void ga_outmm(
    const unsigned short* __restrict__ Opart, const float* __restrict__ Lpart,
    const unsigned short* __restrict__ Bh_, float* __restrict__ Out) {
  const int tid = threadIdx.x;
  const int w = tid >> 6, l = tid & 63;
  const int g = l >> 4, ln = l & 15;
  const int wm = w >> 1, wn = w & 1;
  // XCD swizzle: 768 blocks, 96/XCD = 12 m-blocks x 8 n-blocks (A-panel L2-local)
  const int wgid = blockIdx.x;
  const int i = wgid >> 3;
  const int m0 = ((wgid & 7) * 12 + (i >> 3)) * 64;
  const int n0 = (i & 7) * 64;
  __shared__ unsigned short Alds[64 * 64];
  __shared__ unsigned short Blds[2][64 * 64];
  floatx4 acc[2][2];
#pragma unroll
  for (int mi = 0; mi < 2; ++mi)
#pragma unroll
    for (int ni = 0; ni < 2; ++ni)
#pragma unroll
      for (int r = 0; r < 4; ++r) acc[mi][ni][r] = 0.f;

  const int lm = tid >> 2, lk4 = tid & 3;
  const int m = m0 + lm;
  const int b = (m >= S_TOK) ? 1 : 0;
  const int q = m - b * S_TOK;

  float v[16];
  float ls;
  auto ALOAD = [&](int h) {
    const int bh = b * 8 + h;
    ls = 0.f;
#pragma unroll
    for (int s = 0; s < NS; ++s) {
      const size_t row = (size_t)(s * 16 + bh) * S_TOK + q;
      ls += Lpart[row];
      const unsigned short* op = &Opart[row * 64 + lk4 * 16];
      short8 a0 = *(const short8*)op;
      short8 a1 = *(const short8*)(op + 8);
#pragma unroll
      for (int j = 0; j < 8; ++j) {
        float f0 = bf2f((unsigned short)a0[j]);
        float f1 = bf2f((unsigned short)a1[j]);
        if (s == 0) {
          v[j] = f0;
          v[8 + j] = f1;
        } else {
          v[j] += f0;
          v[8 + j] += f1;
        }
      }
    }
  };
  auto BISSUE = [&](int h, int buf) {
    const char* gb = (const char*)(Bh_ + (size_t)n0 * 512 + h * 64);
#pragma unroll
    for (int i2 = 0; i2 < 2; ++i2) {
      const int off = (w * 2 + i2) * 1024;
      const int gbo = ((off >> 7) + (l >> 3)) * 1024 + (l & 7) * 16;
      gload16(gb + gbo, (char*)&Blds[buf][0] + off);
    }
  };
  auto AWRITE = [&]() {
    const float inv = 1.0f / ls;
    unsigned pk[8];
#pragma unroll
    for (int j = 0; j < 8; ++j)
      pk[j] = pack2bf(v[2 * j] * inv, v[2 * j + 1] * inv);
    const int sw = (lm & 7) << 3;
    unsigned short* ab = &Alds[lm * 64];
#pragma unroll
    for (int j = 0; j < 4; ++j)
      *(uint2*)&ab[(lk4 * 16 + j * 4) ^ sw] = make_uint2(pk[2 * j], pk[2 * j + 1]);
  };

  // prologue: A(0), B(0)
  ALOAD(0);
  BISSUE(0, 0);
  AWRITE();                                          // waits on v automatically
  asm volatile("s_waitcnt vmcnt(0)" ::: "memory");   // B(0) landed
  __syncthreads();                                   // Alds(0)+Blds[0] visible

  int cur = 0;
  for (int h = 0; h < 8; ++h) {
    if (h < 7) {               // next panel's loads fly under this compute
      ALOAD(h + 1);
      BISSUE(h + 1, cur ^ 1);
    }
#pragma unroll
    for (int kk = 0; kk < 64; kk += 32) {
      const int kbase = kk + g * 8;
      short8 af[2], bf[2];
#pragma unroll
      for (int mi = 0; mi < 2; ++mi) {
        const int row = wm * 32 + mi * 16 + ln;
        af[mi] = *(const short8*)&Alds[row * 64 + (kbase ^ ((row & 7) << 3))];
      }
#pragma unroll
      for (int ni = 0; ni < 2; ++ni) {
        const int row = wn * 32 + ni * 16 + ln;
        bf[ni] =
            *(const short8*)&Blds[cur][row * 64 + (kbase ^ ((row & 7) << 3))];
      }
#pragma unroll
      for (int mi = 0; mi < 2; ++mi)
#pragma unroll
        for (int ni = 0; ni < 2; ++ni)
          acc[mi][ni] = __builtin_amdgcn_mfma_f32_16x16x32_bf16(
              af[mi], bf[ni], acc[mi][ni], 0, 0, 0);
    }
    if (h < 7) {
      __syncthreads();   // all waves done reading Alds; B(h+1) long since landed
      AWRITE();          // stage A(h+1) into Alds
      __syncthreads();   // Alds(h+1) visible
      cur ^= 1;
    }
  }
#pragma unroll
  for (int mi = 0; mi < 2; ++mi)
#pragma unroll
    for (int ni = 0; ni < 2; ++ni)
#pragma unroll
      for (int r = 0; r < 4; ++r)
        Out[(size_t)(m0 + wm * 32 + mi * 16 + g * 4 + r) * 512 + n0 +
            wn * 32 + ni * 16 + ln] = acc[mi][ni][r];
}

extern "C" void kernel_launch(void* const* d_in, const int* in_sizes, int n_in,
                              void* d_out, int out_size, void* d_ws,
                              size_t ws_size, hipStream_t stream) {
  const float* x = (const float*)d_in[0];       // [2,64,48,512]
  const float* w_qkv = (const float*)d_in[1];   // [512,1536]
  const float* w_out = (const float*)d_in[2];   // [512,512]
  const float* rrow = (const float*)d_in[3];    // [127,8]
  const float* rcol = (const float*)d_in[4];    // [95,8]
  float* out = (float*)d_out;                   // [6144,512]

  unsigned short* ws16 = (unsigned short*)d_ws;
  unsigned short* xh = ws16;                    // 3145728
  unsigned short* xl = xh + 3145728;            // 3145728
  unsigned short* wqh = xl + 3145728;           // 786432
  unsigned short* wql = wqh + 786432;
  unsigned short* woh = wql + 786432;           // 262144
  unsigned short* wol = woh + 262144;
  unsigned short* Qb = wol + 262144;            // 3145728
  unsigned short* KV = Qb + 3145728;            // 16*32*12800 = 6553600
  unsigned short* Opart = KV + 6553600;         // bf16
  const size_t base_bytes =
      ((size_t)3145728 * 3 + 786432 * 2 + 262144 * 2 + 6553600) * 2;
  const size_t per_split = (size_t)3145728 * 2 + (size_t)49152 * 4;
  const int nsplit = (ws_size >= base_bytes + 2 * per_split) ? 2 : 1;
  float* Lpart = (float*)(Opart + (size_t)nsplit * 3145728);

  ga_conv_all<<<1792, 256, 0, stream>>>(x, w_qkv, w_out, xh, xl, wqh, wql, woh,
                                        wol);
  ga_mm3<128, 128><<<576, 256, 0, stream>>>(xh, xl, wqh, wql, Qb, KV);
  ga_attn16<<<24 * 16 * nsplit, 256, 0, stream>>>(
      Qb, KV, rrow, rcol, Opart, Lpart, nsplit);
  if (nsplit == 2)
    ga_outmm<2><<<768, 256, 0, stream>>>(Opart, Lpart, woh, out);
  else
    ga_outmm<1><<<768, 256, 0, stream>>>(Opart, Lpart, woh, out);
}